// Round 9
// baseline (463.760 us; speedup 1.0000x reference)
//
#include <hip/hip_runtime.h>
#include <math.h>

#define NN 30000          // nodes
#define NE 480000         // edges
#define FEA 16            // edge feature dim
#define HID 64
#define NG 64             // graphs
#define LEAKK 0.2f

// ---- small-constant region layout (float offsets) ----
#define S_MEANEA 0    // 16
#define S_KF1    16   // 64  (K1 [16,4])
#define S_C1     80   // 4
#define S_AEL1   84   // 4
#define S_KF2    88   // 64
#define S_C2     152  // 4
#define S_AEL2   156  // 4
#define S_MS1    160  // 512 (Ms1 [128,4])
#define S_MD1    672  // 512
#define S_MS2    1184 // 256 (Ms2 [64,4])
#define S_MD2    1440 // 256

__device__ __forceinline__ float eluf(float v) { return v > 0.f ? v : expm1f(v); }
__device__ __forceinline__ float leakyf(float v) { return v >= 0.f ? v : LEAKK * v; }
__device__ __forceinline__ void fma4(float4& a, float w, const float4& x) {
    a.x += w * x.x; a.y += w * x.y; a.z += w * x.z; a.w += w * x.w;
}

// ---- count (CSR degree) + mean of edge_attr: 938 blocks x 512 edges ----
__global__ __launch_bounds__(256) void count_mean_kernel(
    const int* __restrict__ dst, const float* __restrict__ EA,
    int* __restrict__ cnt, float* __restrict__ S) {
    __shared__ float red[1024];
    int t = threadIdx.x;
    int base = blockIdx.x * 512;
#pragma unroll
    for (int i = 0; i < 2; i++) {
        int e = base + i * 256 + t;
        if (e < NE) atomicAdd(&cnt[dst[e]], 1);
    }
    int c4 = t & 3;
    int rbase = base + (t >> 2);
    float4 acc = {0, 0, 0, 0};
#pragma unroll
    for (int i = 0; i < 8; i++) {
        int r = rbase + i * 64;
        if (r < NE) {
            float4 v = *(const float4*)(EA + (size_t)r * FEA + c4 * 4);
            acc.x += v.x; acc.y += v.y; acc.z += v.z; acc.w += v.w;
        }
    }
    *(float4*)&red[t * 4] = acc;
    __syncthreads();
    if (t < 16) {
        int grp = t >> 2;
        int comp = t & 3;
        float sum = 0.f;
        for (int j = 0; j < 64; j++) sum += red[(grp + 4 * j) * 4 + comp];
        atomicAdd(&S[S_MEANEA + grp * 4 + comp], sum);
    }
}

// ---- parallel weight-layout build ----
__global__ void prep_weights_kernel(const float* __restrict__ W1, const float* __restrict__ W2,
                                    const float* __restrict__ Wl, const float* __restrict__ Wr,
                                    float* __restrict__ WC1, float* __restrict__ WC2,
                                    float* __restrict__ B128) {
    int i = blockIdx.x * 256 + threadIdx.x;
    if (i < 32768) {
        int hk = i >> 6, c = i & 63;
        int h = hk >> 7, k = hk & 127;
        WC1[i] = 0.25f * W1[k * 256 + h * 64 + c];
    } else if (i < 49152) {
        int j = i - 32768;
        int hk = j >> 6, c = j & 63;
        int h = hk >> 6, k = hk & 63;
        WC2[j] = 0.25f * W2[k * 256 + h * 64 + c];
    } else if (i < 57344) {
        int j = i - 49152;
        int k = j >> 6, c = j & 63;
        B128[j] = (k < 64) ? Wl[k * 64 + c] : Wr[(k - 64) * 64 + c];
    }
}

// ---- fold attention weights into small matrices ----
__global__ void prep_small_kernel(
    const float* __restrict__ W1, const float* __restrict__ as1, const float* __restrict__ ad1,
    const float* __restrict__ ae1, const float* __restrict__ leW1,
    const float* __restrict__ W2, const float* __restrict__ as2, const float* __restrict__ ad2,
    const float* __restrict__ ae2, const float* __restrict__ leW2,
    const float* __restrict__ edge_W, const float* __restrict__ edge_b,
    float* __restrict__ S) {
    __shared__ float M1[256], M2[256], meh[64];
    int t = threadIdx.x;
    if (t < 16) S[S_MEANEA + t] *= (1.0f / (float)NE);
    __syncthreads();
    {
        int k = t >> 2, h = t & 3;
        float m1 = 0.f, m2 = 0.f;
        for (int c = 0; c < 64; c++) {
            m1 += leW1[k * 256 + h * 64 + c] * ae1[h * 64 + c];
            m2 += leW2[k * 256 + h * 64 + c] * ae2[h * 64 + c];
        }
        M1[t] = m1; M2[t] = m2;
    }
    if (t < 64) {
        float v = edge_b[t];
        for (int f = 0; f < FEA; f++) v += S[S_MEANEA + f] * edge_W[f * 64 + t];
        meh[t] = v;
    }
    __syncthreads();
    if (t < 64) {
        int f = t >> 2, h = t & 3;
        float k1 = 0.f, k2 = 0.f;
        for (int k = 0; k < 64; k++) {
            k1 += edge_W[f * 64 + k] * M1[k * 4 + h];
            k2 += edge_W[f * 64 + k] * M2[k * 4 + h];
        }
        S[S_KF1 + t] = k1; S[S_KF2 + t] = k2;
    } else if (t < 68) {
        int h = t - 64;
        float c1 = 0.f, c2 = 0.f, a1 = 0.f, a2 = 0.f;
        for (int k = 0; k < 64; k++) {
            c1 += edge_b[k] * M1[k * 4 + h];
            c2 += edge_b[k] * M2[k * 4 + h];
            a1 += meh[k] * M1[k * 4 + h];
            a2 += meh[k] * M2[k * 4 + h];
        }
        S[S_C1 + h] = c1; S[S_C2 + h] = c2;
        S[S_AEL1 + h] = a1; S[S_AEL2 + h] = a2;
    }
    for (int i = t; i < 512; i += 256) {
        int k = i >> 2, h = i & 3;
        float s = 0.f, d = 0.f;
        for (int c = 0; c < 64; c++) {
            float w = W1[k * 256 + h * 64 + c];
            s += w * as1[h * 64 + c];
            d += w * ad1[h * 64 + c];
        }
        S[S_MS1 + i] = s; S[S_MD1 + i] = d;
    }
    for (int i = t; i < 256; i += 256) {
        int k = i >> 2, h = i & 3;
        float s = 0.f, d = 0.f;
        for (int c = 0; c < 64; c++) {
            float w = W2[k * 256 + h * 64 + c];
            s += w * as2[h * 64 + c];
            d += w * ad2[h * 64 + c];
        }
        S[S_MS2 + i] = s; S[S_MD2 + i] = d;
    }
}

// ---- build h0 = concat(x, emb[type]) AND compute layer-1 a_s/a_d ----
__global__ __launch_bounds__(256) void attn_h0_kernel(
    const float* __restrict__ x, const float* __restrict__ node_emb,
    const int* __restrict__ node_type, const float* __restrict__ S,
    float* __restrict__ h0, float* __restrict__ as_, float* __restrict__ ad_) {
    __shared__ float xt[64 * 132];
    __shared__ float ms[512], md[512];
    __shared__ int ntS[64];
    int t = threadIdx.x;
    int n0 = blockIdx.x * 64;
    if (t < 64) {
        int n = n0 + t;
        ntS[t] = (n < NN) ? node_type[n] : 0;
    }
    for (int i = t; i < 512; i += 256) { ms[i] = S[S_MS1 + i]; md[i] = S[S_MD1 + i]; }
    __syncthreads();
    for (int i = t; i < 1024; i += 256) {
        int r = i >> 4, c4 = (i & 15) * 4;
        int n = n0 + r;
        float4 f = {0, 0, 0, 0};
        if (n < NN) f = *(const float4*)(x + (size_t)n * 64 + c4);
        *(float4*)&xt[r * 132 + c4] = f;
    }
    for (int i = t; i < 1024; i += 256) {
        int r = i >> 4, c4 = (i & 15) * 4;
        int n = n0 + r;
        float4 f = {0, 0, 0, 0};
        if (n < NN) f = *(const float4*)(node_emb + (size_t)ntS[r] * 64 + c4);
        *(float4*)&xt[r * 132 + 64 + c4] = f;
    }
    __syncthreads();
    for (int i = t; i < 2048; i += 256) {
        int r = i >> 5, c4 = (i & 31) * 4;
        int n = n0 + r;
        if (n < NN) *(float4*)(h0 + (size_t)n * 128 + c4) = *(const float4*)&xt[r * 132 + c4];
    }
    int r = t >> 2, h = t & 3;
    float s = 0.f, d = 0.f;
#pragma unroll 8
    for (int k = 0; k < 128; k++) {
        float xv = xt[r * 132 + k];
        s += xv * ms[k * 4 + h];
        d += xv * md[k * 4 + h];
    }
    int n = n0 + r;
    if (n < NN) { as_[n * 4 + h] = s; ad_[n * 4 + h] = d; }
}

// ---- 3-kernel decoupled scan ----
__global__ void scan_blocks_kernel(const int* __restrict__ cnt, int* __restrict__ eoff,
                                   int* __restrict__ bsum) {
    __shared__ int wsum[16];
    int t = threadIdx.x;
    int i = blockIdx.x * 1024 + t;
    int v = (i < NN) ? cnt[i] : 0;
    int lane = t & 63;
    int incl = v;
#pragma unroll
    for (int ofs = 1; ofs < 64; ofs <<= 1) {
        int u = __shfl_up(incl, ofs, 64);
        if (lane >= ofs) incl += u;
    }
    int wid = t >> 6;
    if (lane == 63) wsum[wid] = incl;
    __syncthreads();
    if (t < 16) {
        int s = wsum[t];
#pragma unroll
        for (int ofs = 1; ofs < 16; ofs <<= 1) {
            int u = __shfl_up(s, ofs, 64);
            if (t >= ofs) s += u;
        }
        wsum[t] = s;
    }
    __syncthreads();
    int excl = incl - v + (wid > 0 ? wsum[wid - 1] : 0);
    if (i < NN) eoff[i] = excl;
    if (t == 1023) bsum[blockIdx.x] = excl + v;
}

__global__ void scan_tops_kernel(const int* __restrict__ bsum, int* __restrict__ boff, int nb) {
    int t = threadIdx.x; // 64
    int v = (t < nb) ? bsum[t] : 0;
    int incl = v;
#pragma unroll
    for (int ofs = 1; ofs < 64; ofs <<= 1) {
        int u = __shfl_up(incl, ofs, 64);
        if (t >= ofs) incl += u;
    }
    boff[t] = incl - v;
}

__global__ void scan_add_kernel(const int* __restrict__ boff, int* __restrict__ eoff) {
    int i = blockIdx.x * 256 + threadIdx.x;
    if (i < NN) eoff[i] += boff[i >> 10];
    if (i == 0) eoff[NN] = NE;
}

// ---- fused scatter + scoring v2: coalesced weight writes at [e]; scatter int2{s,e} ----
__global__ void scatter_score_kernel(const int* __restrict__ src, const int* __restrict__ dst,
                                     const float* __restrict__ EA, const float* __restrict__ S,
                                     const float* __restrict__ as_, const float* __restrict__ ad_,
                                     const int* __restrict__ eoff, int* __restrict__ pos,
                                     int2* __restrict__ se_sorted,
                                     float* __restrict__ sc1, float* __restrict__ ae2s) {
    int e = blockIdx.x * 256 + threadIdx.x;
    if (e >= NE) return;
    int s = src[e], d = dst[e];
    float a1[4], a2[4];
#pragma unroll
    for (int h = 0; h < 4; h++) { a1[h] = S[S_C1 + h]; a2[h] = S[S_C2 + h]; }
    const float4* EA4 = (const float4*)(EA + (size_t)e * FEA);
#pragma unroll
    for (int q = 0; q < 4; q++) {
        float4 v = EA4[q];
        float vv[4] = {v.x, v.y, v.z, v.w};
#pragma unroll
        for (int j = 0; j < 4; j++) {
            int f = q * 4 + j;
#pragma unroll
            for (int h = 0; h < 4; h++) {
                a1[h] += vv[j] * S[S_KF1 + f * 4 + h];
                a2[h] += vv[j] * S[S_KF2 + f * 4 + h];
            }
        }
    }
    // coalesced writes in edge order
    ((float4*)ae2s)[e] = make_float4(a2[0], a2[1], a2[2], a2[3]);
    float4 asv = ((const float4*)as_)[s];
    float4 adv = ((const float4*)ad_)[d];
    float4 r;
    r.x = expf(leakyf(asv.x + adv.x + a1[0]));
    r.y = expf(leakyf(asv.y + adv.y + a1[1]));
    r.z = expf(leakyf(asv.z + adv.z + a1[2]));
    r.w = expf(leakyf(asv.w + adv.w + a1[3]));
    ((float4*)sc1)[e] = r;
    // single 8B random write for the CSR permutation
    int p = atomicAdd(&pos[d], 1);
    se_sorted[eoff[d] + p] = make_int2(s, e);
}

// ---- goff via binary search over sorted batch ----
__global__ void goff_bs_kernel(const int* __restrict__ batch, int* __restrict__ goff) {
    int g = threadIdx.x;
    if (g > NG) return;
    int lo = 0, hi = NN;
    while (lo < hi) {
        int mid = (lo + hi) >> 1;
        if (batch[mid] < g) lo = mid + 1; else hi = mid;
    }
    goff[g] = lo;
}

// ---- GAT aggregate-first; weights gathered via edge id (L2/L3-resident) ----
template <int KD, bool CW>
__global__ __launch_bounds__(256) void agg_gat_kernel(
    const int* __restrict__ eoff, const int2* __restrict__ se_sorted,
    const float* __restrict__ wsrc, const float* __restrict__ X,
    const float* __restrict__ as_, const float* __restrict__ ad_,
    const float* __restrict__ Sael, float* __restrict__ agg) {
    constexpr int CHUNKS = KD / 4;
    constexpr int EPW = 64 / CHUNKS;
    int n = blockIdx.x * 4 + (threadIdx.x >> 6);
    if (n >= NN) return;
    int lane = threadIdx.x & 63;
    int sub = lane / CHUNKS;
    int ch = lane % CHUNKS;
    const float4* X4 = (const float4*)X;
    const float4* W4 = (const float4*)wsrc;
    const float4* AS4 = (const float4*)as_;
    float4 asn = AS4[n];
    float4 adn = ((const float4*)ad_)[n];
    float4 a0 = {0, 0, 0, 0}, a1 = a0, a2 = a0, a3 = a0, dn = a0;
    int b = eoff[n], e = eoff[n + 1];
    int nE = e - b;
    int i = sub;
    for (; i + EPW < nE; i += 2 * EPW) {
        int2 se0 = se_sorted[b + i], se1 = se_sorted[b + i + EPW];
        float4 w0 = W4[se0.y], w1 = W4[se1.y];
        if (CW) {
            float4 q0 = AS4[se0.x], q1 = AS4[se1.x];
            w0.x = expf(leakyf(q0.x + adn.x + w0.x));
            w0.y = expf(leakyf(q0.y + adn.y + w0.y));
            w0.z = expf(leakyf(q0.z + adn.z + w0.z));
            w0.w = expf(leakyf(q0.w + adn.w + w0.w));
            w1.x = expf(leakyf(q1.x + adn.x + w1.x));
            w1.y = expf(leakyf(q1.y + adn.y + w1.y));
            w1.z = expf(leakyf(q1.z + adn.z + w1.z));
            w1.w = expf(leakyf(q1.w + adn.w + w1.w));
        }
        float4 x0 = X4[(size_t)se0.x * CHUNKS + ch];
        float4 x1 = X4[(size_t)se1.x * CHUNKS + ch];
        fma4(a0, w0.x, x0); fma4(a1, w0.y, x0); fma4(a2, w0.z, x0); fma4(a3, w0.w, x0);
        fma4(a0, w1.x, x1); fma4(a1, w1.y, x1); fma4(a2, w1.z, x1); fma4(a3, w1.w, x1);
        dn.x += w0.x + w1.x; dn.y += w0.y + w1.y;
        dn.z += w0.z + w1.z; dn.w += w0.w + w1.w;
    }
    for (; i < nE; i += EPW) {
        int2 se0 = se_sorted[b + i];
        float4 w0 = W4[se0.y];
        if (CW) {
            float4 q0 = AS4[se0.x];
            w0.x = expf(leakyf(q0.x + adn.x + w0.x));
            w0.y = expf(leakyf(q0.y + adn.y + w0.y));
            w0.z = expf(leakyf(q0.z + adn.z + w0.z));
            w0.w = expf(leakyf(q0.w + adn.w + w0.w));
        }
        float4 x0 = X4[(size_t)se0.x * CHUNKS + ch];
        fma4(a0, w0.x, x0); fma4(a1, w0.y, x0); fma4(a2, w0.z, x0); fma4(a3, w0.w, x0);
        dn.x += w0.x; dn.y += w0.y; dn.z += w0.z; dn.w += w0.w;
    }
    if (sub == 0) {  // self loop
        float e0 = expf(leakyf(asn.x + adn.x + Sael[0]));
        float e1 = expf(leakyf(asn.y + adn.y + Sael[1]));
        float e2 = expf(leakyf(asn.z + adn.z + Sael[2]));
        float e3 = expf(leakyf(asn.w + adn.w + Sael[3]));
        float4 xs = X4[(size_t)n * CHUNKS + ch];
        fma4(a0, e0, xs); fma4(a1, e1, xs); fma4(a2, e2, xs); fma4(a3, e3, xs);
        dn.x += e0; dn.y += e1; dn.z += e2; dn.w += e3;
    }
#pragma unroll
    for (int mask = CHUNKS; mask < 64; mask <<= 1) {
        a0.x += __shfl_xor(a0.x, mask, 64); a0.y += __shfl_xor(a0.y, mask, 64);
        a0.z += __shfl_xor(a0.z, mask, 64); a0.w += __shfl_xor(a0.w, mask, 64);
        a1.x += __shfl_xor(a1.x, mask, 64); a1.y += __shfl_xor(a1.y, mask, 64);
        a1.z += __shfl_xor(a1.z, mask, 64); a1.w += __shfl_xor(a1.w, mask, 64);
        a2.x += __shfl_xor(a2.x, mask, 64); a2.y += __shfl_xor(a2.y, mask, 64);
        a2.z += __shfl_xor(a2.z, mask, 64); a2.w += __shfl_xor(a2.w, mask, 64);
        a3.x += __shfl_xor(a3.x, mask, 64); a3.y += __shfl_xor(a3.y, mask, 64);
        a3.z += __shfl_xor(a3.z, mask, 64); a3.w += __shfl_xor(a3.w, mask, 64);
        dn.x += __shfl_xor(dn.x, mask, 64); dn.y += __shfl_xor(dn.y, mask, 64);
        dn.z += __shfl_xor(dn.z, mask, 64); dn.w += __shfl_xor(dn.w, mask, 64);
    }
    if (sub == 0) {
        float i0 = 1.f / dn.x, i1 = 1.f / dn.y, i2 = 1.f / dn.z, i3 = 1.f / dn.w;
        float4* agg4 = (float4*)agg;
        size_t base = (size_t)n * 4 * CHUNKS + ch;
        agg4[base]              = make_float4(a0.x * i0, a0.y * i0, a0.z * i0, a0.w * i0);
        agg4[base + CHUNKS]     = make_float4(a1.x * i1, a1.y * i1, a1.z * i1, a1.w * i1);
        agg4[base + 2 * CHUNKS] = make_float4(a2.x * i2, a2.y * i2, a2.z * i2, a2.w * i2);
        agg4[base + 3 * CHUNKS] = make_float4(a3.x * i3, a3.y * i3, a3.z * i3, a3.w * i3);
    }
}

// ---- GEMM: out[M,64] = elu(A[M,K]@B[K,64]+bias); 64-row tiles, reg prefetch ----
template <int K, bool DOATT>
__global__ __launch_bounds__(256) void gemm64_kernel(
    const float* __restrict__ A, const float* __restrict__ B,
    const float* __restrict__ bias, float* __restrict__ out,
    const float* __restrict__ ms_g, const float* __restrict__ md_g,
    float* __restrict__ as_, float* __restrict__ ad_) {
    __shared__ float As[32 * 68];
    __shared__ float Bs[32 * 68];
    __shared__ float msS[256], mdS[256];
    int t = threadIdx.x;
    int tx = t & 15, ty = t >> 4;
    int m_base = blockIdx.x * 64;
    if (DOATT) { msS[t] = ms_g[t]; mdS[t] = md_g[t]; }
    int arow0 = t >> 3, akq0 = (t & 7) * 4;
    int arow1 = (t + 256) >> 3, akq1 = ((t + 256) & 7) * 4;
    int bkr = t >> 4, bnc = (t & 15) * 4;
    int am0 = m_base + arow0, am1 = m_base + arow1;
    float4 fa0, fa1, fb0, fb1;
    fa0 = (am0 < NN) ? *(const float4*)(A + (size_t)am0 * K + akq0) : make_float4(0, 0, 0, 0);
    fa1 = (am1 < NN) ? *(const float4*)(A + (size_t)am1 * K + akq1) : make_float4(0, 0, 0, 0);
    fb0 = *(const float4*)(B + (size_t)bkr * 64 + bnc);
    fb1 = *(const float4*)(B + (size_t)(bkr + 16) * 64 + bnc);
    float acc[4][4] = {};
    for (int k0 = 0;; k0 += 32) {
        As[(akq0 + 0) * 68 + arow0] = fa0.x;
        As[(akq0 + 1) * 68 + arow0] = fa0.y;
        As[(akq0 + 2) * 68 + arow0] = fa0.z;
        As[(akq0 + 3) * 68 + arow0] = fa0.w;
        As[(akq1 + 0) * 68 + arow1] = fa1.x;
        As[(akq1 + 1) * 68 + arow1] = fa1.y;
        As[(akq1 + 2) * 68 + arow1] = fa1.z;
        As[(akq1 + 3) * 68 + arow1] = fa1.w;
        *(float4*)&Bs[bkr * 68 + bnc] = fb0;
        *(float4*)&Bs[(bkr + 16) * 68 + bnc] = fb1;
        __syncthreads();
        bool more = (k0 + 32 < K);
        if (more) {
            int kn = k0 + 32;
            fa0 = (am0 < NN) ? *(const float4*)(A + (size_t)am0 * K + kn + akq0)
                             : make_float4(0, 0, 0, 0);
            fa1 = (am1 < NN) ? *(const float4*)(A + (size_t)am1 * K + kn + akq1)
                             : make_float4(0, 0, 0, 0);
            fb0 = *(const float4*)(B + (size_t)(kn + bkr) * 64 + bnc);
            fb1 = *(const float4*)(B + (size_t)(kn + bkr + 16) * 64 + bnc);
        }
#pragma unroll
        for (int k = 0; k < 32; k++) {
            float4 av = *(const float4*)&As[k * 68 + ty * 4];
            float4 bv = *(const float4*)&Bs[k * 68 + tx * 4];
            float a[4] = {av.x, av.y, av.z, av.w};
            float b[4] = {bv.x, bv.y, bv.z, bv.w};
#pragma unroll
            for (int i = 0; i < 4; i++)
#pragma unroll
                for (int j = 0; j < 4; j++) acc[i][j] += a[i] * b[j];
        }
        if (!more) break;
        __syncthreads();
    }
    float4 bvv = ((const float4*)bias)[tx];
    float o[4][4];
#pragma unroll
    for (int i = 0; i < 4; i++) {
        o[i][0] = eluf(acc[i][0] + bvv.x);
        o[i][1] = eluf(acc[i][1] + bvv.y);
        o[i][2] = eluf(acc[i][2] + bvv.z);
        o[i][3] = eluf(acc[i][3] + bvv.w);
        int m = m_base + ty * 4 + i;
        if (m < NN)
            *(float4*)(out + (size_t)m * 64 + tx * 4) =
                make_float4(o[i][0], o[i][1], o[i][2], o[i][3]);
    }
    if (DOATT) {
        float ps[4][4] = {}, pd[4][4] = {};
#pragma unroll
        for (int i = 0; i < 4; i++)
#pragma unroll
            for (int j = 0; j < 4; j++) {
                float v = o[i][j];
                int kk = (tx * 4 + j) * 4;
#pragma unroll
                for (int h = 0; h < 4; h++) {
                    ps[i][h] += v * msS[kk + h];
                    pd[i][h] += v * mdS[kk + h];
                }
            }
#pragma unroll
        for (int mk = 1; mk < 16; mk <<= 1) {
#pragma unroll
            for (int i = 0; i < 4; i++)
#pragma unroll
                for (int h = 0; h < 4; h++) {
                    ps[i][h] += __shfl_xor(ps[i][h], mk, 64);
                    pd[i][h] += __shfl_xor(pd[i][h], mk, 64);
                }
        }
        if (tx == 0) {
#pragma unroll
            for (int i = 0; i < 4; i++) {
                int m = m_base + ty * 4 + i;
                if (m < NN) {
                    *(float4*)(as_ + (size_t)m * 4) =
                        make_float4(ps[i][0], ps[i][1], ps[i][2], ps[i][3]);
                    *(float4*)(ad_ + (size_t)m * 4) =
                        make_float4(pd[i][0], pd[i][1], pd[i][2], pd[i][3]);
                }
            }
        }
    }
}

// ---- SAGE mean aggregation into AB[:,0:64]; copy h2 into AB[:,64:128] ----
__global__ __launch_bounds__(256) void sage_agg3_kernel(
    const float* __restrict__ h2, const int* __restrict__ eoff,
    const int2* __restrict__ se_sorted, float* __restrict__ AB) {
    int n = blockIdx.x * 16 + (threadIdx.x >> 4);
    if (n >= NN) return;
    int l = threadIdx.x & 15;
    const float4* h24 = (const float4*)h2;
    float4* AB4 = (float4*)AB;
    float ax = 0.f, ay = 0.f, az = 0.f, aw = 0.f;
    int b = eoff[n], e_end = eoff[n + 1];
    int idx = b;
    int stop = b + ((e_end - b) & ~7);
    if (idx < stop) {
        int sreg[8];
#pragma unroll
        for (int u = 0; u < 8; u++) sreg[u] = se_sorted[idx + u].x;
        idx += 8;
        while (true) {
            int sn[8];
            bool more = idx < stop;
            if (more) {
#pragma unroll
                for (int u = 0; u < 8; u++) sn[u] = se_sorted[idx + u].x;
            }
#pragma unroll
            for (int u = 0; u < 8; u++) {
                float4 v = h24[(size_t)sreg[u] * 16 + l];
                ax += v.x; ay += v.y; az += v.z; aw += v.w;
            }
            if (!more) break;
#pragma unroll
            for (int u = 0; u < 8; u++) sreg[u] = sn[u];
            idx += 8;
        }
    }
    for (; idx < e_end; idx++) {
        float4 v0 = h24[(size_t)se_sorted[idx].x * 16 + l];
        ax += v0.x; ay += v0.y; az += v0.z; aw += v0.w;
    }
    float dg = (float)(e_end - b);
    if (dg < 1.f) dg = 1.f;
    float inv = 1.f / dg;
    AB4[(size_t)n * 32 + l] = make_float4(ax * inv, ay * inv, az * inv, aw * inv);
    AB4[(size_t)n * 32 + 16 + l] = h24[(size_t)n * 16 + l];
}

// ---- fused pool + MLP head: one block per graph -> d_out[192] ----
__global__ __launch_bounds__(256) void pool_mlp_kernel(
    const float* __restrict__ h3, const int* __restrict__ goff,
    const float* __restrict__ lin1W, const float* __restrict__ lin1b,
    const float* __restrict__ lin2W, const float* __restrict__ lin2b,
    const float* __restrict__ telW, const float* __restrict__ telb,
    const float* __restrict__ compW, const float* __restrict__ compb,
    const float* __restrict__ pchW, const float* __restrict__ pchb,
    float* __restrict__ out) {
    __shared__ float red[256];
    __shared__ float g[64], G1[64], G2[64];
    int gi = blockIdx.x, t = threadIdx.x;
    int c = t & 63, li = t >> 6;
    int b = goff[gi], e = goff[gi + 1];
    float sum = 0.f;
    for (int r = b + li; r < e; r += 4) sum += h3[(size_t)r * HID + c];
    red[t] = sum;
    __syncthreads();
    if (t < 64) {
        float v = red[t] + red[t + 64] + red[t + 128] + red[t + 192];
        float cntf = (float)(e - b);
        if (cntf < 1.f) cntf = 1.f;
        g[t] = v / cntf;
    }
    __syncthreads();
    {
        float part = 0.f;
#pragma unroll
        for (int k = li * 16; k < li * 16 + 16; k++) part += g[k] * lin1W[k * 64 + c];
        red[t] = part;
        __syncthreads();
        if (t < 64)
            G1[c] = eluf(red[c] + red[c + 64] + red[c + 128] + red[c + 192] + lin1b[c]);
        __syncthreads();
    }
    {
        float part = 0.f;
#pragma unroll
        for (int k = li * 16; k < li * 16 + 16; k++) part += G1[k] * lin2W[k * 64 + c];
        red[t] = part;
        __syncthreads();
        if (t < 64)
            G2[c] = red[c] + red[c + 64] + red[c + 128] + red[c + 192] + lin2b[c];
        __syncthreads();
    }
    if (t < 192) {
        int h = t >> 6, k = t & 63;
        const float* W = (h == 0) ? telW : ((h == 1) ? compW : pchW);
        red[t] = G2[k] * W[k];
    }
    __syncthreads();
    if (t < 3) {
        float acc = 0.f;
        for (int k = 0; k < 64; k++) acc += red[t * 64 + k];
        float bb = (t == 0) ? telb[0] : ((t == 1) ? compb[0] : pchb[0]);
        out[t * 64 + gi] = acc + bb;
    }
}

extern "C" void kernel_launch(void* const* d_in, const int* in_sizes, int n_in,
                              void* d_out, int out_size, void* d_ws, size_t ws_size,
                              hipStream_t stream) {
    const float* x        = (const float*)d_in[0];
    const float* EA       = (const float*)d_in[1];
    const float* node_emb = (const float*)d_in[2];
    const float* edge_W   = (const float*)d_in[3];
    const float* edge_b   = (const float*)d_in[4];
    const float* W1       = (const float*)d_in[5];
    const float* as1      = (const float*)d_in[6];
    const float* ad1      = (const float*)d_in[7];
    const float* ae1      = (const float*)d_in[8];
    const float* leW1     = (const float*)d_in[9];
    const float* b1       = (const float*)d_in[10];
    const float* W2       = (const float*)d_in[11];
    const float* as2      = (const float*)d_in[12];
    const float* ad2      = (const float*)d_in[13];
    const float* ae2      = (const float*)d_in[14];
    const float* leW2     = (const float*)d_in[15];
    const float* b2       = (const float*)d_in[16];
    const float* sage_Wl  = (const float*)d_in[17];
    const float* sage_bl  = (const float*)d_in[18];
    const float* sage_Wr  = (const float*)d_in[19];
    const float* lin1_W   = (const float*)d_in[20];
    const float* lin1_b   = (const float*)d_in[21];
    const float* lin2_W   = (const float*)d_in[22];
    const float* lin2_b   = (const float*)d_in[23];
    const float* tel_W    = (const float*)d_in[24];
    const float* tel_b    = (const float*)d_in[25];
    const float* comp_W   = (const float*)d_in[26];
    const float* comp_b   = (const float*)d_in[27];
    const float* pch_W    = (const float*)d_in[28];
    const float* pch_b    = (const float*)d_in[29];
    const int* edge_index = (const int*)d_in[30];
    const int* batch      = (const int*)d_in[31];
    const int* node_type  = (const int*)d_in[32];
    float* outp = (float*)d_out;

    const int* srcp = edge_index;
    const int* dstp = edge_index + NE;

    float* wf = (float*)d_ws;
    constexpr size_t OFF_H0    = 0;                               // N*128 (h3 aliases later)
    constexpr size_t OFF_AGG   = OFF_H0 + (size_t)NN * 128;       // N*512 (agg1/agg2/AB alias)
    constexpr size_t OFF_H1    = OFF_AGG + (size_t)NN * 512;      // N*64
    constexpr size_t OFF_H2    = OFF_H1 + (size_t)NN * 64;        // N*64
    constexpr size_t OFF_SC    = OFF_H2 + (size_t)NN * 64;        // E*4
    constexpr size_t OFF_AE2   = OFF_SC + (size_t)NE * 4;         // E*4
    constexpr size_t OFF_AS    = OFF_AE2 + (size_t)NE * 4;        // N*4
    constexpr size_t OFF_AD    = OFF_AS + (size_t)NN * 4;         // N*4
    constexpr size_t OFF_SMALL = OFF_AD + (size_t)NN * 4;         // 4096
    constexpr size_t OFF_WC1   = OFF_SMALL + 4096;                // 32768
    constexpr size_t OFF_WC2   = OFF_WC1 + 32768;                 // 16384
    constexpr size_t OFF_B128  = OFF_WC2 + 16384;                 // 8192
    constexpr size_t F_TOTAL   = OFF_B128 + 8192;

    int* wi         = (int*)(wf + F_TOTAL);
    int* cnt        = wi;                        // N
    int* pos        = wi + NN;                   // N   (adjacent: one memset)
    int* eoff       = pos + NN;                  // N+1
    int2* se_sorted = (int2*)(eoff + (NN + 2));  // E int2 (8B-aligned: offset even)
    int* goff       = (int*)(se_sorted + NE);    // NG+1
    int* bsum       = goff + (NG + 1);           // 64
    int* boff       = bsum + 64;                 // 64

    float* h0    = wf + OFF_H0;
    float* aggb  = wf + OFF_AGG;
    float* h1    = wf + OFF_H1;
    float* h2    = wf + OFF_H2;
    float* sc    = wf + OFF_SC;
    float* ae2s  = wf + OFF_AE2;
    float* as_   = wf + OFF_AS;
    float* ad_   = wf + OFF_AD;
    float* S     = wf + OFF_SMALL;
    float* WC1   = wf + OFF_WC1;
    float* WC2   = wf + OFF_WC2;
    float* B128  = wf + OFF_B128;
    float* AB    = wf + OFF_AGG;                 // alias (agg dead after gemm L2)
    float* h3    = wf + OFF_H0;                  // alias (h0 dead after agg L1)

    hipMemsetAsync(S + S_MEANEA, 0, 16 * sizeof(float), stream);
    hipMemsetAsync(cnt, 0, 2 * NN * sizeof(int), stream);   // cnt + pos

    count_mean_kernel<<<(NE + 511) / 512, 256, 0, stream>>>(dstp, EA, cnt, S);
    prep_weights_kernel<<<224, 256, 0, stream>>>(W1, W2, sage_Wl, sage_Wr, WC1, WC2, B128);
    prep_small_kernel<<<1, 256, 0, stream>>>(W1, as1, ad1, ae1, leW1,
                                             W2, as2, ad2, ae2, leW2,
                                             edge_W, edge_b, S);
    {
        int nb = (NN + 1023) / 1024;  // 30
        scan_blocks_kernel<<<nb, 1024, 0, stream>>>(cnt, eoff, bsum);
        scan_tops_kernel<<<1, 64, 0, stream>>>(bsum, boff, nb);
        scan_add_kernel<<<(NN + 255) / 256, 256, 0, stream>>>(boff, eoff);
    }
    attn_h0_kernel<<<(NN + 63) / 64, 256, 0, stream>>>(x, node_emb, node_type, S, h0, as_, ad_);
    goff_bs_kernel<<<1, 128, 0, stream>>>(batch, goff);
    scatter_score_kernel<<<(NE + 255) / 256, 256, 0, stream>>>(
        srcp, dstp, EA, S, as_, ad_, eoff, pos, se_sorted, sc, ae2s);

    // ----- GAT layer 1 -----
    agg_gat_kernel<128, false><<<(NN + 3) / 4, 256, 0, stream>>>(
        eoff, se_sorted, sc, h0, as_, ad_, S + S_AEL1, aggb);
    gemm64_kernel<512, true><<<(NN + 63) / 64, 256, 0, stream>>>(
        aggb, WC1, b1, h1, S + S_MS2, S + S_MD2, as_, ad_);

    // ----- GAT layer 2 -----
    agg_gat_kernel<64, true><<<(NN + 3) / 4, 256, 0, stream>>>(
        eoff, se_sorted, ae2s, h1, as_, ad_, S + S_AEL2, aggb);
    gemm64_kernel<256, false><<<(NN + 63) / 64, 256, 0, stream>>>(
        aggb, WC2, b2, h2, nullptr, nullptr, nullptr, nullptr);

    // ----- SAGE -----
    sage_agg3_kernel<<<(NN + 15) / 16, 256, 0, stream>>>(h2, eoff, se_sorted, AB);
    gemm64_kernel<128, false><<<(NN + 63) / 64, 256, 0, stream>>>(
        AB, B128, sage_bl, h3, nullptr, nullptr, nullptr, nullptr);

    // ----- fused pool + MLP head -----
    pool_mlp_kernel<<<NG, 256, 0, stream>>>(h3, goff, lin1_W, lin1_b, lin2_W, lin2_b,
                                            tel_W, tel_b, comp_W, comp_b, pch_W, pch_b, outp);
}

// Round 10
// 438.882 us; speedup vs baseline: 1.0567x; 1.0567x over previous
//
#include <hip/hip_runtime.h>
#include <math.h>

#define NN 30000          // nodes
#define NE 480000         // edges
#define FEA 16            // edge feature dim
#define HID 64
#define NG 64             // graphs
#define LEAKK 0.2f

// ---- small-constant region layout (float offsets) ----
#define S_MEANEA 0    // 16
#define S_KF1    16   // 64  (K1 [16,4])
#define S_C1     80   // 4
#define S_AEL1   84   // 4
#define S_KF2    88   // 64
#define S_C2     152  // 4
#define S_AEL2   156  // 4
#define S_MS1    160  // 512 (Ms1 [128,4])
#define S_MD1    672  // 512
#define S_MS2    1184 // 256 (Ms2 [64,4])
#define S_MD2    1440 // 256

__device__ __forceinline__ float eluf(float v) { return v > 0.f ? v : expm1f(v); }
__device__ __forceinline__ float leakyf(float v) { return v >= 0.f ? v : LEAKK * v; }
__device__ __forceinline__ void fma4(float4& a, float w, const float4& x) {
    a.x += w * x.x; a.y += w * x.y; a.z += w * x.z; a.w += w * x.w;
}

// ---- count (CSR degree) + mean of edge_attr ----
__global__ __launch_bounds__(256) void count_mean_kernel(
    const int* __restrict__ dst, const float* __restrict__ EA,
    int* __restrict__ cnt, float* __restrict__ S) {
    __shared__ float red[1024];
    int t = threadIdx.x;
    int base = blockIdx.x * 512;
#pragma unroll
    for (int i = 0; i < 2; i++) {
        int e = base + i * 256 + t;
        if (e < NE) atomicAdd(&cnt[dst[e]], 1);
    }
    int c4 = t & 3;
    int rbase = base + (t >> 2);
    float4 acc = {0, 0, 0, 0};
#pragma unroll
    for (int i = 0; i < 8; i++) {
        int r = rbase + i * 64;
        if (r < NE) {
            float4 v = *(const float4*)(EA + (size_t)r * FEA + c4 * 4);
            acc.x += v.x; acc.y += v.y; acc.z += v.z; acc.w += v.w;
        }
    }
    *(float4*)&red[t * 4] = acc;
    __syncthreads();
    if (t < 16) {
        int grp = t >> 2;
        int comp = t & 3;
        float sum = 0.f;
        for (int j = 0; j < 64; j++) sum += red[(grp + 4 * j) * 4 + comp];
        atomicAdd(&S[S_MEANEA + grp * 4 + comp], sum);
    }
}

// ---- parallel weight-layout build:
//      WC1' [320,64] = [W1_x folded (256) ; emb@W1_emb folded (64)], WC2, B128 ----
__global__ void prep_weights_kernel(const float* __restrict__ W1, const float* __restrict__ W2,
                                    const float* __restrict__ Wl, const float* __restrict__ Wr,
                                    const float* __restrict__ emb,
                                    float* __restrict__ WC1, float* __restrict__ WC2,
                                    float* __restrict__ B128) {
    int i = blockIdx.x * 256 + threadIdx.x;
    if (i < 16384) {            // x part: rows h*64+k (k = x col)
        int hk = i >> 6, c = i & 63;
        int h = hk >> 6, k = hk & 63;
        WC1[i] = 0.25f * W1[k * 256 + h * 64 + c];
    } else if (i < 20480) {     // emb part: rows 256 + h*16 + tau
        int j2 = i - 16384;
        int r2 = j2 >> 6, c = j2 & 63;
        int h = r2 >> 4, tau = r2 & 15;
        float v = 0.f;
        for (int j = 0; j < 64; j++)
            v += emb[tau * 64 + j] * W1[(64 + j) * 256 + h * 64 + c];
        WC1[i] = 0.25f * v;
    } else if (i < 36864) {
        int j = i - 20480;
        int hk = j >> 6, c = j & 63;
        int h = hk >> 6, k = hk & 63;
        WC2[j] = 0.25f * W2[k * 256 + h * 64 + c];
    } else if (i < 45056) {
        int j = i - 36864;
        int k = j >> 6, c = j & 63;
        B128[j] = (k < 64) ? Wl[k * 64 + c] : Wr[(k - 64) * 64 + c];
    }
}

// ---- fold attention weights into small matrices ----
__global__ void prep_small_kernel(
    const float* __restrict__ W1, const float* __restrict__ as1, const float* __restrict__ ad1,
    const float* __restrict__ ae1, const float* __restrict__ leW1,
    const float* __restrict__ W2, const float* __restrict__ as2, const float* __restrict__ ad2,
    const float* __restrict__ ae2, const float* __restrict__ leW2,
    const float* __restrict__ edge_W, const float* __restrict__ edge_b,
    float* __restrict__ S) {
    __shared__ float M1[256], M2[256], meh[64];
    int t = threadIdx.x;
    if (t < 16) S[S_MEANEA + t] *= (1.0f / (float)NE);
    __syncthreads();
    {
        int k = t >> 2, h = t & 3;
        float m1 = 0.f, m2 = 0.f;
        for (int c = 0; c < 64; c++) {
            m1 += leW1[k * 256 + h * 64 + c] * ae1[h * 64 + c];
            m2 += leW2[k * 256 + h * 64 + c] * ae2[h * 64 + c];
        }
        M1[t] = m1; M2[t] = m2;
    }
    if (t < 64) {
        float v = edge_b[t];
        for (int f = 0; f < FEA; f++) v += S[S_MEANEA + f] * edge_W[f * 64 + t];
        meh[t] = v;
    }
    __syncthreads();
    if (t < 64) {
        int f = t >> 2, h = t & 3;
        float k1 = 0.f, k2 = 0.f;
        for (int k = 0; k < 64; k++) {
            k1 += edge_W[f * 64 + k] * M1[k * 4 + h];
            k2 += edge_W[f * 64 + k] * M2[k * 4 + h];
        }
        S[S_KF1 + t] = k1; S[S_KF2 + t] = k2;
    } else if (t < 68) {
        int h = t - 64;
        float c1 = 0.f, c2 = 0.f, a1 = 0.f, a2 = 0.f;
        for (int k = 0; k < 64; k++) {
            c1 += edge_b[k] * M1[k * 4 + h];
            c2 += edge_b[k] * M2[k * 4 + h];
            a1 += meh[k] * M1[k * 4 + h];
            a2 += meh[k] * M2[k * 4 + h];
        }
        S[S_C1 + h] = c1; S[S_C2 + h] = c2;
        S[S_AEL1 + h] = a1; S[S_AEL2 + h] = a2;
    }
    for (int i = t; i < 512; i += 256) {
        int k = i >> 2, h = i & 3;
        float s = 0.f, d = 0.f;
        for (int c = 0; c < 64; c++) {
            float w = W1[k * 256 + h * 64 + c];
            s += w * as1[h * 64 + c];
            d += w * ad1[h * 64 + c];
        }
        S[S_MS1 + i] = s; S[S_MD1 + i] = d;
    }
    for (int i = t; i < 256; i += 256) {
        int k = i >> 2, h = i & 3;
        float s = 0.f, d = 0.f;
        for (int c = 0; c < 64; c++) {
            float w = W2[k * 256 + h * 64 + c];
            s += w * as2[h * 64 + c];
            d += w * ad2[h * 64 + c];
        }
        S[S_MS2 + i] = s; S[S_MD2 + i] = d;
    }
}

// ---- layer-1 a_s/a_d from [x | emb[type]] (h0 NOT materialized) ----
__global__ __launch_bounds__(256) void attn_h0_kernel(
    const float* __restrict__ x, const float* __restrict__ node_emb,
    const int* __restrict__ node_type, const float* __restrict__ S,
    float* __restrict__ as_, float* __restrict__ ad_) {
    __shared__ float xt[64 * 132];
    __shared__ float ms[512], md[512];
    __shared__ int ntS[64];
    int t = threadIdx.x;
    int n0 = blockIdx.x * 64;
    if (t < 64) {
        int n = n0 + t;
        ntS[t] = (n < NN) ? node_type[n] : 0;
    }
    for (int i = t; i < 512; i += 256) { ms[i] = S[S_MS1 + i]; md[i] = S[S_MD1 + i]; }
    __syncthreads();
    for (int i = t; i < 1024; i += 256) {
        int r = i >> 4, c4 = (i & 15) * 4;
        int n = n0 + r;
        float4 f = {0, 0, 0, 0};
        if (n < NN) f = *(const float4*)(x + (size_t)n * 64 + c4);
        *(float4*)&xt[r * 132 + c4] = f;
    }
    for (int i = t; i < 1024; i += 256) {
        int r = i >> 4, c4 = (i & 15) * 4;
        int n = n0 + r;
        float4 f = {0, 0, 0, 0};
        if (n < NN) f = *(const float4*)(node_emb + (size_t)ntS[r] * 64 + c4);
        *(float4*)&xt[r * 132 + 64 + c4] = f;
    }
    __syncthreads();
    int r = t >> 2, h = t & 3;
    float s = 0.f, d = 0.f;
#pragma unroll 8
    for (int k = 0; k < 128; k++) {
        float xv = xt[r * 132 + k];
        s += xv * ms[k * 4 + h];
        d += xv * md[k * 4 + h];
    }
    int n = n0 + r;
    if (n < NN) { as_[n * 4 + h] = s; ad_[n * 4 + h] = d; }
}

// ---- 3-kernel decoupled scan ----
__global__ void scan_blocks_kernel(const int* __restrict__ cnt, int* __restrict__ eoff,
                                   int* __restrict__ bsum) {
    __shared__ int wsum[16];
    int t = threadIdx.x;
    int i = blockIdx.x * 1024 + t;
    int v = (i < NN) ? cnt[i] : 0;
    int lane = t & 63;
    int incl = v;
#pragma unroll
    for (int ofs = 1; ofs < 64; ofs <<= 1) {
        int u = __shfl_up(incl, ofs, 64);
        if (lane >= ofs) incl += u;
    }
    int wid = t >> 6;
    if (lane == 63) wsum[wid] = incl;
    __syncthreads();
    if (t < 16) {
        int s = wsum[t];
#pragma unroll
        for (int ofs = 1; ofs < 16; ofs <<= 1) {
            int u = __shfl_up(s, ofs, 64);
            if (t >= ofs) s += u;
        }
        wsum[t] = s;
    }
    __syncthreads();
    int excl = incl - v + (wid > 0 ? wsum[wid - 1] : 0);
    if (i < NN) eoff[i] = excl;
    if (t == 1023) bsum[blockIdx.x] = excl + v;
}

__global__ void scan_tops_kernel(const int* __restrict__ bsum, int* __restrict__ boff, int nb) {
    int t = threadIdx.x; // 64
    int v = (t < nb) ? bsum[t] : 0;
    int incl = v;
#pragma unroll
    for (int ofs = 1; ofs < 64; ofs <<= 1) {
        int u = __shfl_up(incl, ofs, 64);
        if (t >= ofs) incl += u;
    }
    boff[t] = incl - v;
}

__global__ void scan_add_kernel(const int* __restrict__ boff, int* __restrict__ eoff) {
    int i = blockIdx.x * 256 + threadIdx.x;
    if (i < NN) eoff[i] += boff[i >> 10];
    if (i == 0) eoff[NN] = NE;
}

// ---- fused scatter + scoring: coalesced weight writes at [e]; scatter int2{s, e|type<<24} ----
__global__ void scatter_score_kernel(const int* __restrict__ src, const int* __restrict__ dst,
                                     const float* __restrict__ EA, const float* __restrict__ S,
                                     const float* __restrict__ as_, const float* __restrict__ ad_,
                                     const int* __restrict__ node_type,
                                     const int* __restrict__ eoff, int* __restrict__ pos,
                                     int2* __restrict__ se_sorted,
                                     float* __restrict__ sc1, float* __restrict__ ae2s) {
    int e = blockIdx.x * 256 + threadIdx.x;
    if (e >= NE) return;
    int s = src[e], d = dst[e];
    float a1[4], a2[4];
#pragma unroll
    for (int h = 0; h < 4; h++) { a1[h] = S[S_C1 + h]; a2[h] = S[S_C2 + h]; }
    const float4* EA4 = (const float4*)(EA + (size_t)e * FEA);
#pragma unroll
    for (int q = 0; q < 4; q++) {
        float4 v = EA4[q];
        float vv[4] = {v.x, v.y, v.z, v.w};
#pragma unroll
        for (int j = 0; j < 4; j++) {
            int f = q * 4 + j;
#pragma unroll
            for (int h = 0; h < 4; h++) {
                a1[h] += vv[j] * S[S_KF1 + f * 4 + h];
                a2[h] += vv[j] * S[S_KF2 + f * 4 + h];
            }
        }
    }
    ((float4*)ae2s)[e] = make_float4(a2[0], a2[1], a2[2], a2[3]);
    float4 asv = ((const float4*)as_)[s];
    float4 adv = ((const float4*)ad_)[d];
    float4 r;
    r.x = expf(leakyf(asv.x + adv.x + a1[0]));
    r.y = expf(leakyf(asv.y + adv.y + a1[1]));
    r.z = expf(leakyf(asv.z + adv.z + a1[2]));
    r.w = expf(leakyf(asv.w + adv.w + a1[3]));
    ((float4*)sc1)[e] = r;
    int ty = node_type[s];
    int p = atomicAdd(&pos[d], 1);
    se_sorted[eoff[d] + p] = make_int2(s, e | (ty << 24));
}

// ---- goff via binary search over sorted batch ----
__global__ void goff_bs_kernel(const int* __restrict__ batch, int* __restrict__ goff) {
    int g = threadIdx.x;
    if (g > NG) return;
    int lo = 0, hi = NN;
    while (lo < hi) {
        int mid = (lo + hi) >> 1;
        if (batch[mid] < g) lo = mid + 1; else hi = mid;
    }
    goff[g] = lo;
}

// ---- layer-1 GAT aggregation: gather x rows (256B) + per-type weight histogram ----
// out A[n, 320] = [aggx(4x64)/den | tw(4x16)/den]
__global__ __launch_bounds__(256) void agg_gat1_kernel(
    const int* __restrict__ eoff, const int2* __restrict__ se_sorted,
    const float* __restrict__ sc1, const float* __restrict__ x,
    const int* __restrict__ node_type,
    const float* __restrict__ as_, const float* __restrict__ ad_,
    const float* __restrict__ Sael, float* __restrict__ agg) {
    int n = blockIdx.x * 4 + (threadIdx.x >> 6);
    if (n >= NN) return;
    int lane = threadIdx.x & 63;
    int sub = lane >> 4, ch = lane & 15;
    const float4* X4 = (const float4*)x;
    const float4* W4 = (const float4*)sc1;
    float4 asn = ((const float4*)as_)[n];
    float4 adn = ((const float4*)ad_)[n];
    float4 a0 = {0, 0, 0, 0}, a1 = a0, a2 = a0, a3 = a0, dn = a0, tw = a0;
    int b = eoff[n], e_end = eoff[n + 1];
    int nE = e_end - b;
    int i = sub;
    for (; i + 4 < nE; i += 8) {
        int2 se0 = se_sorted[b + i], se1 = se_sorted[b + i + 4];
        int e0 = se0.y & 0xFFFFFF, t0 = se0.y >> 24;
        int e1 = se1.y & 0xFFFFFF, t1 = se1.y >> 24;
        float4 w0 = W4[e0], w1 = W4[e1];
        float4 x0 = X4[(size_t)se0.x * 16 + ch];
        float4 x1 = X4[(size_t)se1.x * 16 + ch];
        fma4(a0, w0.x, x0); fma4(a1, w0.y, x0); fma4(a2, w0.z, x0); fma4(a3, w0.w, x0);
        fma4(a0, w1.x, x1); fma4(a1, w1.y, x1); fma4(a2, w1.z, x1); fma4(a3, w1.w, x1);
        dn.x += w0.x + w1.x; dn.y += w0.y + w1.y;
        dn.z += w0.z + w1.z; dn.w += w0.w + w1.w;
        if (ch == t0) { tw.x += w0.x; tw.y += w0.y; tw.z += w0.z; tw.w += w0.w; }
        if (ch == t1) { tw.x += w1.x; tw.y += w1.y; tw.z += w1.z; tw.w += w1.w; }
    }
    for (; i < nE; i += 4) {
        int2 se0 = se_sorted[b + i];
        int e0 = se0.y & 0xFFFFFF, t0 = se0.y >> 24;
        float4 w0 = W4[e0];
        float4 x0 = X4[(size_t)se0.x * 16 + ch];
        fma4(a0, w0.x, x0); fma4(a1, w0.y, x0); fma4(a2, w0.z, x0); fma4(a3, w0.w, x0);
        dn.x += w0.x; dn.y += w0.y; dn.z += w0.z; dn.w += w0.w;
        if (ch == t0) { tw.x += w0.x; tw.y += w0.y; tw.z += w0.z; tw.w += w0.w; }
    }
    if (sub == 0) {  // self loop
        float e0 = expf(leakyf(asn.x + adn.x + Sael[0]));
        float e1 = expf(leakyf(asn.y + adn.y + Sael[1]));
        float e2 = expf(leakyf(asn.z + adn.z + Sael[2]));
        float e3 = expf(leakyf(asn.w + adn.w + Sael[3]));
        float4 xs = X4[(size_t)n * 16 + ch];
        fma4(a0, e0, xs); fma4(a1, e1, xs); fma4(a2, e2, xs); fma4(a3, e3, xs);
        dn.x += e0; dn.y += e1; dn.z += e2; dn.w += e3;
        int tn = node_type[n];
        if (ch == tn) { tw.x += e0; tw.y += e1; tw.z += e2; tw.w += e3; }
    }
#pragma unroll
    for (int mask = 16; mask < 64; mask <<= 1) {
        a0.x += __shfl_xor(a0.x, mask, 64); a0.y += __shfl_xor(a0.y, mask, 64);
        a0.z += __shfl_xor(a0.z, mask, 64); a0.w += __shfl_xor(a0.w, mask, 64);
        a1.x += __shfl_xor(a1.x, mask, 64); a1.y += __shfl_xor(a1.y, mask, 64);
        a1.z += __shfl_xor(a1.z, mask, 64); a1.w += __shfl_xor(a1.w, mask, 64);
        a2.x += __shfl_xor(a2.x, mask, 64); a2.y += __shfl_xor(a2.y, mask, 64);
        a2.z += __shfl_xor(a2.z, mask, 64); a2.w += __shfl_xor(a2.w, mask, 64);
        a3.x += __shfl_xor(a3.x, mask, 64); a3.y += __shfl_xor(a3.y, mask, 64);
        a3.z += __shfl_xor(a3.z, mask, 64); a3.w += __shfl_xor(a3.w, mask, 64);
        dn.x += __shfl_xor(dn.x, mask, 64); dn.y += __shfl_xor(dn.y, mask, 64);
        dn.z += __shfl_xor(dn.z, mask, 64); dn.w += __shfl_xor(dn.w, mask, 64);
        tw.x += __shfl_xor(tw.x, mask, 64); tw.y += __shfl_xor(tw.y, mask, 64);
        tw.z += __shfl_xor(tw.z, mask, 64); tw.w += __shfl_xor(tw.w, mask, 64);
    }
    if (sub == 0) {
        float i0 = 1.f / dn.x, i1 = 1.f / dn.y, i2 = 1.f / dn.z, i3 = 1.f / dn.w;
        float* A = agg + (size_t)n * 320;
        float4* A4 = (float4*)A;
        A4[ch]      = make_float4(a0.x * i0, a0.y * i0, a0.z * i0, a0.w * i0);
        A4[16 + ch] = make_float4(a1.x * i1, a1.y * i1, a1.z * i1, a1.w * i1);
        A4[32 + ch] = make_float4(a2.x * i2, a2.y * i2, a2.z * i2, a2.w * i2);
        A4[48 + ch] = make_float4(a3.x * i3, a3.y * i3, a3.z * i3, a3.w * i3);
        A[256 + ch]      = tw.x * i0;
        A[256 + 16 + ch] = tw.y * i1;
        A[256 + 32 + ch] = tw.z * i2;
        A[256 + 48 + ch] = tw.w * i3;
    }
}

// ---- layer-2 GAT aggregation (compute-weights in loop) ----
__global__ __launch_bounds__(256) void agg_gat2_kernel(
    const int* __restrict__ eoff, const int2* __restrict__ se_sorted,
    const float* __restrict__ ae2s, const float* __restrict__ X,
    const float* __restrict__ as_, const float* __restrict__ ad_,
    const float* __restrict__ Sael, float* __restrict__ agg) {
    int n = blockIdx.x * 4 + (threadIdx.x >> 6);
    if (n >= NN) return;
    int lane = threadIdx.x & 63;
    int sub = lane >> 4, ch = lane & 15;
    const float4* X4 = (const float4*)X;
    const float4* W4 = (const float4*)ae2s;
    const float4* AS4 = (const float4*)as_;
    float4 asn = AS4[n];
    float4 adn = ((const float4*)ad_)[n];
    float4 a0 = {0, 0, 0, 0}, a1 = a0, a2 = a0, a3 = a0, dn = a0;
    int b = eoff[n], e = eoff[n + 1];
    int nE = e - b;
    int i = sub;
    for (; i + 4 < nE; i += 8) {
        int2 se0 = se_sorted[b + i], se1 = se_sorted[b + i + 4];
        float4 w0 = W4[se0.y & 0xFFFFFF], w1 = W4[se1.y & 0xFFFFFF];
        float4 q0 = AS4[se0.x], q1 = AS4[se1.x];
        w0.x = expf(leakyf(q0.x + adn.x + w0.x));
        w0.y = expf(leakyf(q0.y + adn.y + w0.y));
        w0.z = expf(leakyf(q0.z + adn.z + w0.z));
        w0.w = expf(leakyf(q0.w + adn.w + w0.w));
        w1.x = expf(leakyf(q1.x + adn.x + w1.x));
        w1.y = expf(leakyf(q1.y + adn.y + w1.y));
        w1.z = expf(leakyf(q1.z + adn.z + w1.z));
        w1.w = expf(leakyf(q1.w + adn.w + w1.w));
        float4 x0 = X4[(size_t)se0.x * 16 + ch];
        float4 x1 = X4[(size_t)se1.x * 16 + ch];
        fma4(a0, w0.x, x0); fma4(a1, w0.y, x0); fma4(a2, w0.z, x0); fma4(a3, w0.w, x0);
        fma4(a0, w1.x, x1); fma4(a1, w1.y, x1); fma4(a2, w1.z, x1); fma4(a3, w1.w, x1);
        dn.x += w0.x + w1.x; dn.y += w0.y + w1.y;
        dn.z += w0.z + w1.z; dn.w += w0.w + w1.w;
    }
    for (; i < nE; i += 4) {
        int2 se0 = se_sorted[b + i];
        float4 w0 = W4[se0.y & 0xFFFFFF];
        float4 q0 = AS4[se0.x];
        w0.x = expf(leakyf(q0.x + adn.x + w0.x));
        w0.y = expf(leakyf(q0.y + adn.y + w0.y));
        w0.z = expf(leakyf(q0.z + adn.z + w0.z));
        w0.w = expf(leakyf(q0.w + adn.w + w0.w));
        float4 x0 = X4[(size_t)se0.x * 16 + ch];
        fma4(a0, w0.x, x0); fma4(a1, w0.y, x0); fma4(a2, w0.z, x0); fma4(a3, w0.w, x0);
        dn.x += w0.x; dn.y += w0.y; dn.z += w0.z; dn.w += w0.w;
    }
    if (sub == 0) {  // self loop
        float e0 = expf(leakyf(asn.x + adn.x + Sael[0]));
        float e1 = expf(leakyf(asn.y + adn.y + Sael[1]));
        float e2 = expf(leakyf(asn.z + adn.z + Sael[2]));
        float e3 = expf(leakyf(asn.w + adn.w + Sael[3]));
        float4 xs = X4[(size_t)n * 16 + ch];
        fma4(a0, e0, xs); fma4(a1, e1, xs); fma4(a2, e2, xs); fma4(a3, e3, xs);
        dn.x += e0; dn.y += e1; dn.z += e2; dn.w += e3;
    }
#pragma unroll
    for (int mask = 16; mask < 64; mask <<= 1) {
        a0.x += __shfl_xor(a0.x, mask, 64); a0.y += __shfl_xor(a0.y, mask, 64);
        a0.z += __shfl_xor(a0.z, mask, 64); a0.w += __shfl_xor(a0.w, mask, 64);
        a1.x += __shfl_xor(a1.x, mask, 64); a1.y += __shfl_xor(a1.y, mask, 64);
        a1.z += __shfl_xor(a1.z, mask, 64); a1.w += __shfl_xor(a1.w, mask, 64);
        a2.x += __shfl_xor(a2.x, mask, 64); a2.y += __shfl_xor(a2.y, mask, 64);
        a2.z += __shfl_xor(a2.z, mask, 64); a2.w += __shfl_xor(a2.w, mask, 64);
        a3.x += __shfl_xor(a3.x, mask, 64); a3.y += __shfl_xor(a3.y, mask, 64);
        a3.z += __shfl_xor(a3.z, mask, 64); a3.w += __shfl_xor(a3.w, mask, 64);
        dn.x += __shfl_xor(dn.x, mask, 64); dn.y += __shfl_xor(dn.y, mask, 64);
        dn.z += __shfl_xor(dn.z, mask, 64); dn.w += __shfl_xor(dn.w, mask, 64);
    }
    if (sub == 0) {
        float i0 = 1.f / dn.x, i1 = 1.f / dn.y, i2 = 1.f / dn.z, i3 = 1.f / dn.w;
        float4* agg4 = (float4*)(agg + (size_t)n * 256);
        agg4[ch]      = make_float4(a0.x * i0, a0.y * i0, a0.z * i0, a0.w * i0);
        agg4[16 + ch] = make_float4(a1.x * i1, a1.y * i1, a1.z * i1, a1.w * i1);
        agg4[32 + ch] = make_float4(a2.x * i2, a2.y * i2, a2.z * i2, a2.w * i2);
        agg4[48 + ch] = make_float4(a3.x * i3, a3.y * i3, a3.z * i3, a3.w * i3);
    }
}

// ---- GEMM: out[M,64] = elu(A[M,K]@B[K,64]+bias); 64-row tiles, reg prefetch ----
template <int K, bool DOATT>
__global__ __launch_bounds__(256) void gemm64_kernel(
    const float* __restrict__ A, const float* __restrict__ B,
    const float* __restrict__ bias, float* __restrict__ out,
    const float* __restrict__ ms_g, const float* __restrict__ md_g,
    float* __restrict__ as_, float* __restrict__ ad_) {
    __shared__ float As[32 * 68];
    __shared__ float Bs[32 * 68];
    __shared__ float msS[256], mdS[256];
    int t = threadIdx.x;
    int tx = t & 15, ty = t >> 4;
    int m_base = blockIdx.x * 64;
    if (DOATT) { msS[t] = ms_g[t]; mdS[t] = md_g[t]; }
    int arow0 = t >> 3, akq0 = (t & 7) * 4;
    int arow1 = (t + 256) >> 3, akq1 = ((t + 256) & 7) * 4;
    int bkr = t >> 4, bnc = (t & 15) * 4;
    int am0 = m_base + arow0, am1 = m_base + arow1;
    float4 fa0, fa1, fb0, fb1;
    fa0 = (am0 < NN) ? *(const float4*)(A + (size_t)am0 * K + akq0) : make_float4(0, 0, 0, 0);
    fa1 = (am1 < NN) ? *(const float4*)(A + (size_t)am1 * K + akq1) : make_float4(0, 0, 0, 0);
    fb0 = *(const float4*)(B + (size_t)bkr * 64 + bnc);
    fb1 = *(const float4*)(B + (size_t)(bkr + 16) * 64 + bnc);
    float acc[4][4] = {};
    for (int k0 = 0;; k0 += 32) {
        As[(akq0 + 0) * 68 + arow0] = fa0.x;
        As[(akq0 + 1) * 68 + arow0] = fa0.y;
        As[(akq0 + 2) * 68 + arow0] = fa0.z;
        As[(akq0 + 3) * 68 + arow0] = fa0.w;
        As[(akq1 + 0) * 68 + arow1] = fa1.x;
        As[(akq1 + 1) * 68 + arow1] = fa1.y;
        As[(akq1 + 2) * 68 + arow1] = fa1.z;
        As[(akq1 + 3) * 68 + arow1] = fa1.w;
        *(float4*)&Bs[bkr * 68 + bnc] = fb0;
        *(float4*)&Bs[(bkr + 16) * 68 + bnc] = fb1;
        __syncthreads();
        bool more = (k0 + 32 < K);
        if (more) {
            int kn = k0 + 32;
            fa0 = (am0 < NN) ? *(const float4*)(A + (size_t)am0 * K + kn + akq0)
                             : make_float4(0, 0, 0, 0);
            fa1 = (am1 < NN) ? *(const float4*)(A + (size_t)am1 * K + kn + akq1)
                             : make_float4(0, 0, 0, 0);
            fb0 = *(const float4*)(B + (size_t)(kn + bkr) * 64 + bnc);
            fb1 = *(const float4*)(B + (size_t)(kn + bkr + 16) * 64 + bnc);
        }
#pragma unroll
        for (int k = 0; k < 32; k++) {
            float4 av = *(const float4*)&As[k * 68 + ty * 4];
            float4 bv = *(const float4*)&Bs[k * 68 + tx * 4];
            float a[4] = {av.x, av.y, av.z, av.w};
            float b[4] = {bv.x, bv.y, bv.z, bv.w};
#pragma unroll
            for (int i = 0; i < 4; i++)
#pragma unroll
                for (int j = 0; j < 4; j++) acc[i][j] += a[i] * b[j];
        }
        if (!more) break;
        __syncthreads();
    }
    float4 bvv = ((const float4*)bias)[tx];
    float o[4][4];
#pragma unroll
    for (int i = 0; i < 4; i++) {
        o[i][0] = eluf(acc[i][0] + bvv.x);
        o[i][1] = eluf(acc[i][1] + bvv.y);
        o[i][2] = eluf(acc[i][2] + bvv.z);
        o[i][3] = eluf(acc[i][3] + bvv.w);
        int m = m_base + ty * 4 + i;
        if (m < NN)
            *(float4*)(out + (size_t)m * 64 + tx * 4) =
                make_float4(o[i][0], o[i][1], o[i][2], o[i][3]);
    }
    if (DOATT) {
        float ps[4][4] = {}, pd[4][4] = {};
#pragma unroll
        for (int i = 0; i < 4; i++)
#pragma unroll
            for (int j = 0; j < 4; j++) {
                float v = o[i][j];
                int kk = (tx * 4 + j) * 4;
#pragma unroll
                for (int h = 0; h < 4; h++) {
                    ps[i][h] += v * msS[kk + h];
                    pd[i][h] += v * mdS[kk + h];
                }
            }
#pragma unroll
        for (int mk = 1; mk < 16; mk <<= 1) {
#pragma unroll
            for (int i = 0; i < 4; i++)
#pragma unroll
                for (int h = 0; h < 4; h++) {
                    ps[i][h] += __shfl_xor(ps[i][h], mk, 64);
                    pd[i][h] += __shfl_xor(pd[i][h], mk, 64);
                }
        }
        if (tx == 0) {
#pragma unroll
            for (int i = 0; i < 4; i++) {
                int m = m_base + ty * 4 + i;
                if (m < NN) {
                    *(float4*)(as_ + (size_t)m * 4) =
                        make_float4(ps[i][0], ps[i][1], ps[i][2], ps[i][3]);
                    *(float4*)(ad_ + (size_t)m * 4) =
                        make_float4(pd[i][0], pd[i][1], pd[i][2], pd[i][3]);
                }
            }
        }
    }
}

// ---- SAGE mean aggregation into AB[:,0:64]; copy h2 into AB[:,64:128] ----
__global__ __launch_bounds__(256) void sage_agg3_kernel(
    const float* __restrict__ h2, const int* __restrict__ eoff,
    const int2* __restrict__ se_sorted, float* __restrict__ AB) {
    int n = blockIdx.x * 16 + (threadIdx.x >> 4);
    if (n >= NN) return;
    int l = threadIdx.x & 15;
    const float4* h24 = (const float4*)h2;
    float4* AB4 = (float4*)AB;
    float ax = 0.f, ay = 0.f, az = 0.f, aw = 0.f;
    int b = eoff[n], e_end = eoff[n + 1];
    int idx = b;
    int stop = b + ((e_end - b) & ~7);
    if (idx < stop) {
        int sreg[8];
#pragma unroll
        for (int u = 0; u < 8; u++) sreg[u] = se_sorted[idx + u].x;
        idx += 8;
        while (true) {
            int sn[8];
            bool more = idx < stop;
            if (more) {
#pragma unroll
                for (int u = 0; u < 8; u++) sn[u] = se_sorted[idx + u].x;
            }
#pragma unroll
            for (int u = 0; u < 8; u++) {
                float4 v = h24[(size_t)sreg[u] * 16 + l];
                ax += v.x; ay += v.y; az += v.z; aw += v.w;
            }
            if (!more) break;
#pragma unroll
            for (int u = 0; u < 8; u++) sreg[u] = sn[u];
            idx += 8;
        }
    }
    for (; idx < e_end; idx++) {
        float4 v0 = h24[(size_t)se_sorted[idx].x * 16 + l];
        ax += v0.x; ay += v0.y; az += v0.z; aw += v0.w;
    }
    float dg = (float)(e_end - b);
    if (dg < 1.f) dg = 1.f;
    float inv = 1.f / dg;
    AB4[(size_t)n * 32 + l] = make_float4(ax * inv, ay * inv, az * inv, aw * inv);
    AB4[(size_t)n * 32 + 16 + l] = h24[(size_t)n * 16 + l];
}

// ---- fused pool + MLP head: one block per graph -> d_out[192] ----
__global__ __launch_bounds__(256) void pool_mlp_kernel(
    const float* __restrict__ h3, const int* __restrict__ goff,
    const float* __restrict__ lin1W, const float* __restrict__ lin1b,
    const float* __restrict__ lin2W, const float* __restrict__ lin2b,
    const float* __restrict__ telW, const float* __restrict__ telb,
    const float* __restrict__ compW, const float* __restrict__ compb,
    const float* __restrict__ pchW, const float* __restrict__ pchb,
    float* __restrict__ out) {
    __shared__ float red[256];
    __shared__ float g[64], G1[64], G2[64];
    int gi = blockIdx.x, t = threadIdx.x;
    int c = t & 63, li = t >> 6;
    int b = goff[gi], e = goff[gi + 1];
    float sum = 0.f;
    for (int r = b + li; r < e; r += 4) sum += h3[(size_t)r * HID + c];
    red[t] = sum;
    __syncthreads();
    if (t < 64) {
        float v = red[t] + red[t + 64] + red[t + 128] + red[t + 192];
        float cntf = (float)(e - b);
        if (cntf < 1.f) cntf = 1.f;
        g[t] = v / cntf;
    }
    __syncthreads();
    {
        float part = 0.f;
#pragma unroll
        for (int k = li * 16; k < li * 16 + 16; k++) part += g[k] * lin1W[k * 64 + c];
        red[t] = part;
        __syncthreads();
        if (t < 64)
            G1[c] = eluf(red[c] + red[c + 64] + red[c + 128] + red[c + 192] + lin1b[c]);
        __syncthreads();
    }
    {
        float part = 0.f;
#pragma unroll
        for (int k = li * 16; k < li * 16 + 16; k++) part += G1[k] * lin2W[k * 64 + c];
        red[t] = part;
        __syncthreads();
        if (t < 64)
            G2[c] = red[c] + red[c + 64] + red[c + 128] + red[c + 192] + lin2b[c];
        __syncthreads();
    }
    if (t < 192) {
        int h = t >> 6, k = t & 63;
        const float* W = (h == 0) ? telW : ((h == 1) ? compW : pchW);
        red[t] = G2[k] * W[k];
    }
    __syncthreads();
    if (t < 3) {
        float acc = 0.f;
        for (int k = 0; k < 64; k++) acc += red[t * 64 + k];
        float bb = (t == 0) ? telb[0] : ((t == 1) ? compb[0] : pchb[0]);
        out[t * 64 + gi] = acc + bb;
    }
}

extern "C" void kernel_launch(void* const* d_in, const int* in_sizes, int n_in,
                              void* d_out, int out_size, void* d_ws, size_t ws_size,
                              hipStream_t stream) {
    const float* x        = (const float*)d_in[0];
    const float* EA       = (const float*)d_in[1];
    const float* node_emb = (const float*)d_in[2];
    const float* edge_W   = (const float*)d_in[3];
    const float* edge_b   = (const float*)d_in[4];
    const float* W1       = (const float*)d_in[5];
    const float* as1      = (const float*)d_in[6];
    const float* ad1      = (const float*)d_in[7];
    const float* ae1      = (const float*)d_in[8];
    const float* leW1     = (const float*)d_in[9];
    const float* b1       = (const float*)d_in[10];
    const float* W2       = (const float*)d_in[11];
    const float* as2      = (const float*)d_in[12];
    const float* ad2      = (const float*)d_in[13];
    const float* ae2      = (const float*)d_in[14];
    const float* leW2     = (const float*)d_in[15];
    const float* b2       = (const float*)d_in[16];
    const float* sage_Wl  = (const float*)d_in[17];
    const float* sage_bl  = (const float*)d_in[18];
    const float* sage_Wr  = (const float*)d_in[19];
    const float* lin1_W   = (const float*)d_in[20];
    const float* lin1_b   = (const float*)d_in[21];
    const float* lin2_W   = (const float*)d_in[22];
    const float* lin2_b   = (const float*)d_in[23];
    const float* tel_W    = (const float*)d_in[24];
    const float* tel_b    = (const float*)d_in[25];
    const float* comp_W   = (const float*)d_in[26];
    const float* comp_b   = (const float*)d_in[27];
    const float* pch_W    = (const float*)d_in[28];
    const float* pch_b    = (const float*)d_in[29];
    const int* edge_index = (const int*)d_in[30];
    const int* batch      = (const int*)d_in[31];
    const int* node_type  = (const int*)d_in[32];
    float* outp = (float*)d_out;

    const int* srcp = edge_index;
    const int* dstp = edge_index + NE;

    float* wf = (float*)d_ws;
    constexpr size_t OFF_H3    = 0;                               // N*64 (h3)
    constexpr size_t OFF_AGG   = OFF_H3 + (size_t)NN * 64;        // N*512 (agg1[320]/agg2[256]/AB alias)
    constexpr size_t OFF_H1    = OFF_AGG + (size_t)NN * 512;      // N*64
    constexpr size_t OFF_H2    = OFF_H1 + (size_t)NN * 64;        // N*64
    constexpr size_t OFF_SC    = OFF_H2 + (size_t)NN * 64;        // E*4
    constexpr size_t OFF_AE2   = OFF_SC + (size_t)NE * 4;         // E*4
    constexpr size_t OFF_AS    = OFF_AE2 + (size_t)NE * 4;        // N*4
    constexpr size_t OFF_AD    = OFF_AS + (size_t)NN * 4;         // N*4
    constexpr size_t OFF_SMALL = OFF_AD + (size_t)NN * 4;         // 4096
    constexpr size_t OFF_WC1   = OFF_SMALL + 4096;                // 20480
    constexpr size_t OFF_WC2   = OFF_WC1 + 20480;                 // 16384
    constexpr size_t OFF_B128  = OFF_WC2 + 16384;                 // 8192
    constexpr size_t F_TOTAL   = OFF_B128 + 8192;

    int* wi         = (int*)(wf + F_TOTAL);
    int* cnt        = wi;                        // N
    int* pos        = wi + NN;                   // N   (adjacent: one memset)
    int* eoff       = pos + NN;                  // N+1
    int2* se_sorted = (int2*)(eoff + (NN + 2));  // E int2
    int* goff       = (int*)(se_sorted + NE);    // NG+1
    int* bsum       = goff + (NG + 1);           // 64
    int* boff       = bsum + 64;                 // 64

    float* h3    = wf + OFF_H3;
    float* aggb  = wf + OFF_AGG;
    float* h1    = wf + OFF_H1;
    float* h2    = wf + OFF_H2;
    float* sc    = wf + OFF_SC;
    float* ae2s  = wf + OFF_AE2;
    float* as_   = wf + OFF_AS;
    float* ad_   = wf + OFF_AD;
    float* S     = wf + OFF_SMALL;
    float* WC1   = wf + OFF_WC1;
    float* WC2   = wf + OFF_WC2;
    float* B128  = wf + OFF_B128;
    float* AB    = wf + OFF_AGG;                 // alias (agg dead after gemm L2)

    hipMemsetAsync(S + S_MEANEA, 0, 16 * sizeof(float), stream);
    hipMemsetAsync(cnt, 0, 2 * NN * sizeof(int), stream);   // cnt + pos

    count_mean_kernel<<<(NE + 511) / 512, 256, 0, stream>>>(dstp, EA, cnt, S);
    prep_weights_kernel<<<176, 256, 0, stream>>>(W1, W2, sage_Wl, sage_Wr, node_emb,
                                                 WC1, WC2, B128);
    prep_small_kernel<<<1, 256, 0, stream>>>(W1, as1, ad1, ae1, leW1,
                                             W2, as2, ad2, ae2, leW2,
                                             edge_W, edge_b, S);
    {
        int nb = (NN + 1023) / 1024;  // 30
        scan_blocks_kernel<<<nb, 1024, 0, stream>>>(cnt, eoff, bsum);
        scan_tops_kernel<<<1, 64, 0, stream>>>(bsum, boff, nb);
        scan_add_kernel<<<(NN + 255) / 256, 256, 0, stream>>>(boff, eoff);
    }
    attn_h0_kernel<<<(NN + 63) / 64, 256, 0, stream>>>(x, node_emb, node_type, S, as_, ad_);
    goff_bs_kernel<<<1, 128, 0, stream>>>(batch, goff);
    scatter_score_kernel<<<(NE + 255) / 256, 256, 0, stream>>>(
        srcp, dstp, EA, S, as_, ad_, node_type, eoff, pos, se_sorted, sc, ae2s);

    // ----- GAT layer 1: x-gather + type histogram -> K=320 projection -----
    agg_gat1_kernel<<<(NN + 3) / 4, 256, 0, stream>>>(
        eoff, se_sorted, sc, x, node_type, as_, ad_, S + S_AEL1, aggb);
    gemm64_kernel<320, true><<<(NN + 63) / 64, 256, 0, stream>>>(
        aggb, WC1, b1, h1, S + S_MS2, S + S_MD2, as_, ad_);

    // ----- GAT layer 2 -----
    agg_gat2_kernel<<<(NN + 3) / 4, 256, 0, stream>>>(
        eoff, se_sorted, ae2s, h1, as_, ad_, S + S_AEL2, aggb);
    gemm64_kernel<256, false><<<(NN + 63) / 64, 256, 0, stream>>>(
        aggb, WC2, b2, h2, nullptr, nullptr, nullptr, nullptr);

    // ----- SAGE -----
    sage_agg3_kernel<<<(NN + 15) / 16, 256, 0, stream>>>(h2, eoff, se_sorted, AB);
    gemm64_kernel<128, false><<<(NN + 63) / 64, 256, 0, stream>>>(
        AB, B128, sage_bl, h3, nullptr, nullptr, nullptr, nullptr);

    // ----- fused pool + MLP head -----
    pool_mlp_kernel<<<NG, 256, 0, stream>>>(h3, goff, lin1_W, lin1_b, lin2_W, lin2_b,
                                            tel_W, tel_b, comp_W, comp_b, pch_W, pch_b, outp);
}

// Round 11
// 437.512 us; speedup vs baseline: 1.0600x; 1.0031x over previous
//
#include <hip/hip_runtime.h>
#include <math.h>

#define NN 30000          // nodes
#define NE 480000         // edges
#define FEA 16            // edge feature dim
#define HID 64
#define NG 64             // graphs
#define LEAKK 0.2f

// ---- small-constant region layout (float offsets) ----
#define S_MEANEA 0    // 16
#define S_KF1    16   // 64  (K1 [16,4])
#define S_C1     80   // 4
#define S_AEL1   84   // 4
#define S_KF2    88   // 64
#define S_C2     152  // 4
#define S_AEL2   156  // 4
#define S_MS1    160  // 512 (Ms1 [128,4])
#define S_MD1    672  // 512
#define S_MS2    1184 // 256 (Ms2 [64,4])
#define S_MD2    1440 // 256

__device__ __forceinline__ float eluf(float v) { return v > 0.f ? v : expm1f(v); }
__device__ __forceinline__ float leakyf(float v) { return v >= 0.f ? v : LEAKK * v; }
__device__ __forceinline__ void fma4(float4& a, float w, const float4& x) {
    a.x += w * x.x; a.y += w * x.y; a.z += w * x.z; a.w += w * x.w;
}

// ---- count (CSR degree) + mean of edge_attr ----
__global__ __launch_bounds__(256) void count_mean_kernel(
    const int* __restrict__ dst, const float* __restrict__ EA,
    int* __restrict__ cnt, float* __restrict__ S) {
    __shared__ float red[1024];
    int t = threadIdx.x;
    int base = blockIdx.x * 512;
#pragma unroll
    for (int i = 0; i < 2; i++) {
        int e = base + i * 256 + t;
        if (e < NE) atomicAdd(&cnt[dst[e]], 1);
    }
    int c4 = t & 3;
    int rbase = base + (t >> 2);
    float4 acc = {0, 0, 0, 0};
#pragma unroll
    for (int i = 0; i < 8; i++) {
        int r = rbase + i * 64;
        if (r < NE) {
            float4 v = *(const float4*)(EA + (size_t)r * FEA + c4 * 4);
            acc.x += v.x; acc.y += v.y; acc.z += v.z; acc.w += v.w;
        }
    }
    *(float4*)&red[t * 4] = acc;
    __syncthreads();
    if (t < 16) {
        int grp = t >> 2;
        int comp = t & 3;
        float sum = 0.f;
        for (int j = 0; j < 64; j++) sum += red[(grp + 4 * j) * 4 + comp];
        atomicAdd(&S[S_MEANEA + grp * 4 + comp], sum);
    }
}

// ---- merged prep: block 0 = small attention folds; blocks 1..176 = weight layouts ----
__global__ void prep_all_kernel(
    const float* __restrict__ W1, const float* __restrict__ as1, const float* __restrict__ ad1,
    const float* __restrict__ ae1, const float* __restrict__ leW1,
    const float* __restrict__ W2, const float* __restrict__ as2, const float* __restrict__ ad2,
    const float* __restrict__ ae2, const float* __restrict__ leW2,
    const float* __restrict__ edge_W, const float* __restrict__ edge_b,
    const float* __restrict__ Wl, const float* __restrict__ Wr,
    const float* __restrict__ emb,
    float* __restrict__ S, float* __restrict__ WC1, float* __restrict__ WC2,
    float* __restrict__ B128) {
    int t = threadIdx.x;
    if (blockIdx.x > 0) {
        int i = (blockIdx.x - 1) * 256 + t;
        if (i < 16384) {            // WC1 x part
            int hk = i >> 6, c = i & 63;
            int h = hk >> 6, k = hk & 63;
            WC1[i] = 0.25f * W1[k * 256 + h * 64 + c];
        } else if (i < 20480) {     // WC1 emb part
            int j2 = i - 16384;
            int r2 = j2 >> 6, c = j2 & 63;
            int h = r2 >> 4, tau = r2 & 15;
            float v = 0.f;
            for (int j = 0; j < 64; j++)
                v += emb[tau * 64 + j] * W1[(64 + j) * 256 + h * 64 + c];
            WC1[i] = 0.25f * v;
        } else if (i < 36864) {
            int j = i - 20480;
            int hk = j >> 6, c = j & 63;
            int h = hk >> 6, k = hk & 63;
            WC2[j] = 0.25f * W2[k * 256 + h * 64 + c];
        } else if (i < 45056) {
            int j = i - 36864;
            int k = j >> 6, c = j & 63;
            B128[j] = (k < 64) ? Wl[k * 64 + c] : Wr[(k - 64) * 64 + c];
        }
        return;
    }
    __shared__ float M1[256], M2[256], meh[64];
    if (t < 16) S[S_MEANEA + t] *= (1.0f / (float)NE);
    __syncthreads();
    {
        int k = t >> 2, h = t & 3;
        float m1 = 0.f, m2 = 0.f;
        for (int c = 0; c < 64; c++) {
            m1 += leW1[k * 256 + h * 64 + c] * ae1[h * 64 + c];
            m2 += leW2[k * 256 + h * 64 + c] * ae2[h * 64 + c];
        }
        M1[t] = m1; M2[t] = m2;
    }
    if (t < 64) {
        float v = edge_b[t];
        for (int f = 0; f < FEA; f++) v += S[S_MEANEA + f] * edge_W[f * 64 + t];
        meh[t] = v;
    }
    __syncthreads();
    if (t < 64) {
        int f = t >> 2, h = t & 3;
        float k1 = 0.f, k2 = 0.f;
        for (int k = 0; k < 64; k++) {
            k1 += edge_W[f * 64 + k] * M1[k * 4 + h];
            k2 += edge_W[f * 64 + k] * M2[k * 4 + h];
        }
        S[S_KF1 + t] = k1; S[S_KF2 + t] = k2;
    } else if (t < 68) {
        int h = t - 64;
        float c1 = 0.f, c2 = 0.f, a1 = 0.f, a2 = 0.f;
        for (int k = 0; k < 64; k++) {
            c1 += edge_b[k] * M1[k * 4 + h];
            c2 += edge_b[k] * M2[k * 4 + h];
            a1 += meh[k] * M1[k * 4 + h];
            a2 += meh[k] * M2[k * 4 + h];
        }
        S[S_C1 + h] = c1; S[S_C2 + h] = c2;
        S[S_AEL1 + h] = a1; S[S_AEL2 + h] = a2;
    }
    for (int i = t; i < 512; i += 256) {
        int k = i >> 2, h = i & 3;
        float s = 0.f, d = 0.f;
        for (int c = 0; c < 64; c++) {
            float w = W1[k * 256 + h * 64 + c];
            s += w * as1[h * 64 + c];
            d += w * ad1[h * 64 + c];
        }
        S[S_MS1 + i] = s; S[S_MD1 + i] = d;
    }
    for (int i = t; i < 256; i += 256) {
        int k = i >> 2, h = i & 3;
        float s = 0.f, d = 0.f;
        for (int c = 0; c < 64; c++) {
            float w = W2[k * 256 + h * 64 + c];
            s += w * as2[h * 64 + c];
            d += w * ad2[h * 64 + c];
        }
        S[S_MS2 + i] = s; S[S_MD2 + i] = d;
    }
}

// ---- layer-1 a_s/a_d from [x | emb[type]] (h0 NOT materialized) ----
__global__ __launch_bounds__(256) void attn_h0_kernel(
    const float* __restrict__ x, const float* __restrict__ node_emb,
    const int* __restrict__ node_type, const float* __restrict__ S,
    float* __restrict__ as_, float* __restrict__ ad_) {
    __shared__ float xt[64 * 132];
    __shared__ float ms[512], md[512];
    __shared__ int ntS[64];
    int t = threadIdx.x;
    int n0 = blockIdx.x * 64;
    if (t < 64) {
        int n = n0 + t;
        ntS[t] = (n < NN) ? node_type[n] : 0;
    }
    for (int i = t; i < 512; i += 256) { ms[i] = S[S_MS1 + i]; md[i] = S[S_MD1 + i]; }
    __syncthreads();
    for (int i = t; i < 1024; i += 256) {
        int r = i >> 4, c4 = (i & 15) * 4;
        int n = n0 + r;
        float4 f = {0, 0, 0, 0};
        if (n < NN) f = *(const float4*)(x + (size_t)n * 64 + c4);
        *(float4*)&xt[r * 132 + c4] = f;
    }
    for (int i = t; i < 1024; i += 256) {
        int r = i >> 4, c4 = (i & 15) * 4;
        int n = n0 + r;
        float4 f = {0, 0, 0, 0};
        if (n < NN) f = *(const float4*)(node_emb + (size_t)ntS[r] * 64 + c4);
        *(float4*)&xt[r * 132 + 64 + c4] = f;
    }
    __syncthreads();
    int r = t >> 2, h = t & 3;
    float s = 0.f, d = 0.f;
#pragma unroll 8
    for (int k = 0; k < 128; k++) {
        float xv = xt[r * 132 + k];
        s += xv * ms[k * 4 + h];
        d += xv * md[k * 4 + h];
    }
    int n = n0 + r;
    if (n < NN) { as_[n * 4 + h] = s; ad_[n * 4 + h] = d; }
}

// ---- 3-kernel decoupled scan ----
__global__ void scan_blocks_kernel(const int* __restrict__ cnt, int* __restrict__ eoff,
                                   int* __restrict__ bsum) {
    __shared__ int wsum[16];
    int t = threadIdx.x;
    int i = blockIdx.x * 1024 + t;
    int v = (i < NN) ? cnt[i] : 0;
    int lane = t & 63;
    int incl = v;
#pragma unroll
    for (int ofs = 1; ofs < 64; ofs <<= 1) {
        int u = __shfl_up(incl, ofs, 64);
        if (lane >= ofs) incl += u;
    }
    int wid = t >> 6;
    if (lane == 63) wsum[wid] = incl;
    __syncthreads();
    if (t < 16) {
        int s = wsum[t];
#pragma unroll
        for (int ofs = 1; ofs < 16; ofs <<= 1) {
            int u = __shfl_up(s, ofs, 64);
            if (t >= ofs) s += u;
        }
        wsum[t] = s;
    }
    __syncthreads();
    int excl = incl - v + (wid > 0 ? wsum[wid - 1] : 0);
    if (i < NN) eoff[i] = excl;
    if (t == 1023) bsum[blockIdx.x] = excl + v;
}

// block 0: scan tops; block 1: goff binary search
__global__ void scan_tops_goff_kernel(const int* __restrict__ bsum, int* __restrict__ boff,
                                      int nb, const int* __restrict__ batch,
                                      int* __restrict__ goff) {
    int t = threadIdx.x;
    if (blockIdx.x == 1) {
        if (t > NG) return;
        int lo = 0, hi = NN;
        while (lo < hi) {
            int mid = (lo + hi) >> 1;
            if (batch[mid] < t) lo = mid + 1; else hi = mid;
        }
        goff[t] = lo;
        return;
    }
    if (t >= 64) return;
    int v = (t < nb) ? bsum[t] : 0;
    int incl = v;
#pragma unroll
    for (int ofs = 1; ofs < 64; ofs <<= 1) {
        int u = __shfl_up(incl, ofs, 64);
        if (t >= ofs) incl += u;
    }
    boff[t] = incl - v;
}

__global__ void scan_add_kernel(const int* __restrict__ boff, int* __restrict__ eoff) {
    int i = blockIdx.x * 256 + threadIdx.x;
    if (i < NN) eoff[i] += boff[i >> 10];
    if (i == 0) eoff[NN] = NE;
}

// ---- fused scatter + layer-1 scoring: coalesced writes at [e]; scatter int2{s, e|type<<24} ----
__global__ void scatter_score_kernel(const int* __restrict__ src, const int* __restrict__ dst,
                                     const float* __restrict__ EA, const float* __restrict__ S,
                                     const float* __restrict__ as_, const float* __restrict__ ad_,
                                     const int* __restrict__ node_type,
                                     const int* __restrict__ eoff, int* __restrict__ pos,
                                     int2* __restrict__ se_sorted,
                                     float* __restrict__ sc1, float* __restrict__ ae2s) {
    int e = blockIdx.x * 256 + threadIdx.x;
    if (e >= NE) return;
    int s = src[e], d = dst[e];
    float a1[4], a2[4];
#pragma unroll
    for (int h = 0; h < 4; h++) { a1[h] = S[S_C1 + h]; a2[h] = S[S_C2 + h]; }
    const float4* EA4 = (const float4*)(EA + (size_t)e * FEA);
#pragma unroll
    for (int q = 0; q < 4; q++) {
        float4 v = EA4[q];
        float vv[4] = {v.x, v.y, v.z, v.w};
#pragma unroll
        for (int j = 0; j < 4; j++) {
            int f = q * 4 + j;
#pragma unroll
            for (int h = 0; h < 4; h++) {
                a1[h] += vv[j] * S[S_KF1 + f * 4 + h];
                a2[h] += vv[j] * S[S_KF2 + f * 4 + h];
            }
        }
    }
    ((float4*)ae2s)[e] = make_float4(a2[0], a2[1], a2[2], a2[3]);
    float4 asv = ((const float4*)as_)[s];
    float4 adv = ((const float4*)ad_)[d];
    float4 r;
    r.x = expf(leakyf(asv.x + adv.x + a1[0]));
    r.y = expf(leakyf(asv.y + adv.y + a1[1]));
    r.z = expf(leakyf(asv.z + adv.z + a1[2]));
    r.w = expf(leakyf(asv.w + adv.w + a1[3]));
    ((float4*)sc1)[e] = r;
    int ty = node_type[s];
    int p = atomicAdd(&pos[d], 1);
    se_sorted[eoff[d] + p] = make_int2(s, e | (ty << 24));
}

// ---- dense layer-2 scoring: sc2[e] = exp(leaky(as2[s]+ad2[d]+ae2s[e])), coalesced ----
__global__ void score2_kernel(const int* __restrict__ src, const int* __restrict__ dst,
                              const float* __restrict__ ae2s,
                              const float* __restrict__ as_, const float* __restrict__ ad_,
                              float* __restrict__ sc2) {
    int e = blockIdx.x * 256 + threadIdx.x;
    if (e >= NE) return;
    int s = src[e], d = dst[e];
    float4 ae = ((const float4*)ae2s)[e];
    float4 asv = ((const float4*)as_)[s];
    float4 adv = ((const float4*)ad_)[d];
    float4 r;
    r.x = expf(leakyf(asv.x + adv.x + ae.x));
    r.y = expf(leakyf(asv.y + adv.y + ae.y));
    r.z = expf(leakyf(asv.z + adv.z + ae.z));
    r.w = expf(leakyf(asv.w + adv.w + ae.w));
    ((float4*)sc2)[e] = r;
}

// ---- layer-1 GAT aggregation: gather x rows (256B) + per-type weight histogram ----
__global__ __launch_bounds__(256) void agg_gat1_kernel(
    const int* __restrict__ eoff, const int2* __restrict__ se_sorted,
    const float* __restrict__ sc1, const float* __restrict__ x,
    const int* __restrict__ node_type,
    const float* __restrict__ as_, const float* __restrict__ ad_,
    const float* __restrict__ Sael, float* __restrict__ agg) {
    int n = blockIdx.x * 4 + (threadIdx.x >> 6);
    if (n >= NN) return;
    int lane = threadIdx.x & 63;
    int sub = lane >> 4, ch = lane & 15;
    const float4* X4 = (const float4*)x;
    const float4* W4 = (const float4*)sc1;
    float4 asn = ((const float4*)as_)[n];
    float4 adn = ((const float4*)ad_)[n];
    float4 a0 = {0, 0, 0, 0}, a1 = a0, a2 = a0, a3 = a0, dn = a0, tw = a0;
    int b = eoff[n], e_end = eoff[n + 1];
    int nE = e_end - b;
    int i = sub;
    for (; i + 4 < nE; i += 8) {
        int2 se0 = se_sorted[b + i], se1 = se_sorted[b + i + 4];
        int e0 = se0.y & 0xFFFFFF, t0 = se0.y >> 24;
        int e1 = se1.y & 0xFFFFFF, t1 = se1.y >> 24;
        float4 w0 = W4[e0], w1 = W4[e1];
        float4 x0 = X4[(size_t)se0.x * 16 + ch];
        float4 x1 = X4[(size_t)se1.x * 16 + ch];
        fma4(a0, w0.x, x0); fma4(a1, w0.y, x0); fma4(a2, w0.z, x0); fma4(a3, w0.w, x0);
        fma4(a0, w1.x, x1); fma4(a1, w1.y, x1); fma4(a2, w1.z, x1); fma4(a3, w1.w, x1);
        dn.x += w0.x + w1.x; dn.y += w0.y + w1.y;
        dn.z += w0.z + w1.z; dn.w += w0.w + w1.w;
        if (ch == t0) { tw.x += w0.x; tw.y += w0.y; tw.z += w0.z; tw.w += w0.w; }
        if (ch == t1) { tw.x += w1.x; tw.y += w1.y; tw.z += w1.z; tw.w += w1.w; }
    }
    for (; i < nE; i += 4) {
        int2 se0 = se_sorted[b + i];
        int e0 = se0.y & 0xFFFFFF, t0 = se0.y >> 24;
        float4 w0 = W4[e0];
        float4 x0 = X4[(size_t)se0.x * 16 + ch];
        fma4(a0, w0.x, x0); fma4(a1, w0.y, x0); fma4(a2, w0.z, x0); fma4(a3, w0.w, x0);
        dn.x += w0.x; dn.y += w0.y; dn.z += w0.z; dn.w += w0.w;
        if (ch == t0) { tw.x += w0.x; tw.y += w0.y; tw.z += w0.z; tw.w += w0.w; }
    }
    if (sub == 0) {  // self loop
        float e0 = expf(leakyf(asn.x + adn.x + Sael[0]));
        float e1 = expf(leakyf(asn.y + adn.y + Sael[1]));
        float e2 = expf(leakyf(asn.z + adn.z + Sael[2]));
        float e3 = expf(leakyf(asn.w + adn.w + Sael[3]));
        float4 xs = X4[(size_t)n * 16 + ch];
        fma4(a0, e0, xs); fma4(a1, e1, xs); fma4(a2, e2, xs); fma4(a3, e3, xs);
        dn.x += e0; dn.y += e1; dn.z += e2; dn.w += e3;
        int tn = node_type[n];
        if (ch == tn) { tw.x += e0; tw.y += e1; tw.z += e2; tw.w += e3; }
    }
#pragma unroll
    for (int mask = 16; mask < 64; mask <<= 1) {
        a0.x += __shfl_xor(a0.x, mask, 64); a0.y += __shfl_xor(a0.y, mask, 64);
        a0.z += __shfl_xor(a0.z, mask, 64); a0.w += __shfl_xor(a0.w, mask, 64);
        a1.x += __shfl_xor(a1.x, mask, 64); a1.y += __shfl_xor(a1.y, mask, 64);
        a1.z += __shfl_xor(a1.z, mask, 64); a1.w += __shfl_xor(a1.w, mask, 64);
        a2.x += __shfl_xor(a2.x, mask, 64); a2.y += __shfl_xor(a2.y, mask, 64);
        a2.z += __shfl_xor(a2.z, mask, 64); a2.w += __shfl_xor(a2.w, mask, 64);
        a3.x += __shfl_xor(a3.x, mask, 64); a3.y += __shfl_xor(a3.y, mask, 64);
        a3.z += __shfl_xor(a3.z, mask, 64); a3.w += __shfl_xor(a3.w, mask, 64);
        dn.x += __shfl_xor(dn.x, mask, 64); dn.y += __shfl_xor(dn.y, mask, 64);
        dn.z += __shfl_xor(dn.z, mask, 64); dn.w += __shfl_xor(dn.w, mask, 64);
        tw.x += __shfl_xor(tw.x, mask, 64); tw.y += __shfl_xor(tw.y, mask, 64);
        tw.z += __shfl_xor(tw.z, mask, 64); tw.w += __shfl_xor(tw.w, mask, 64);
    }
    if (sub == 0) {
        float i0 = 1.f / dn.x, i1 = 1.f / dn.y, i2 = 1.f / dn.z, i3 = 1.f / dn.w;
        float* A = agg + (size_t)n * 320;
        float4* A4 = (float4*)A;
        A4[ch]      = make_float4(a0.x * i0, a0.y * i0, a0.z * i0, a0.w * i0);
        A4[16 + ch] = make_float4(a1.x * i1, a1.y * i1, a1.z * i1, a1.w * i1);
        A4[32 + ch] = make_float4(a2.x * i2, a2.y * i2, a2.z * i2, a2.w * i2);
        A4[48 + ch] = make_float4(a3.x * i3, a3.y * i3, a3.z * i3, a3.w * i3);
        A[256 + ch]      = tw.x * i0;
        A[256 + 16 + ch] = tw.y * i1;
        A[256 + 32 + ch] = tw.z * i2;
        A[256 + 48 + ch] = tw.w * i3;
    }
}

// ---- layer-2 GAT aggregation: pure gather (scores precomputed in sc2) ----
__global__ __launch_bounds__(256) void agg_gat2_kernel(
    const int* __restrict__ eoff, const int2* __restrict__ se_sorted,
    const float* __restrict__ sc2, const float* __restrict__ X,
    const float* __restrict__ as_, const float* __restrict__ ad_,
    const float* __restrict__ Sael, float* __restrict__ agg) {
    int n = blockIdx.x * 4 + (threadIdx.x >> 6);
    if (n >= NN) return;
    int lane = threadIdx.x & 63;
    int sub = lane >> 4, ch = lane & 15;
    const float4* X4 = (const float4*)X;
    const float4* W4 = (const float4*)sc2;
    float4 asn = ((const float4*)as_)[n];
    float4 adn = ((const float4*)ad_)[n];
    float4 a0 = {0, 0, 0, 0}, a1 = a0, a2 = a0, a3 = a0, dn = a0;
    int b = eoff[n], e = eoff[n + 1];
    int nE = e - b;
    int i = sub;
    for (; i + 4 < nE; i += 8) {
        int2 se0 = se_sorted[b + i], se1 = se_sorted[b + i + 4];
        float4 w0 = W4[se0.y & 0xFFFFFF], w1 = W4[se1.y & 0xFFFFFF];
        float4 x0 = X4[(size_t)se0.x * 16 + ch];
        float4 x1 = X4[(size_t)se1.x * 16 + ch];
        fma4(a0, w0.x, x0); fma4(a1, w0.y, x0); fma4(a2, w0.z, x0); fma4(a3, w0.w, x0);
        fma4(a0, w1.x, x1); fma4(a1, w1.y, x1); fma4(a2, w1.z, x1); fma4(a3, w1.w, x1);
        dn.x += w0.x + w1.x; dn.y += w0.y + w1.y;
        dn.z += w0.z + w1.z; dn.w += w0.w + w1.w;
    }
    for (; i < nE; i += 4) {
        int2 se0 = se_sorted[b + i];
        float4 w0 = W4[se0.y & 0xFFFFFF];
        float4 x0 = X4[(size_t)se0.x * 16 + ch];
        fma4(a0, w0.x, x0); fma4(a1, w0.y, x0); fma4(a2, w0.z, x0); fma4(a3, w0.w, x0);
        dn.x += w0.x; dn.y += w0.y; dn.z += w0.z; dn.w += w0.w;
    }
    if (sub == 0) {  // self loop
        float e0 = expf(leakyf(asn.x + adn.x + Sael[0]));
        float e1 = expf(leakyf(asn.y + adn.y + Sael[1]));
        float e2 = expf(leakyf(asn.z + adn.z + Sael[2]));
        float e3 = expf(leakyf(asn.w + adn.w + Sael[3]));
        float4 xs = X4[(size_t)n * 16 + ch];
        fma4(a0, e0, xs); fma4(a1, e1, xs); fma4(a2, e2, xs); fma4(a3, e3, xs);
        dn.x += e0; dn.y += e1; dn.z += e2; dn.w += e3;
    }
#pragma unroll
    for (int mask = 16; mask < 64; mask <<= 1) {
        a0.x += __shfl_xor(a0.x, mask, 64); a0.y += __shfl_xor(a0.y, mask, 64);
        a0.z += __shfl_xor(a0.z, mask, 64); a0.w += __shfl_xor(a0.w, mask, 64);
        a1.x += __shfl_xor(a1.x, mask, 64); a1.y += __shfl_xor(a1.y, mask, 64);
        a1.z += __shfl_xor(a1.z, mask, 64); a1.w += __shfl_xor(a1.w, mask, 64);
        a2.x += __shfl_xor(a2.x, mask, 64); a2.y += __shfl_xor(a2.y, mask, 64);
        a2.z += __shfl_xor(a2.z, mask, 64); a2.w += __shfl_xor(a2.w, mask, 64);
        a3.x += __shfl_xor(a3.x, mask, 64); a3.y += __shfl_xor(a3.y, mask, 64);
        a3.z += __shfl_xor(a3.z, mask, 64); a3.w += __shfl_xor(a3.w, mask, 64);
        dn.x += __shfl_xor(dn.x, mask, 64); dn.y += __shfl_xor(dn.y, mask, 64);
        dn.z += __shfl_xor(dn.z, mask, 64); dn.w += __shfl_xor(dn.w, mask, 64);
    }
    if (sub == 0) {
        float i0 = 1.f / dn.x, i1 = 1.f / dn.y, i2 = 1.f / dn.z, i3 = 1.f / dn.w;
        float4* agg4 = (float4*)(agg + (size_t)n * 256);
        agg4[ch]      = make_float4(a0.x * i0, a0.y * i0, a0.z * i0, a0.w * i0);
        agg4[16 + ch] = make_float4(a1.x * i1, a1.y * i1, a1.z * i1, a1.w * i1);
        agg4[32 + ch] = make_float4(a2.x * i2, a2.y * i2, a2.z * i2, a2.w * i2);
        agg4[48 + ch] = make_float4(a3.x * i3, a3.y * i3, a3.z * i3, a3.w * i3);
    }
}

// ---- GEMM: out[M,64] = elu(A[M,K]@B[K,64]+bias); 64-row tiles, reg prefetch ----
template <int K, bool DOATT>
__global__ __launch_bounds__(256) void gemm64_kernel(
    const float* __restrict__ A, const float* __restrict__ B,
    const float* __restrict__ bias, float* __restrict__ out,
    const float* __restrict__ ms_g, const float* __restrict__ md_g,
    float* __restrict__ as_, float* __restrict__ ad_) {
    __shared__ float As[32 * 68];
    __shared__ float Bs[32 * 68];
    __shared__ float msS[256], mdS[256];
    int t = threadIdx.x;
    int tx = t & 15, ty = t >> 4;
    int m_base = blockIdx.x * 64;
    if (DOATT) { msS[t] = ms_g[t]; mdS[t] = md_g[t]; }
    int arow0 = t >> 3, akq0 = (t & 7) * 4;
    int arow1 = (t + 256) >> 3, akq1 = ((t + 256) & 7) * 4;
    int bkr = t >> 4, bnc = (t & 15) * 4;
    int am0 = m_base + arow0, am1 = m_base + arow1;
    float4 fa0, fa1, fb0, fb1;
    fa0 = (am0 < NN) ? *(const float4*)(A + (size_t)am0 * K + akq0) : make_float4(0, 0, 0, 0);
    fa1 = (am1 < NN) ? *(const float4*)(A + (size_t)am1 * K + akq1) : make_float4(0, 0, 0, 0);
    fb0 = *(const float4*)(B + (size_t)bkr * 64 + bnc);
    fb1 = *(const float4*)(B + (size_t)(bkr + 16) * 64 + bnc);
    float acc[4][4] = {};
    for (int k0 = 0;; k0 += 32) {
        As[(akq0 + 0) * 68 + arow0] = fa0.x;
        As[(akq0 + 1) * 68 + arow0] = fa0.y;
        As[(akq0 + 2) * 68 + arow0] = fa0.z;
        As[(akq0 + 3) * 68 + arow0] = fa0.w;
        As[(akq1 + 0) * 68 + arow1] = fa1.x;
        As[(akq1 + 1) * 68 + arow1] = fa1.y;
        As[(akq1 + 2) * 68 + arow1] = fa1.z;
        As[(akq1 + 3) * 68 + arow1] = fa1.w;
        *(float4*)&Bs[bkr * 68 + bnc] = fb0;
        *(float4*)&Bs[(bkr + 16) * 68 + bnc] = fb1;
        __syncthreads();
        bool more = (k0 + 32 < K);
        if (more) {
            int kn = k0 + 32;
            fa0 = (am0 < NN) ? *(const float4*)(A + (size_t)am0 * K + kn + akq0)
                             : make_float4(0, 0, 0, 0);
            fa1 = (am1 < NN) ? *(const float4*)(A + (size_t)am1 * K + kn + akq1)
                             : make_float4(0, 0, 0, 0);
            fb0 = *(const float4*)(B + (size_t)(kn + bkr) * 64 + bnc);
            fb1 = *(const float4*)(B + (size_t)(kn + bkr + 16) * 64 + bnc);
        }
#pragma unroll
        for (int k = 0; k < 32; k++) {
            float4 av = *(const float4*)&As[k * 68 + ty * 4];
            float4 bv = *(const float4*)&Bs[k * 68 + tx * 4];
            float a[4] = {av.x, av.y, av.z, av.w};
            float b[4] = {bv.x, bv.y, bv.z, bv.w};
#pragma unroll
            for (int i = 0; i < 4; i++)
#pragma unroll
                for (int j = 0; j < 4; j++) acc[i][j] += a[i] * b[j];
        }
        if (!more) break;
        __syncthreads();
    }
    float4 bvv = ((const float4*)bias)[tx];
    float o[4][4];
#pragma unroll
    for (int i = 0; i < 4; i++) {
        o[i][0] = eluf(acc[i][0] + bvv.x);
        o[i][1] = eluf(acc[i][1] + bvv.y);
        o[i][2] = eluf(acc[i][2] + bvv.z);
        o[i][3] = eluf(acc[i][3] + bvv.w);
        int m = m_base + ty * 4 + i;
        if (m < NN)
            *(float4*)(out + (size_t)m * 64 + tx * 4) =
                make_float4(o[i][0], o[i][1], o[i][2], o[i][3]);
    }
    if (DOATT) {
        float ps[4][4] = {}, pd[4][4] = {};
#pragma unroll
        for (int i = 0; i < 4; i++)
#pragma unroll
            for (int j = 0; j < 4; j++) {
                float v = o[i][j];
                int kk = (tx * 4 + j) * 4;
#pragma unroll
                for (int h = 0; h < 4; h++) {
                    ps[i][h] += v * msS[kk + h];
                    pd[i][h] += v * mdS[kk + h];
                }
            }
#pragma unroll
        for (int mk = 1; mk < 16; mk <<= 1) {
#pragma unroll
            for (int i = 0; i < 4; i++)
#pragma unroll
                for (int h = 0; h < 4; h++) {
                    ps[i][h] += __shfl_xor(ps[i][h], mk, 64);
                    pd[i][h] += __shfl_xor(pd[i][h], mk, 64);
                }
        }
        if (tx == 0) {
#pragma unroll
            for (int i = 0; i < 4; i++) {
                int m = m_base + ty * 4 + i;
                if (m < NN) {
                    *(float4*)(as_ + (size_t)m * 4) =
                        make_float4(ps[i][0], ps[i][1], ps[i][2], ps[i][3]);
                    *(float4*)(ad_ + (size_t)m * 4) =
                        make_float4(pd[i][0], pd[i][1], pd[i][2], pd[i][3]);
                }
            }
        }
    }
}

// ---- SAGE mean aggregation into AB[:,0:64]; copy h2 into AB[:,64:128] ----
__global__ __launch_bounds__(256) void sage_agg3_kernel(
    const float* __restrict__ h2, const int* __restrict__ eoff,
    const int2* __restrict__ se_sorted, float* __restrict__ AB) {
    int n = blockIdx.x * 16 + (threadIdx.x >> 4);
    if (n >= NN) return;
    int l = threadIdx.x & 15;
    const float4* h24 = (const float4*)h2;
    float4* AB4 = (float4*)AB;
    float ax = 0.f, ay = 0.f, az = 0.f, aw = 0.f;
    int b = eoff[n], e_end = eoff[n + 1];
    int idx = b;
    int stop = b + ((e_end - b) & ~7);
    if (idx < stop) {
        int sreg[8];
#pragma unroll
        for (int u = 0; u < 8; u++) sreg[u] = se_sorted[idx + u].x;
        idx += 8;
        while (true) {
            int sn[8];
            bool more = idx < stop;
            if (more) {
#pragma unroll
                for (int u = 0; u < 8; u++) sn[u] = se_sorted[idx + u].x;
            }
#pragma unroll
            for (int u = 0; u < 8; u++) {
                float4 v = h24[(size_t)sreg[u] * 16 + l];
                ax += v.x; ay += v.y; az += v.z; aw += v.w;
            }
            if (!more) break;
#pragma unroll
            for (int u = 0; u < 8; u++) sreg[u] = sn[u];
            idx += 8;
        }
    }
    for (; idx < e_end; idx++) {
        float4 v0 = h24[(size_t)se_sorted[idx].x * 16 + l];
        ax += v0.x; ay += v0.y; az += v0.z; aw += v0.w;
    }
    float dg = (float)(e_end - b);
    if (dg < 1.f) dg = 1.f;
    float inv = 1.f / dg;
    AB4[(size_t)n * 32 + l] = make_float4(ax * inv, ay * inv, az * inv, aw * inv);
    AB4[(size_t)n * 32 + 16 + l] = h24[(size_t)n * 16 + l];
}

// ---- fused pool + MLP head: one block per graph -> d_out[192] ----
__global__ __launch_bounds__(256) void pool_mlp_kernel(
    const float* __restrict__ h3, const int* __restrict__ goff,
    const float* __restrict__ lin1W, const float* __restrict__ lin1b,
    const float* __restrict__ lin2W, const float* __restrict__ lin2b,
    const float* __restrict__ telW, const float* __restrict__ telb,
    const float* __restrict__ compW, const float* __restrict__ compb,
    const float* __restrict__ pchW, const float* __restrict__ pchb,
    float* __restrict__ out) {
    __shared__ float red[256];
    __shared__ float g[64], G1[64], G2[64];
    int gi = blockIdx.x, t = threadIdx.x;
    int c = t & 63, li = t >> 6;
    int b = goff[gi], e = goff[gi + 1];
    float sum = 0.f;
    for (int r = b + li; r < e; r += 4) sum += h3[(size_t)r * HID + c];
    red[t] = sum;
    __syncthreads();
    if (t < 64) {
        float v = red[t] + red[t + 64] + red[t + 128] + red[t + 192];
        float cntf = (float)(e - b);
        if (cntf < 1.f) cntf = 1.f;
        g[t] = v / cntf;
    }
    __syncthreads();
    {
        float part = 0.f;
#pragma unroll
        for (int k = li * 16; k < li * 16 + 16; k++) part += g[k] * lin1W[k * 64 + c];
        red[t] = part;
        __syncthreads();
        if (t < 64)
            G1[c] = eluf(red[c] + red[c + 64] + red[c + 128] + red[c + 192] + lin1b[c]);
        __syncthreads();
    }
    {
        float part = 0.f;
#pragma unroll
        for (int k = li * 16; k < li * 16 + 16; k++) part += G1[k] * lin2W[k * 64 + c];
        red[t] = part;
        __syncthreads();
        if (t < 64)
            G2[c] = red[c] + red[c + 64] + red[c + 128] + red[c + 192] + lin2b[c];
        __syncthreads();
    }
    if (t < 192) {
        int h = t >> 6, k = t & 63;
        const float* W = (h == 0) ? telW : ((h == 1) ? compW : pchW);
        red[t] = G2[k] * W[k];
    }
    __syncthreads();
    if (t < 3) {
        float acc = 0.f;
        for (int k = 0; k < 64; k++) acc += red[t * 64 + k];
        float bb = (t == 0) ? telb[0] : ((t == 1) ? compb[0] : pchb[0]);
        out[t * 64 + gi] = acc + bb;
    }
}

extern "C" void kernel_launch(void* const* d_in, const int* in_sizes, int n_in,
                              void* d_out, int out_size, void* d_ws, size_t ws_size,
                              hipStream_t stream) {
    const float* x        = (const float*)d_in[0];
    const float* EA       = (const float*)d_in[1];
    const float* node_emb = (const float*)d_in[2];
    const float* edge_W   = (const float*)d_in[3];
    const float* edge_b   = (const float*)d_in[4];
    const float* W1       = (const float*)d_in[5];
    const float* as1      = (const float*)d_in[6];
    const float* ad1      = (const float*)d_in[7];
    const float* ae1      = (const float*)d_in[8];
    const float* leW1     = (const float*)d_in[9];
    const float* b1       = (const float*)d_in[10];
    const float* W2       = (const float*)d_in[11];
    const float* as2      = (const float*)d_in[12];
    const float* ad2      = (const float*)d_in[13];
    const float* ae2      = (const float*)d_in[14];
    const float* leW2     = (const float*)d_in[15];
    const float* b2       = (const float*)d_in[16];
    const float* sage_Wl  = (const float*)d_in[17];
    const float* sage_bl  = (const float*)d_in[18];
    const float* sage_Wr  = (const float*)d_in[19];
    const float* lin1_W   = (const float*)d_in[20];
    const float* lin1_b   = (const float*)d_in[21];
    const float* lin2_W   = (const float*)d_in[22];
    const float* lin2_b   = (const float*)d_in[23];
    const float* tel_W    = (const float*)d_in[24];
    const float* tel_b    = (const float*)d_in[25];
    const float* comp_W   = (const float*)d_in[26];
    const float* comp_b   = (const float*)d_in[27];
    const float* pch_W    = (const float*)d_in[28];
    const float* pch_b    = (const float*)d_in[29];
    const int* edge_index = (const int*)d_in[30];
    const int* batch      = (const int*)d_in[31];
    const int* node_type  = (const int*)d_in[32];
    float* outp = (float*)d_out;

    const int* srcp = edge_index;
    const int* dstp = edge_index + NE;

    float* wf = (float*)d_ws;
    constexpr size_t OFF_H3    = 0;                               // N*64
    constexpr size_t OFF_AGG   = OFF_H3 + (size_t)NN * 64;        // N*512 (agg1[320]/agg2[256]/AB)
    constexpr size_t OFF_H1    = OFF_AGG + (size_t)NN * 512;      // N*64
    constexpr size_t OFF_H2    = OFF_H1 + (size_t)NN * 64;        // N*64
    constexpr size_t OFF_SC    = OFF_H2 + (size_t)NN * 64;        // E*4 (sc1 then sc2)
    constexpr size_t OFF_AE2   = OFF_SC + (size_t)NE * 4;         // E*4
    constexpr size_t OFF_AS    = OFF_AE2 + (size_t)NE * 4;        // N*4
    constexpr size_t OFF_AD    = OFF_AS + (size_t)NN * 4;         // N*4
    constexpr size_t OFF_SMALL = OFF_AD + (size_t)NN * 4;         // 4096
    constexpr size_t OFF_WC1   = OFF_SMALL + 4096;                // 20480
    constexpr size_t OFF_WC2   = OFF_WC1 + 20480;                 // 16384
    constexpr size_t OFF_B128  = OFF_WC2 + 16384;                 // 8192
    constexpr size_t F_TOTAL   = OFF_B128 + 8192;

    int* wi         = (int*)(wf + F_TOTAL);
    int* cnt        = wi;                        // N
    int* pos        = wi + NN;                   // N
    int* eoff       = pos + NN;                  // N+1
    int2* se_sorted = (int2*)(eoff + (NN + 2));  // E int2
    int* goff       = (int*)(se_sorted + NE);    // NG+1
    int* bsum       = goff + (NG + 1);           // 64
    int* boff       = bsum + 64;                 // 64

    float* h3    = wf + OFF_H3;
    float* aggb  = wf + OFF_AGG;
    float* h1    = wf + OFF_H1;
    float* h2    = wf + OFF_H2;
    float* sc    = wf + OFF_SC;
    float* ae2s  = wf + OFF_AE2;
    float* as_   = wf + OFF_AS;
    float* ad_   = wf + OFF_AD;
    float* S     = wf + OFF_SMALL;
    float* WC1   = wf + OFF_WC1;
    float* WC2   = wf + OFF_WC2;
    float* B128  = wf + OFF_B128;
    float* AB    = wf + OFF_AGG;                 // alias

    hipMemsetAsync(S + S_MEANEA, 0, 16 * sizeof(float), stream);
    hipMemsetAsync(cnt, 0, 2 * NN * sizeof(int), stream);   // cnt + pos

    count_mean_kernel<<<(NE + 511) / 512, 256, 0, stream>>>(dstp, EA, cnt, S);
    prep_all_kernel<<<177, 256, 0, stream>>>(W1, as1, ad1, ae1, leW1,
                                             W2, as2, ad2, ae2, leW2,
                                             edge_W, edge_b, sage_Wl, sage_Wr, node_emb,
                                             S, WC1, WC2, B128);
    {
        int nb = (NN + 1023) / 1024;  // 30
        scan_blocks_kernel<<<nb, 1024, 0, stream>>>(cnt, eoff, bsum);
        scan_tops_goff_kernel<<<2, 128, 0, stream>>>(bsum, boff, nb, batch, goff);
        scan_add_kernel<<<(NN + 255) / 256, 256, 0, stream>>>(boff, eoff);
    }
    attn_h0_kernel<<<(NN + 63) / 64, 256, 0, stream>>>(x, node_emb, node_type, S, as_, ad_);
    scatter_score_kernel<<<(NE + 255) / 256, 256, 0, stream>>>(
        srcp, dstp, EA, S, as_, ad_, node_type, eoff, pos, se_sorted, sc, ae2s);

    // ----- GAT layer 1: x-gather + type histogram -> K=320 projection -----
    agg_gat1_kernel<<<(NN + 3) / 4, 256, 0, stream>>>(
        eoff, se_sorted, sc, x, node_type, as_, ad_, S + S_AEL1, aggb);
    gemm64_kernel<320, true><<<(NN + 63) / 64, 256, 0, stream>>>(
        aggb, WC1, b1, h1, S + S_MS2, S + S_MD2, as_, ad_);

    // ----- GAT layer 2: dense score pass then pure gather -----
    score2_kernel<<<(NE + 255) / 256, 256, 0, stream>>>(srcp, dstp, ae2s, as_, ad_, sc);
    agg_gat2_kernel<<<(NN + 3) / 4, 256, 0, stream>>>(
        eoff, se_sorted, sc, h1, as_, ad_, S + S_AEL2, aggb);
    gemm64_kernel<256, false><<<(NN + 63) / 64, 256, 0, stream>>>(
        aggb, WC2, b2, h2, nullptr, nullptr, nullptr, nullptr);

    // ----- SAGE -----
    sage_agg3_kernel<<<(NN + 15) / 16, 256, 0, stream>>>(h2, eoff, se_sorted, AB);
    gemm64_kernel<128, false><<<(NN + 63) / 64, 256, 0, stream>>>(
        AB, B128, sage_bl, h3, nullptr, nullptr, nullptr, nullptr);

    // ----- fused pool + MLP head -----
    pool_mlp_kernel<<<NG, 256, 0, stream>>>(h3, goff, lin1_W, lin1_b, lin2_W, lin2_b,
                                            tel_W, tel_b, comp_W, comp_b, pch_W, pch_b, outp);
}

// Round 12
// 421.478 us; speedup vs baseline: 1.1003x; 1.0380x over previous
//
#include <hip/hip_runtime.h>
#include <math.h>

#define NN 30000          // nodes
#define NE 480000         // edges
#define FEA 16            // edge feature dim
#define HID 64
#define NG 64             // graphs
#define LEAKK 0.2f

// ---- small-constant region layout (float offsets) ----
#define S_MEANEA 0    // 16
#define S_KF1    16   // 64  (K1 [16,4])
#define S_C1     80   // 4
#define S_AEL1   84   // 4
#define S_KF2    88   // 64
#define S_C2     152  // 4
#define S_AEL2   156  // 4
#define S_MS1    160  // 512 (Ms1 [128,4])
#define S_MD1    672  // 512
#define S_MS2    1184 // 256 (Ms2 [64,4])
#define S_MD2    1440 // 256

__device__ __forceinline__ float eluf(float v) { return v > 0.f ? v : expm1f(v); }
__device__ __forceinline__ float leakyf(float v) { return v >= 0.f ? v : LEAKK * v; }
__device__ __forceinline__ void fma4(float4& a, float w, const float4& x) {
    a.x += w * x.x; a.y += w * x.y; a.z += w * x.z; a.w += w * x.w;
}

// ---- count (CSR degree, rank per edge) + mean of edge_attr ----
__global__ __launch_bounds__(256) void count_mean_kernel(
    const int* __restrict__ dst, const float* __restrict__ EA,
    int* __restrict__ cnt, int* __restrict__ rank, float* __restrict__ S) {
    __shared__ float red[1024];
    int t = threadIdx.x;
    int base = blockIdx.x * 512;
#pragma unroll
    for (int i = 0; i < 2; i++) {
        int e = base + i * 256 + t;
        if (e < NE) rank[e] = atomicAdd(&cnt[dst[e]], 1);
    }
    int c4 = t & 3;
    int rbase = base + (t >> 2);
    float4 acc = {0, 0, 0, 0};
#pragma unroll
    for (int i = 0; i < 8; i++) {
        int r = rbase + i * 64;
        if (r < NE) {
            float4 v = *(const float4*)(EA + (size_t)r * FEA + c4 * 4);
            acc.x += v.x; acc.y += v.y; acc.z += v.z; acc.w += v.w;
        }
    }
    *(float4*)&red[t * 4] = acc;
    __syncthreads();
    if (t < 16) {
        int grp = t >> 2;
        int comp = t & 3;
        float sum = 0.f;
        for (int j = 0; j < 64; j++) sum += red[(grp + 4 * j) * 4 + comp];
        atomicAdd(&S[S_MEANEA + grp * 4 + comp], sum);
    }
}

// ---- merged prep: block 0 = small attention folds; blocks 1..176 = weight layouts ----
__global__ void prep_all_kernel(
    const float* __restrict__ W1, const float* __restrict__ as1, const float* __restrict__ ad1,
    const float* __restrict__ ae1, const float* __restrict__ leW1,
    const float* __restrict__ W2, const float* __restrict__ as2, const float* __restrict__ ad2,
    const float* __restrict__ ae2, const float* __restrict__ leW2,
    const float* __restrict__ edge_W, const float* __restrict__ edge_b,
    const float* __restrict__ Wl, const float* __restrict__ Wr,
    const float* __restrict__ emb,
    float* __restrict__ S, float* __restrict__ WC1, float* __restrict__ WC2,
    float* __restrict__ B128) {
    int t = threadIdx.x;
    if (blockIdx.x > 0) {
        int i = (blockIdx.x - 1) * 256 + t;
        if (i < 16384) {            // WC1 x part
            int hk = i >> 6, c = i & 63;
            int h = hk >> 6, k = hk & 63;
            WC1[i] = 0.25f * W1[k * 256 + h * 64 + c];
        } else if (i < 20480) {     // WC1 emb part
            int j2 = i - 16384;
            int r2 = j2 >> 6, c = j2 & 63;
            int h = r2 >> 4, tau = r2 & 15;
            float v = 0.f;
            for (int j = 0; j < 64; j++)
                v += emb[tau * 64 + j] * W1[(64 + j) * 256 + h * 64 + c];
            WC1[i] = 0.25f * v;
        } else if (i < 36864) {
            int j = i - 20480;
            int hk = j >> 6, c = j & 63;
            int h = hk >> 6, k = hk & 63;
            WC2[j] = 0.25f * W2[k * 256 + h * 64 + c];
        } else if (i < 45056) {
            int j = i - 36864;
            int k = j >> 6, c = j & 63;
            B128[j] = (k < 64) ? Wl[k * 64 + c] : Wr[(k - 64) * 64 + c];
        }
        return;
    }
    __shared__ float M1[256], M2[256], meh[64];
    if (t < 16) S[S_MEANEA + t] *= (1.0f / (float)NE);
    __syncthreads();
    {
        int k = t >> 2, h = t & 3;
        float m1 = 0.f, m2 = 0.f;
        for (int c = 0; c < 64; c++) {
            m1 += leW1[k * 256 + h * 64 + c] * ae1[h * 64 + c];
            m2 += leW2[k * 256 + h * 64 + c] * ae2[h * 64 + c];
        }
        M1[t] = m1; M2[t] = m2;
    }
    if (t < 64) {
        float v = edge_b[t];
        for (int f = 0; f < FEA; f++) v += S[S_MEANEA + f] * edge_W[f * 64 + t];
        meh[t] = v;
    }
    __syncthreads();
    if (t < 64) {
        int f = t >> 2, h = t & 3;
        float k1 = 0.f, k2 = 0.f;
        for (int k = 0; k < 64; k++) {
            k1 += edge_W[f * 64 + k] * M1[k * 4 + h];
            k2 += edge_W[f * 64 + k] * M2[k * 4 + h];
        }
        S[S_KF1 + t] = k1; S[S_KF2 + t] = k2;
    } else if (t < 68) {
        int h = t - 64;
        float c1 = 0.f, c2 = 0.f, a1 = 0.f, a2 = 0.f;
        for (int k = 0; k < 64; k++) {
            c1 += edge_b[k] * M1[k * 4 + h];
            c2 += edge_b[k] * M2[k * 4 + h];
            a1 += meh[k] * M1[k * 4 + h];
            a2 += meh[k] * M2[k * 4 + h];
        }
        S[S_C1 + h] = c1; S[S_C2 + h] = c2;
        S[S_AEL1 + h] = a1; S[S_AEL2 + h] = a2;
    }
    for (int i = t; i < 512; i += 256) {
        int k = i >> 2, h = i & 3;
        float s = 0.f, d = 0.f;
        for (int c = 0; c < 64; c++) {
            float w = W1[k * 256 + h * 64 + c];
            s += w * as1[h * 64 + c];
            d += w * ad1[h * 64 + c];
        }
        S[S_MS1 + i] = s; S[S_MD1 + i] = d;
    }
    for (int i = t; i < 256; i += 256) {
        int k = i >> 2, h = i & 3;
        float s = 0.f, d = 0.f;
        for (int c = 0; c < 64; c++) {
            float w = W2[k * 256 + h * 64 + c];
            s += w * as2[h * 64 + c];
            d += w * ad2[h * 64 + c];
        }
        S[S_MS2 + i] = s; S[S_MD2 + i] = d;
    }
}

// ---- layer-1 a_s/a_d from [x | emb[type]] (h0 NOT materialized) ----
__global__ __launch_bounds__(256) void attn_h0_kernel(
    const float* __restrict__ x, const float* __restrict__ node_emb,
    const int* __restrict__ node_type, const float* __restrict__ S,
    float* __restrict__ as_, float* __restrict__ ad_) {
    __shared__ float xt[64 * 132];
    __shared__ float ms[512], md[512];
    __shared__ int ntS[64];
    int t = threadIdx.x;
    int n0 = blockIdx.x * 64;
    if (t < 64) {
        int n = n0 + t;
        ntS[t] = (n < NN) ? node_type[n] : 0;
    }
    for (int i = t; i < 512; i += 256) { ms[i] = S[S_MS1 + i]; md[i] = S[S_MD1 + i]; }
    __syncthreads();
    for (int i = t; i < 1024; i += 256) {
        int r = i >> 4, c4 = (i & 15) * 4;
        int n = n0 + r;
        float4 f = {0, 0, 0, 0};
        if (n < NN) f = *(const float4*)(x + (size_t)n * 64 + c4);
        *(float4*)&xt[r * 132 + c4] = f;
    }
    for (int i = t; i < 1024; i += 256) {
        int r = i >> 4, c4 = (i & 15) * 4;
        int n = n0 + r;
        float4 f = {0, 0, 0, 0};
        if (n < NN) f = *(const float4*)(node_emb + (size_t)ntS[r] * 64 + c4);
        *(float4*)&xt[r * 132 + 64 + c4] = f;
    }
    __syncthreads();
    int r = t >> 2, h = t & 3;
    float s = 0.f, d = 0.f;
#pragma unroll 8
    for (int k = 0; k < 128; k++) {
        float xv = xt[r * 132 + k];
        s += xv * ms[k * 4 + h];
        d += xv * md[k * 4 + h];
    }
    int n = n0 + r;
    if (n < NN) { as_[n * 4 + h] = s; ad_[n * 4 + h] = d; }
}

// ---- 3-kernel decoupled scan ----
__global__ void scan_blocks_kernel(const int* __restrict__ cnt, int* __restrict__ eoff,
                                   int* __restrict__ bsum) {
    __shared__ int wsum[16];
    int t = threadIdx.x;
    int i = blockIdx.x * 1024 + t;
    int v = (i < NN) ? cnt[i] : 0;
    int lane = t & 63;
    int incl = v;
#pragma unroll
    for (int ofs = 1; ofs < 64; ofs <<= 1) {
        int u = __shfl_up(incl, ofs, 64);
        if (lane >= ofs) incl += u;
    }
    int wid = t >> 6;
    if (lane == 63) wsum[wid] = incl;
    __syncthreads();
    if (t < 16) {
        int s = wsum[t];
#pragma unroll
        for (int ofs = 1; ofs < 16; ofs <<= 1) {
            int u = __shfl_up(s, ofs, 64);
            if (t >= ofs) s += u;
        }
        wsum[t] = s;
    }
    __syncthreads();
    int excl = incl - v + (wid > 0 ? wsum[wid - 1] : 0);
    if (i < NN) eoff[i] = excl;
    if (t == 1023) bsum[blockIdx.x] = excl + v;
}

// block 0: scan tops; block 1: goff binary search
__global__ void scan_tops_goff_kernel(const int* __restrict__ bsum, int* __restrict__ boff,
                                      int nb, const int* __restrict__ batch,
                                      int* __restrict__ goff) {
    int t = threadIdx.x;
    if (blockIdx.x == 1) {
        if (t > NG) return;
        int lo = 0, hi = NN;
        while (lo < hi) {
            int mid = (lo + hi) >> 1;
            if (batch[mid] < t) lo = mid + 1; else hi = mid;
        }
        goff[t] = lo;
        return;
    }
    if (t >= 64) return;
    int v = (t < nb) ? bsum[t] : 0;
    int incl = v;
#pragma unroll
    for (int ofs = 1; ofs < 64; ofs <<= 1) {
        int u = __shfl_up(incl, ofs, 64);
        if (t >= ofs) incl += u;
    }
    boff[t] = incl - v;
}

__global__ void scan_add_kernel(const int* __restrict__ boff, int* __restrict__ eoff) {
    int i = blockIdx.x * 256 + threadIdx.x;
    if (i < NN) eoff[i] += boff[i >> 10];
    if (i == 0) eoff[NN] = NE;
}

// ---- fused scatter + layer-1 scoring (ATOMIC-FREE: uses precomputed rank) ----
__global__ void scatter_score_kernel(const int* __restrict__ src, const int* __restrict__ dst,
                                     const float* __restrict__ EA, const float* __restrict__ S,
                                     const float* __restrict__ as_, const float* __restrict__ ad_,
                                     const int* __restrict__ node_type,
                                     const int* __restrict__ eoff, const int* __restrict__ rank,
                                     int2* __restrict__ se_sorted,
                                     float* __restrict__ sc1, float* __restrict__ ae2s) {
    int e = blockIdx.x * 256 + threadIdx.x;
    if (e >= NE) return;
    int s = src[e], d = dst[e];
    float a1[4], a2[4];
#pragma unroll
    for (int h = 0; h < 4; h++) { a1[h] = S[S_C1 + h]; a2[h] = S[S_C2 + h]; }
    const float4* EA4 = (const float4*)(EA + (size_t)e * FEA);
#pragma unroll
    for (int q = 0; q < 4; q++) {
        float4 v = EA4[q];
        float vv[4] = {v.x, v.y, v.z, v.w};
#pragma unroll
        for (int j = 0; j < 4; j++) {
            int f = q * 4 + j;
#pragma unroll
            for (int h = 0; h < 4; h++) {
                a1[h] += vv[j] * S[S_KF1 + f * 4 + h];
                a2[h] += vv[j] * S[S_KF2 + f * 4 + h];
            }
        }
    }
    ((float4*)ae2s)[e] = make_float4(a2[0], a2[1], a2[2], a2[3]);
    float4 asv = ((const float4*)as_)[s];
    float4 adv = ((const float4*)ad_)[d];
    float4 r;
    r.x = expf(leakyf(asv.x + adv.x + a1[0]));
    r.y = expf(leakyf(asv.y + adv.y + a1[1]));
    r.z = expf(leakyf(asv.z + adv.z + a1[2]));
    r.w = expf(leakyf(asv.w + adv.w + a1[3]));
    ((float4*)sc1)[e] = r;
    int ty = node_type[s];
    se_sorted[eoff[d] + rank[e]] = make_int2(s, e | (ty << 24));
}

// ---- dense layer-2 scoring: sc2[e] = exp(leaky(as2[s]+ad2[d]+ae2s[e])), coalesced ----
__global__ void score2_kernel(const int* __restrict__ src, const int* __restrict__ dst,
                              const float* __restrict__ ae2s,
                              const float* __restrict__ as_, const float* __restrict__ ad_,
                              float* __restrict__ sc2) {
    int e = blockIdx.x * 256 + threadIdx.x;
    if (e >= NE) return;
    int s = src[e], d = dst[e];
    float4 ae = ((const float4*)ae2s)[e];
    float4 asv = ((const float4*)as_)[s];
    float4 adv = ((const float4*)ad_)[d];
    float4 r;
    r.x = expf(leakyf(asv.x + adv.x + ae.x));
    r.y = expf(leakyf(asv.y + adv.y + ae.y));
    r.z = expf(leakyf(asv.z + adv.z + ae.z));
    r.w = expf(leakyf(asv.w + adv.w + ae.w));
    ((float4*)sc2)[e] = r;
}

// ---- layer-1 GAT aggregation: gather x rows (256B) + per-type weight histogram ----
__global__ __launch_bounds__(256) void agg_gat1_kernel(
    const int* __restrict__ eoff, const int2* __restrict__ se_sorted,
    const float* __restrict__ sc1, const float* __restrict__ x,
    const int* __restrict__ node_type,
    const float* __restrict__ as_, const float* __restrict__ ad_,
    const float* __restrict__ Sael, float* __restrict__ agg) {
    int n = blockIdx.x * 4 + (threadIdx.x >> 6);
    if (n >= NN) return;
    int lane = threadIdx.x & 63;
    int sub = lane >> 4, ch = lane & 15;
    const float4* X4 = (const float4*)x;
    const float4* W4 = (const float4*)sc1;
    float4 asn = ((const float4*)as_)[n];
    float4 adn = ((const float4*)ad_)[n];
    float4 a0 = {0, 0, 0, 0}, a1 = a0, a2 = a0, a3 = a0, dn = a0, tw = a0;
    int b = eoff[n], e_end = eoff[n + 1];
    int nE = e_end - b;
    int i = sub;
    for (; i + 4 < nE; i += 8) {
        int2 se0 = se_sorted[b + i], se1 = se_sorted[b + i + 4];
        int e0 = se0.y & 0xFFFFFF, t0 = se0.y >> 24;
        int e1 = se1.y & 0xFFFFFF, t1 = se1.y >> 24;
        float4 w0 = W4[e0], w1 = W4[e1];
        float4 x0 = X4[(size_t)se0.x * 16 + ch];
        float4 x1 = X4[(size_t)se1.x * 16 + ch];
        fma4(a0, w0.x, x0); fma4(a1, w0.y, x0); fma4(a2, w0.z, x0); fma4(a3, w0.w, x0);
        fma4(a0, w1.x, x1); fma4(a1, w1.y, x1); fma4(a2, w1.z, x1); fma4(a3, w1.w, x1);
        dn.x += w0.x + w1.x; dn.y += w0.y + w1.y;
        dn.z += w0.z + w1.z; dn.w += w0.w + w1.w;
        if (ch == t0) { tw.x += w0.x; tw.y += w0.y; tw.z += w0.z; tw.w += w0.w; }
        if (ch == t1) { tw.x += w1.x; tw.y += w1.y; tw.z += w1.z; tw.w += w1.w; }
    }
    for (; i < nE; i += 4) {
        int2 se0 = se_sorted[b + i];
        int e0 = se0.y & 0xFFFFFF, t0 = se0.y >> 24;
        float4 w0 = W4[e0];
        float4 x0 = X4[(size_t)se0.x * 16 + ch];
        fma4(a0, w0.x, x0); fma4(a1, w0.y, x0); fma4(a2, w0.z, x0); fma4(a3, w0.w, x0);
        dn.x += w0.x; dn.y += w0.y; dn.z += w0.z; dn.w += w0.w;
        if (ch == t0) { tw.x += w0.x; tw.y += w0.y; tw.z += w0.z; tw.w += w0.w; }
    }
    if (sub == 0) {  // self loop
        float e0 = expf(leakyf(asn.x + adn.x + Sael[0]));
        float e1 = expf(leakyf(asn.y + adn.y + Sael[1]));
        float e2 = expf(leakyf(asn.z + adn.z + Sael[2]));
        float e3 = expf(leakyf(asn.w + adn.w + Sael[3]));
        float4 xs = X4[(size_t)n * 16 + ch];
        fma4(a0, e0, xs); fma4(a1, e1, xs); fma4(a2, e2, xs); fma4(a3, e3, xs);
        dn.x += e0; dn.y += e1; dn.z += e2; dn.w += e3;
        int tn = node_type[n];
        if (ch == tn) { tw.x += e0; tw.y += e1; tw.z += e2; tw.w += e3; }
    }
#pragma unroll
    for (int mask = 16; mask < 64; mask <<= 1) {
        a0.x += __shfl_xor(a0.x, mask, 64); a0.y += __shfl_xor(a0.y, mask, 64);
        a0.z += __shfl_xor(a0.z, mask, 64); a0.w += __shfl_xor(a0.w, mask, 64);
        a1.x += __shfl_xor(a1.x, mask, 64); a1.y += __shfl_xor(a1.y, mask, 64);
        a1.z += __shfl_xor(a1.z, mask, 64); a1.w += __shfl_xor(a1.w, mask, 64);
        a2.x += __shfl_xor(a2.x, mask, 64); a2.y += __shfl_xor(a2.y, mask, 64);
        a2.z += __shfl_xor(a2.z, mask, 64); a2.w += __shfl_xor(a2.w, mask, 64);
        a3.x += __shfl_xor(a3.x, mask, 64); a3.y += __shfl_xor(a3.y, mask, 64);
        a3.z += __shfl_xor(a3.z, mask, 64); a3.w += __shfl_xor(a3.w, mask, 64);
        dn.x += __shfl_xor(dn.x, mask, 64); dn.y += __shfl_xor(dn.y, mask, 64);
        dn.z += __shfl_xor(dn.z, mask, 64); dn.w += __shfl_xor(dn.w, mask, 64);
        tw.x += __shfl_xor(tw.x, mask, 64); tw.y += __shfl_xor(tw.y, mask, 64);
        tw.z += __shfl_xor(tw.z, mask, 64); tw.w += __shfl_xor(tw.w, mask, 64);
    }
    if (sub == 0) {
        float i0 = 1.f / dn.x, i1 = 1.f / dn.y, i2 = 1.f / dn.z, i3 = 1.f / dn.w;
        float* A = agg + (size_t)n * 320;
        float4* A4 = (float4*)A;
        A4[ch]      = make_float4(a0.x * i0, a0.y * i0, a0.z * i0, a0.w * i0);
        A4[16 + ch] = make_float4(a1.x * i1, a1.y * i1, a1.z * i1, a1.w * i1);
        A4[32 + ch] = make_float4(a2.x * i2, a2.y * i2, a2.z * i2, a2.w * i2);
        A4[48 + ch] = make_float4(a3.x * i3, a3.y * i3, a3.z * i3, a3.w * i3);
        A[256 + ch]      = tw.x * i0;
        A[256 + 16 + ch] = tw.y * i1;
        A[256 + 32 + ch] = tw.z * i2;
        A[256 + 48 + ch] = tw.w * i3;
    }
}

// ---- layer-2 GAT aggregation: pure gather (scores precomputed in sc2) ----
__global__ __launch_bounds__(256) void agg_gat2_kernel(
    const int* __restrict__ eoff, const int2* __restrict__ se_sorted,
    const float* __restrict__ sc2, const float* __restrict__ X,
    const float* __restrict__ as_, const float* __restrict__ ad_,
    const float* __restrict__ Sael, float* __restrict__ agg) {
    int n = blockIdx.x * 4 + (threadIdx.x >> 6);
    if (n >= NN) return;
    int lane = threadIdx.x & 63;
    int sub = lane >> 4, ch = lane & 15;
    const float4* X4 = (const float4*)X;
    const float4* W4 = (const float4*)sc2;
    float4 asn = ((const float4*)as_)[n];
    float4 adn = ((const float4*)ad_)[n];
    float4 a0 = {0, 0, 0, 0}, a1 = a0, a2 = a0, a3 = a0, dn = a0;
    int b = eoff[n], e = eoff[n + 1];
    int nE = e - b;
    int i = sub;
    for (; i + 4 < nE; i += 8) {
        int2 se0 = se_sorted[b + i], se1 = se_sorted[b + i + 4];
        float4 w0 = W4[se0.y & 0xFFFFFF], w1 = W4[se1.y & 0xFFFFFF];
        float4 x0 = X4[(size_t)se0.x * 16 + ch];
        float4 x1 = X4[(size_t)se1.x * 16 + ch];
        fma4(a0, w0.x, x0); fma4(a1, w0.y, x0); fma4(a2, w0.z, x0); fma4(a3, w0.w, x0);
        fma4(a0, w1.x, x1); fma4(a1, w1.y, x1); fma4(a2, w1.z, x1); fma4(a3, w1.w, x1);
        dn.x += w0.x + w1.x; dn.y += w0.y + w1.y;
        dn.z += w0.z + w1.z; dn.w += w0.w + w1.w;
    }
    for (; i < nE; i += 4) {
        int2 se0 = se_sorted[b + i];
        float4 w0 = W4[se0.y & 0xFFFFFF];
        float4 x0 = X4[(size_t)se0.x * 16 + ch];
        fma4(a0, w0.x, x0); fma4(a1, w0.y, x0); fma4(a2, w0.z, x0); fma4(a3, w0.w, x0);
        dn.x += w0.x; dn.y += w0.y; dn.z += w0.z; dn.w += w0.w;
    }
    if (sub == 0) {  // self loop
        float e0 = expf(leakyf(asn.x + adn.x + Sael[0]));
        float e1 = expf(leakyf(asn.y + adn.y + Sael[1]));
        float e2 = expf(leakyf(asn.z + adn.z + Sael[2]));
        float e3 = expf(leakyf(asn.w + adn.w + Sael[3]));
        float4 xs = X4[(size_t)n * 16 + ch];
        fma4(a0, e0, xs); fma4(a1, e1, xs); fma4(a2, e2, xs); fma4(a3, e3, xs);
        dn.x += e0; dn.y += e1; dn.z += e2; dn.w += e3;
    }
#pragma unroll
    for (int mask = 16; mask < 64; mask <<= 1) {
        a0.x += __shfl_xor(a0.x, mask, 64); a0.y += __shfl_xor(a0.y, mask, 64);
        a0.z += __shfl_xor(a0.z, mask, 64); a0.w += __shfl_xor(a0.w, mask, 64);
        a1.x += __shfl_xor(a1.x, mask, 64); a1.y += __shfl_xor(a1.y, mask, 64);
        a1.z += __shfl_xor(a1.z, mask, 64); a1.w += __shfl_xor(a1.w, mask, 64);
        a2.x += __shfl_xor(a2.x, mask, 64); a2.y += __shfl_xor(a2.y, mask, 64);
        a2.z += __shfl_xor(a2.z, mask, 64); a2.w += __shfl_xor(a2.w, mask, 64);
        a3.x += __shfl_xor(a3.x, mask, 64); a3.y += __shfl_xor(a3.y, mask, 64);
        a3.z += __shfl_xor(a3.z, mask, 64); a3.w += __shfl_xor(a3.w, mask, 64);
        dn.x += __shfl_xor(dn.x, mask, 64); dn.y += __shfl_xor(dn.y, mask, 64);
        dn.z += __shfl_xor(dn.z, mask, 64); dn.w += __shfl_xor(dn.w, mask, 64);
    }
    if (sub == 0) {
        float i0 = 1.f / dn.x, i1 = 1.f / dn.y, i2 = 1.f / dn.z, i3 = 1.f / dn.w;
        float4* agg4 = (float4*)(agg + (size_t)n * 256);
        agg4[ch]      = make_float4(a0.x * i0, a0.y * i0, a0.z * i0, a0.w * i0);
        agg4[16 + ch] = make_float4(a1.x * i1, a1.y * i1, a1.z * i1, a1.w * i1);
        agg4[32 + ch] = make_float4(a2.x * i2, a2.y * i2, a2.z * i2, a2.w * i2);
        agg4[48 + ch] = make_float4(a3.x * i3, a3.y * i3, a3.z * i3, a3.w * i3);
    }
}

// ---- GEMM: out[M,64] = elu(A[M,K]@B[K,64]+bias); 64-row tiles, reg prefetch ----
template <int K, bool DOATT>
__global__ __launch_bounds__(256) void gemm64_kernel(
    const float* __restrict__ A, const float* __restrict__ B,
    const float* __restrict__ bias, float* __restrict__ out,
    const float* __restrict__ ms_g, const float* __restrict__ md_g,
    float* __restrict__ as_, float* __restrict__ ad_) {
    __shared__ float As[32 * 68];
    __shared__ float Bs[32 * 68];
    __shared__ float msS[256], mdS[256];
    int t = threadIdx.x;
    int tx = t & 15, ty = t >> 4;
    int m_base = blockIdx.x * 64;
    if (DOATT) { msS[t] = ms_g[t]; mdS[t] = md_g[t]; }
    int arow0 = t >> 3, akq0 = (t & 7) * 4;
    int arow1 = (t + 256) >> 3, akq1 = ((t + 256) & 7) * 4;
    int bkr = t >> 4, bnc = (t & 15) * 4;
    int am0 = m_base + arow0, am1 = m_base + arow1;
    float4 fa0, fa1, fb0, fb1;
    fa0 = (am0 < NN) ? *(const float4*)(A + (size_t)am0 * K + akq0) : make_float4(0, 0, 0, 0);
    fa1 = (am1 < NN) ? *(const float4*)(A + (size_t)am1 * K + akq1) : make_float4(0, 0, 0, 0);
    fb0 = *(const float4*)(B + (size_t)bkr * 64 + bnc);
    fb1 = *(const float4*)(B + (size_t)(bkr + 16) * 64 + bnc);
    float acc[4][4] = {};
    for (int k0 = 0;; k0 += 32) {
        As[(akq0 + 0) * 68 + arow0] = fa0.x;
        As[(akq0 + 1) * 68 + arow0] = fa0.y;
        As[(akq0 + 2) * 68 + arow0] = fa0.z;
        As[(akq0 + 3) * 68 + arow0] = fa0.w;
        As[(akq1 + 0) * 68 + arow1] = fa1.x;
        As[(akq1 + 1) * 68 + arow1] = fa1.y;
        As[(akq1 + 2) * 68 + arow1] = fa1.z;
        As[(akq1 + 3) * 68 + arow1] = fa1.w;
        *(float4*)&Bs[bkr * 68 + bnc] = fb0;
        *(float4*)&Bs[(bkr + 16) * 68 + bnc] = fb1;
        __syncthreads();
        bool more = (k0 + 32 < K);
        if (more) {
            int kn = k0 + 32;
            fa0 = (am0 < NN) ? *(const float4*)(A + (size_t)am0 * K + kn + akq0)
                             : make_float4(0, 0, 0, 0);
            fa1 = (am1 < NN) ? *(const float4*)(A + (size_t)am1 * K + kn + akq1)
                             : make_float4(0, 0, 0, 0);
            fb0 = *(const float4*)(B + (size_t)(kn + bkr) * 64 + bnc);
            fb1 = *(const float4*)(B + (size_t)(kn + bkr + 16) * 64 + bnc);
        }
#pragma unroll
        for (int k = 0; k < 32; k++) {
            float4 av = *(const float4*)&As[k * 68 + ty * 4];
            float4 bv = *(const float4*)&Bs[k * 68 + tx * 4];
            float a[4] = {av.x, av.y, av.z, av.w};
            float b[4] = {bv.x, bv.y, bv.z, bv.w};
#pragma unroll
            for (int i = 0; i < 4; i++)
#pragma unroll
                for (int j = 0; j < 4; j++) acc[i][j] += a[i] * b[j];
        }
        if (!more) break;
        __syncthreads();
    }
    float4 bvv = ((const float4*)bias)[tx];
    float o[4][4];
#pragma unroll
    for (int i = 0; i < 4; i++) {
        o[i][0] = eluf(acc[i][0] + bvv.x);
        o[i][1] = eluf(acc[i][1] + bvv.y);
        o[i][2] = eluf(acc[i][2] + bvv.z);
        o[i][3] = eluf(acc[i][3] + bvv.w);
        int m = m_base + ty * 4 + i;
        if (m < NN)
            *(float4*)(out + (size_t)m * 64 + tx * 4) =
                make_float4(o[i][0], o[i][1], o[i][2], o[i][3]);
    }
    if (DOATT) {
        float ps[4][4] = {}, pd[4][4] = {};
#pragma unroll
        for (int i = 0; i < 4; i++)
#pragma unroll
            for (int j = 0; j < 4; j++) {
                float v = o[i][j];
                int kk = (tx * 4 + j) * 4;
#pragma unroll
                for (int h = 0; h < 4; h++) {
                    ps[i][h] += v * msS[kk + h];
                    pd[i][h] += v * mdS[kk + h];
                }
            }
#pragma unroll
        for (int mk = 1; mk < 16; mk <<= 1) {
#pragma unroll
            for (int i = 0; i < 4; i++)
#pragma unroll
                for (int h = 0; h < 4; h++) {
                    ps[i][h] += __shfl_xor(ps[i][h], mk, 64);
                    pd[i][h] += __shfl_xor(pd[i][h], mk, 64);
                }
        }
        if (tx == 0) {
#pragma unroll
            for (int i = 0; i < 4; i++) {
                int m = m_base + ty * 4 + i;
                if (m < NN) {
                    *(float4*)(as_ + (size_t)m * 4) =
                        make_float4(ps[i][0], ps[i][1], ps[i][2], ps[i][3]);
                    *(float4*)(ad_ + (size_t)m * 4) =
                        make_float4(pd[i][0], pd[i][1], pd[i][2], pd[i][3]);
                }
            }
        }
    }
}

// ---- SAGE mean aggregation into AB[:,0:64]; copy h2 into AB[:,64:128] ----
__global__ __launch_bounds__(256) void sage_agg3_kernel(
    const float* __restrict__ h2, const int* __restrict__ eoff,
    const int2* __restrict__ se_sorted, float* __restrict__ AB) {
    int n = blockIdx.x * 16 + (threadIdx.x >> 4);
    if (n >= NN) return;
    int l = threadIdx.x & 15;
    const float4* h24 = (const float4*)h2;
    float4* AB4 = (float4*)AB;
    float ax = 0.f, ay = 0.f, az = 0.f, aw = 0.f;
    int b = eoff[n], e_end = eoff[n + 1];
    int idx = b;
    int stop = b + ((e_end - b) & ~7);
    if (idx < stop) {
        int sreg[8];
#pragma unroll
        for (int u = 0; u < 8; u++) sreg[u] = se_sorted[idx + u].x;
        idx += 8;
        while (true) {
            int sn[8];
            bool more = idx < stop;
            if (more) {
#pragma unroll
                for (int u = 0; u < 8; u++) sn[u] = se_sorted[idx + u].x;
            }
#pragma unroll
            for (int u = 0; u < 8; u++) {
                float4 v = h24[(size_t)sreg[u] * 16 + l];
                ax += v.x; ay += v.y; az += v.z; aw += v.w;
            }
            if (!more) break;
#pragma unroll
            for (int u = 0; u < 8; u++) sreg[u] = sn[u];
            idx += 8;
        }
    }
    for (; idx < e_end; idx++) {
        float4 v0 = h24[(size_t)se_sorted[idx].x * 16 + l];
        ax += v0.x; ay += v0.y; az += v0.z; aw += v0.w;
    }
    float dg = (float)(e_end - b);
    if (dg < 1.f) dg = 1.f;
    float inv = 1.f / dg;
    AB4[(size_t)n * 32 + l] = make_float4(ax * inv, ay * inv, az * inv, aw * inv);
    AB4[(size_t)n * 32 + 16 + l] = h24[(size_t)n * 16 + l];
}

// ---- fused pool + MLP head: one block per graph -> d_out[192] ----
__global__ __launch_bounds__(256) void pool_mlp_kernel(
    const float* __restrict__ h3, const int* __restrict__ goff,
    const float* __restrict__ lin1W, const float* __restrict__ lin1b,
    const float* __restrict__ lin2W, const float* __restrict__ lin2b,
    const float* __restrict__ telW, const float* __restrict__ telb,
    const float* __restrict__ compW, const float* __restrict__ compb,
    const float* __restrict__ pchW, const float* __restrict__ pchb,
    float* __restrict__ out) {
    __shared__ float red[256];
    __shared__ float g[64], G1[64], G2[64];
    int gi = blockIdx.x, t = threadIdx.x;
    int c = t & 63, li = t >> 6;
    int b = goff[gi], e = goff[gi + 1];
    float sum = 0.f;
    for (int r = b + li; r < e; r += 4) sum += h3[(size_t)r * HID + c];
    red[t] = sum;
    __syncthreads();
    if (t < 64) {
        float v = red[t] + red[t + 64] + red[t + 128] + red[t + 192];
        float cntf = (float)(e - b);
        if (cntf < 1.f) cntf = 1.f;
        g[t] = v / cntf;
    }
    __syncthreads();
    {
        float part = 0.f;
#pragma unroll
        for (int k = li * 16; k < li * 16 + 16; k++) part += g[k] * lin1W[k * 64 + c];
        red[t] = part;
        __syncthreads();
        if (t < 64)
            G1[c] = eluf(red[c] + red[c + 64] + red[c + 128] + red[c + 192] + lin1b[c]);
        __syncthreads();
    }
    {
        float part = 0.f;
#pragma unroll
        for (int k = li * 16; k < li * 16 + 16; k++) part += G1[k] * lin2W[k * 64 + c];
        red[t] = part;
        __syncthreads();
        if (t < 64)
            G2[c] = red[c] + red[c + 64] + red[c + 128] + red[c + 192] + lin2b[c];
        __syncthreads();
    }
    if (t < 192) {
        int h = t >> 6, k = t & 63;
        const float* W = (h == 0) ? telW : ((h == 1) ? compW : pchW);
        red[t] = G2[k] * W[k];
    }
    __syncthreads();
    if (t < 3) {
        float acc = 0.f;
        for (int k = 0; k < 64; k++) acc += red[t * 64 + k];
        float bb = (t == 0) ? telb[0] : ((t == 1) ? compb[0] : pchb[0]);
        out[t * 64 + gi] = acc + bb;
    }
}

extern "C" void kernel_launch(void* const* d_in, const int* in_sizes, int n_in,
                              void* d_out, int out_size, void* d_ws, size_t ws_size,
                              hipStream_t stream) {
    const float* x        = (const float*)d_in[0];
    const float* EA       = (const float*)d_in[1];
    const float* node_emb = (const float*)d_in[2];
    const float* edge_W   = (const float*)d_in[3];
    const float* edge_b   = (const float*)d_in[4];
    const float* W1       = (const float*)d_in[5];
    const float* as1      = (const float*)d_in[6];
    const float* ad1      = (const float*)d_in[7];
    const float* ae1      = (const float*)d_in[8];
    const float* leW1     = (const float*)d_in[9];
    const float* b1       = (const float*)d_in[10];
    const float* W2       = (const float*)d_in[11];
    const float* as2      = (const float*)d_in[12];
    const float* ad2      = (const float*)d_in[13];
    const float* ae2      = (const float*)d_in[14];
    const float* leW2     = (const float*)d_in[15];
    const float* b2       = (const float*)d_in[16];
    const float* sage_Wl  = (const float*)d_in[17];
    const float* sage_bl  = (const float*)d_in[18];
    const float* sage_Wr  = (const float*)d_in[19];
    const float* lin1_W   = (const float*)d_in[20];
    const float* lin1_b   = (const float*)d_in[21];
    const float* lin2_W   = (const float*)d_in[22];
    const float* lin2_b   = (const float*)d_in[23];
    const float* tel_W    = (const float*)d_in[24];
    const float* tel_b    = (const float*)d_in[25];
    const float* comp_W   = (const float*)d_in[26];
    const float* comp_b   = (const float*)d_in[27];
    const float* pch_W    = (const float*)d_in[28];
    const float* pch_b    = (const float*)d_in[29];
    const int* edge_index = (const int*)d_in[30];
    const int* batch      = (const int*)d_in[31];
    const int* node_type  = (const int*)d_in[32];
    float* outp = (float*)d_out;

    const int* srcp = edge_index;
    const int* dstp = edge_index + NE;

    float* wf = (float*)d_ws;
    constexpr size_t OFF_H3    = 0;                               // N*64
    constexpr size_t OFF_AGG   = OFF_H3 + (size_t)NN * 64;        // N*512 (agg1[320]/agg2[256]/AB)
    constexpr size_t OFF_H1    = OFF_AGG + (size_t)NN * 512;      // N*64
    constexpr size_t OFF_H2    = OFF_H1 + (size_t)NN * 64;        // N*64
    constexpr size_t OFF_SC    = OFF_H2 + (size_t)NN * 64;        // E*4 (sc1 then sc2)
    constexpr size_t OFF_AE2   = OFF_SC + (size_t)NE * 4;         // E*4
    constexpr size_t OFF_AS    = OFF_AE2 + (size_t)NE * 4;        // N*4
    constexpr size_t OFF_AD    = OFF_AS + (size_t)NN * 4;         // N*4
    constexpr size_t OFF_SMALL = OFF_AD + (size_t)NN * 4;         // 4096
    constexpr size_t OFF_WC1   = OFF_SMALL + 4096;                // 20480
    constexpr size_t OFF_WC2   = OFF_WC1 + 20480;                 // 16384
    constexpr size_t OFF_B128  = OFF_WC2 + 16384;                 // 8192
    constexpr size_t F_TOTAL   = OFF_B128 + 8192;

    int* wi         = (int*)(wf + F_TOTAL);
    int* cnt        = wi;                        // N
    int* rank       = wi + NN;                   // E
    int* eoff       = rank + NE;                 // N+1
    int2* se_sorted = (int2*)(eoff + (NN + 2));  // E int2 (8B aligned)
    int* goff       = (int*)(se_sorted + NE);    // NG+1
    int* bsum       = goff + (NG + 1);           // 64
    int* boff       = bsum + 64;                 // 64

    float* h3    = wf + OFF_H3;
    float* aggb  = wf + OFF_AGG;
    float* h1    = wf + OFF_H1;
    float* h2    = wf + OFF_H2;
    float* sc    = wf + OFF_SC;
    float* ae2s  = wf + OFF_AE2;
    float* as_   = wf + OFF_AS;
    float* ad_   = wf + OFF_AD;
    float* S     = wf + OFF_SMALL;
    float* WC1   = wf + OFF_WC1;
    float* WC2   = wf + OFF_WC2;
    float* B128  = wf + OFF_B128;
    float* AB    = wf + OFF_AGG;                 // alias

    hipMemsetAsync(S + S_MEANEA, 0, 16 * sizeof(float), stream);
    hipMemsetAsync(cnt, 0, NN * sizeof(int), stream);

    count_mean_kernel<<<(NE + 511) / 512, 256, 0, stream>>>(dstp, EA, cnt, rank, S);
    prep_all_kernel<<<177, 256, 0, stream>>>(W1, as1, ad1, ae1, leW1,
                                             W2, as2, ad2, ae2, leW2,
                                             edge_W, edge_b, sage_Wl, sage_Wr, node_emb,
                                             S, WC1, WC2, B128);
    {
        int nb = (NN + 1023) / 1024;  // 30
        scan_blocks_kernel<<<nb, 1024, 0, stream>>>(cnt, eoff, bsum);
        scan_tops_goff_kernel<<<2, 128, 0, stream>>>(bsum, boff, nb, batch, goff);
        scan_add_kernel<<<(NN + 255) / 256, 256, 0, stream>>>(boff, eoff);
    }
    attn_h0_kernel<<<(NN + 63) / 64, 256, 0, stream>>>(x, node_emb, node_type, S, as_, ad_);
    scatter_score_kernel<<<(NE + 255) / 256, 256, 0, stream>>>(
        srcp, dstp, EA, S, as_, ad_, node_type, eoff, rank, se_sorted, sc, ae2s);

    // ----- GAT layer 1: x-gather + type histogram -> K=320 projection -----
    agg_gat1_kernel<<<(NN + 3) / 4, 256, 0, stream>>>(
        eoff, se_sorted, sc, x, node_type, as_, ad_, S + S_AEL1, aggb);
    gemm64_kernel<320, true><<<(NN + 63) / 64, 256, 0, stream>>>(
        aggb, WC1, b1, h1, S + S_MS2, S + S_MD2, as_, ad_);

    // ----- GAT layer 2: dense score pass then pure gather -----
    score2_kernel<<<(NE + 255) / 256, 256, 0, stream>>>(srcp, dstp, ae2s, as_, ad_, sc);
    agg_gat2_kernel<<<(NN + 3) / 4, 256, 0, stream>>>(
        eoff, se_sorted, sc, h1, as_, ad_, S + S_AEL2, aggb);
    gemm64_kernel<256, false><<<(NN + 63) / 64, 256, 0, stream>>>(
        aggb, WC2, b2, h2, nullptr, nullptr, nullptr, nullptr);

    // ----- SAGE -----
    sage_agg3_kernel<<<(NN + 15) / 16, 256, 0, stream>>>(h2, eoff, se_sorted, AB);
    gemm64_kernel<128, false><<<(NN + 63) / 64, 256, 0, stream>>>(
        AB, B128, sage_bl, h3, nullptr, nullptr, nullptr, nullptr);

    // ----- fused pool + MLP head -----
    pool_mlp_kernel<<<NG, 256, 0, stream>>>(h3, goff, lin1_W, lin1_b, lin2_W, lin2_b,
                                            tel_W, tel_b, comp_W, comp_b, pch_W, pch_b, outp);
}

// Round 13
// 411.466 us; speedup vs baseline: 1.1271x; 1.0243x over previous
//
#include <hip/hip_runtime.h>
#include <math.h>

#define NN 30000          // nodes
#define NE 480000         // edges
#define FEA 16            // edge feature dim
#define HID 64
#define NG 64             // graphs
#define LEAKK 0.2f

// ---- small-constant region layout (float offsets) ----
#define S_MEANEA 0    // 16
#define S_KF1    16   // 64  (K1 [16,4])
#define S_C1     80   // 4
#define S_AEL1   84   // 4
#define S_KF2    88   // 64
#define S_C2     152  // 4
#define S_AEL2   156  // 4
#define S_MS1    160  // 512 (Ms1 [128,4])
#define S_MD1    672  // 512
#define S_MS2    1184 // 256 (Ms2 [64,4])
#define S_MD2    1440 // 256

__device__ __forceinline__ float eluf(float v) { return v > 0.f ? v : expm1f(v); }
__device__ __forceinline__ float leakyf(float v) { return v >= 0.f ? v : LEAKK * v; }
__device__ __forceinline__ void fma4(float4& a, float w, const float4& x) {
    a.x += w * x.x; a.y += w * x.y; a.z += w * x.z; a.w += w * x.w;
}

// ---- merged: blocks 0..175 weight-layout build; blocks 176.. count+rank+mean ----
__global__ __launch_bounds__(256) void cm_prepw_kernel(
    const int* __restrict__ dst, const float* __restrict__ EA,
    int* __restrict__ cnt, int* __restrict__ rank, float* __restrict__ S,
    const float* __restrict__ W1, const float* __restrict__ W2,
    const float* __restrict__ Wl, const float* __restrict__ Wr,
    const float* __restrict__ emb,
    float* __restrict__ WC1, float* __restrict__ WC2, float* __restrict__ B128) {
    __shared__ float red[1024];
    int t = threadIdx.x;
    if (blockIdx.x < 176) {
        int i = blockIdx.x * 256 + t;
        if (i < 16384) {            // WC1 x part
            int hk = i >> 6, c = i & 63;
            int h = hk >> 6, k = hk & 63;
            WC1[i] = 0.25f * W1[k * 256 + h * 64 + c];
        } else if (i < 20480) {     // WC1 emb part
            int j2 = i - 16384;
            int r2 = j2 >> 6, c = j2 & 63;
            int h = r2 >> 4, tau = r2 & 15;
            float v = 0.f;
            for (int j = 0; j < 64; j++)
                v += emb[tau * 64 + j] * W1[(64 + j) * 256 + h * 64 + c];
            WC1[i] = 0.25f * v;
        } else if (i < 36864) {
            int j = i - 20480;
            int hk = j >> 6, c = j & 63;
            int h = hk >> 6, k = hk & 63;
            WC2[j] = 0.25f * W2[k * 256 + h * 64 + c];
        } else if (i < 45056) {
            int j = i - 36864;
            int k = j >> 6, c = j & 63;
            B128[j] = (k < 64) ? Wl[k * 64 + c] : Wr[(k - 64) * 64 + c];
        }
        return;
    }
    int base = (blockIdx.x - 176) * 512;
#pragma unroll
    for (int i = 0; i < 2; i++) {
        int e = base + i * 256 + t;
        if (e < NE) rank[e] = atomicAdd(&cnt[dst[e]], 1);
    }
    int c4 = t & 3;
    int rbase = base + (t >> 2);
    float4 acc = {0, 0, 0, 0};
#pragma unroll
    for (int i = 0; i < 8; i++) {
        int r = rbase + i * 64;
        if (r < NE) {
            float4 v = *(const float4*)(EA + (size_t)r * FEA + c4 * 4);
            acc.x += v.x; acc.y += v.y; acc.z += v.z; acc.w += v.w;
        }
    }
    *(float4*)&red[t * 4] = acc;
    __syncthreads();
    if (t < 16) {
        int grp = t >> 2;
        int comp = t & 3;
        float sum = 0.f;
        for (int j = 0; j < 64; j++) sum += red[(grp + 4 * j) * 4 + comp];
        atomicAdd(&S[S_MEANEA + grp * 4 + comp], sum);
    }
}

// ---- 30-block scan over degree counts ----
__global__ void scan_blocks_kernel(const int* __restrict__ cnt, int* __restrict__ eoff,
                                   int* __restrict__ bsum) {
    __shared__ int wsum[16];
    int t = threadIdx.x;
    int i = blockIdx.x * 1024 + t;
    int v = (i < NN) ? cnt[i] : 0;
    int lane = t & 63;
    int incl = v;
#pragma unroll
    for (int ofs = 1; ofs < 64; ofs <<= 1) {
        int u = __shfl_up(incl, ofs, 64);
        if (lane >= ofs) incl += u;
    }
    int wid = t >> 6;
    if (lane == 63) wsum[wid] = incl;
    __syncthreads();
    if (t < 16) {
        int s = wsum[t];
#pragma unroll
        for (int ofs = 1; ofs < 16; ofs <<= 1) {
            int u = __shfl_up(s, ofs, 64);
            if (t >= ofs) s += u;
        }
        wsum[t] = s;
    }
    __syncthreads();
    int excl = incl - v + (wid > 0 ? wsum[wid - 1] : 0);
    if (i < NN) eoff[i] = excl;
    if (t == 1023) bsum[blockIdx.x] = excl + v;
}

// ---- merged: block 0 scan-tops; block 1 goff; block 2 prep_small folds ----
__global__ void tops_goff_prep_kernel(
    const int* __restrict__ bsum, int* __restrict__ boff, int nb,
    const int* __restrict__ batch, int* __restrict__ goff,
    const float* __restrict__ W1, const float* __restrict__ as1, const float* __restrict__ ad1,
    const float* __restrict__ ae1, const float* __restrict__ leW1,
    const float* __restrict__ W2, const float* __restrict__ as2, const float* __restrict__ ad2,
    const float* __restrict__ ae2, const float* __restrict__ leW2,
    const float* __restrict__ edge_W, const float* __restrict__ edge_b,
    float* __restrict__ S) {
    __shared__ float M1[256], M2[256], meh[64];
    int t = threadIdx.x;
    if (blockIdx.x == 0) {
        if (t >= 64) return;
        int v = (t < nb) ? bsum[t] : 0;
        int incl = v;
#pragma unroll
        for (int ofs = 1; ofs < 64; ofs <<= 1) {
            int u = __shfl_up(incl, ofs, 64);
            if (t >= ofs) incl += u;
        }
        boff[t] = incl - v;
        return;
    }
    if (blockIdx.x == 1) {
        if (t > NG) return;
        int lo = 0, hi = NN;
        while (lo < hi) {
            int mid = (lo + hi) >> 1;
            if (batch[mid] < t) lo = mid + 1; else hi = mid;
        }
        goff[t] = lo;
        return;
    }
    // block 2: prep_small (count_mean finished in previous kernel)
    if (t < 16) S[S_MEANEA + t] *= (1.0f / (float)NE);
    __syncthreads();
    {
        int k = t >> 2, h = t & 3;
        float m1 = 0.f, m2 = 0.f;
        for (int c = 0; c < 64; c++) {
            m1 += leW1[k * 256 + h * 64 + c] * ae1[h * 64 + c];
            m2 += leW2[k * 256 + h * 64 + c] * ae2[h * 64 + c];
        }
        M1[t] = m1; M2[t] = m2;
    }
    if (t < 64) {
        float v = edge_b[t];
        for (int f = 0; f < FEA; f++) v += S[S_MEANEA + f] * edge_W[f * 64 + t];
        meh[t] = v;
    }
    __syncthreads();
    if (t < 64) {
        int f = t >> 2, h = t & 3;
        float k1 = 0.f, k2 = 0.f;
        for (int k = 0; k < 64; k++) {
            k1 += edge_W[f * 64 + k] * M1[k * 4 + h];
            k2 += edge_W[f * 64 + k] * M2[k * 4 + h];
        }
        S[S_KF1 + t] = k1; S[S_KF2 + t] = k2;
    } else if (t < 68) {
        int h = t - 64;
        float c1 = 0.f, c2 = 0.f, a1 = 0.f, a2 = 0.f;
        for (int k = 0; k < 64; k++) {
            c1 += edge_b[k] * M1[k * 4 + h];
            c2 += edge_b[k] * M2[k * 4 + h];
            a1 += meh[k] * M1[k * 4 + h];
            a2 += meh[k] * M2[k * 4 + h];
        }
        S[S_C1 + h] = c1; S[S_C2 + h] = c2;
        S[S_AEL1 + h] = a1; S[S_AEL2 + h] = a2;
    }
    for (int i = t; i < 512; i += 256) {
        int k = i >> 2, h = i & 3;
        float s = 0.f, d = 0.f;
        for (int c = 0; c < 64; c++) {
            float w = W1[k * 256 + h * 64 + c];
            s += w * as1[h * 64 + c];
            d += w * ad1[h * 64 + c];
        }
        S[S_MS1 + i] = s; S[S_MD1 + i] = d;
    }
    for (int i = t; i < 256; i += 256) {
        int k = i >> 2, h = i & 3;
        float s = 0.f, d = 0.f;
        for (int c = 0; c < 64; c++) {
            float w = W2[k * 256 + h * 64 + c];
            s += w * as2[h * 64 + c];
            d += w * ad2[h * 64 + c];
        }
        S[S_MS2 + i] = s; S[S_MD2 + i] = d;
    }
}

// ---- merged: blocks 0..117 scan-add; blocks 118.. layer-1 a_s/a_d ----
__global__ __launch_bounds__(256) void scanadd_attn_kernel(
    const int* __restrict__ boff, int* __restrict__ eoff,
    const float* __restrict__ x, const float* __restrict__ node_emb,
    const int* __restrict__ node_type, const float* __restrict__ S,
    float* __restrict__ as_, float* __restrict__ ad_) {
    __shared__ float xt[64 * 132];
    __shared__ float ms[512], md[512];
    __shared__ int ntS[64];
    int t = threadIdx.x;
    if (blockIdx.x < 118) {
        int i = blockIdx.x * 256 + t;
        if (i < NN) eoff[i] += boff[i >> 10];
        if (i == 0) eoff[NN] = NE;
        return;
    }
    int n0 = (blockIdx.x - 118) * 64;
    if (t < 64) {
        int n = n0 + t;
        ntS[t] = (n < NN) ? node_type[n] : 0;
    }
    for (int i = t; i < 512; i += 256) { ms[i] = S[S_MS1 + i]; md[i] = S[S_MD1 + i]; }
    __syncthreads();
    for (int i = t; i < 1024; i += 256) {
        int r = i >> 4, c4 = (i & 15) * 4;
        int n = n0 + r;
        float4 f = {0, 0, 0, 0};
        if (n < NN) f = *(const float4*)(x + (size_t)n * 64 + c4);
        *(float4*)&xt[r * 132 + c4] = f;
    }
    for (int i = t; i < 1024; i += 256) {
        int r = i >> 4, c4 = (i & 15) * 4;
        int n = n0 + r;
        float4 f = {0, 0, 0, 0};
        if (n < NN) f = *(const float4*)(node_emb + (size_t)ntS[r] * 64 + c4);
        *(float4*)&xt[r * 132 + 64 + c4] = f;
    }
    __syncthreads();
    int r = t >> 2, h = t & 3;
    float s = 0.f, d = 0.f;
#pragma unroll 8
    for (int k = 0; k < 128; k++) {
        float xv = xt[r * 132 + k];
        s += xv * ms[k * 4 + h];
        d += xv * md[k * 4 + h];
    }
    int n = n0 + r;
    if (n < NN) { as_[n * 4 + h] = s; ad_[n * 4 + h] = d; }
}

// ---- fused scatter + layer-1 scoring (atomic-free via rank) ----
__global__ void scatter_score_kernel(const int* __restrict__ src, const int* __restrict__ dst,
                                     const float* __restrict__ EA, const float* __restrict__ S,
                                     const float* __restrict__ as_, const float* __restrict__ ad_,
                                     const int* __restrict__ node_type,
                                     const int* __restrict__ eoff, const int* __restrict__ rank,
                                     int2* __restrict__ se_sorted,
                                     float* __restrict__ sc1, float* __restrict__ ae2s) {
    int e = blockIdx.x * 256 + threadIdx.x;
    if (e >= NE) return;
    int s = src[e], d = dst[e];
    float a1[4], a2[4];
#pragma unroll
    for (int h = 0; h < 4; h++) { a1[h] = S[S_C1 + h]; a2[h] = S[S_C2 + h]; }
    const float4* EA4 = (const float4*)(EA + (size_t)e * FEA);
#pragma unroll
    for (int q = 0; q < 4; q++) {
        float4 v = EA4[q];
        float vv[4] = {v.x, v.y, v.z, v.w};
#pragma unroll
        for (int j = 0; j < 4; j++) {
            int f = q * 4 + j;
#pragma unroll
            for (int h = 0; h < 4; h++) {
                a1[h] += vv[j] * S[S_KF1 + f * 4 + h];
                a2[h] += vv[j] * S[S_KF2 + f * 4 + h];
            }
        }
    }
    ((float4*)ae2s)[e] = make_float4(a2[0], a2[1], a2[2], a2[3]);
    float4 asv = ((const float4*)as_)[s];
    float4 adv = ((const float4*)ad_)[d];
    float4 r;
    r.x = expf(leakyf(asv.x + adv.x + a1[0]));
    r.y = expf(leakyf(asv.y + adv.y + a1[1]));
    r.z = expf(leakyf(asv.z + adv.z + a1[2]));
    r.w = expf(leakyf(asv.w + adv.w + a1[3]));
    ((float4*)sc1)[e] = r;
    int ty = node_type[s];
    se_sorted[eoff[d] + rank[e]] = make_int2(s, e | (ty << 24));
}

// ---- dense layer-2 scoring ----
__global__ void score2_kernel(const int* __restrict__ src, const int* __restrict__ dst,
                              const float* __restrict__ ae2s,
                              const float* __restrict__ as_, const float* __restrict__ ad_,
                              float* __restrict__ sc2) {
    int e = blockIdx.x * 256 + threadIdx.x;
    if (e >= NE) return;
    int s = src[e], d = dst[e];
    float4 ae = ((const float4*)ae2s)[e];
    float4 asv = ((const float4*)as_)[s];
    float4 adv = ((const float4*)ad_)[d];
    float4 r;
    r.x = expf(leakyf(asv.x + adv.x + ae.x));
    r.y = expf(leakyf(asv.y + adv.y + ae.y));
    r.z = expf(leakyf(asv.z + adv.z + ae.z));
    r.w = expf(leakyf(asv.w + adv.w + ae.w));
    ((float4*)sc2)[e] = r;
}

// ---- layer-1 GAT aggregation: gather x rows + per-type weight histogram ----
__global__ __launch_bounds__(256) void agg_gat1_kernel(
    const int* __restrict__ eoff, const int2* __restrict__ se_sorted,
    const float* __restrict__ sc1, const float* __restrict__ x,
    const int* __restrict__ node_type,
    const float* __restrict__ as_, const float* __restrict__ ad_,
    const float* __restrict__ Sael, float* __restrict__ agg) {
    int n = blockIdx.x * 4 + (threadIdx.x >> 6);
    if (n >= NN) return;
    int lane = threadIdx.x & 63;
    int sub = lane >> 4, ch = lane & 15;
    const float4* X4 = (const float4*)x;
    const float4* W4 = (const float4*)sc1;
    float4 asn = ((const float4*)as_)[n];
    float4 adn = ((const float4*)ad_)[n];
    float4 a0 = {0, 0, 0, 0}, a1 = a0, a2 = a0, a3 = a0, dn = a0, tw = a0;
    int b = eoff[n], e_end = eoff[n + 1];
    int nE = e_end - b;
    int i = sub;
    for (; i + 4 < nE; i += 8) {
        int2 se0 = se_sorted[b + i], se1 = se_sorted[b + i + 4];
        int e0 = se0.y & 0xFFFFFF, t0 = se0.y >> 24;
        int e1 = se1.y & 0xFFFFFF, t1 = se1.y >> 24;
        float4 w0 = W4[e0], w1 = W4[e1];
        float4 x0 = X4[(size_t)se0.x * 16 + ch];
        float4 x1 = X4[(size_t)se1.x * 16 + ch];
        fma4(a0, w0.x, x0); fma4(a1, w0.y, x0); fma4(a2, w0.z, x0); fma4(a3, w0.w, x0);
        fma4(a0, w1.x, x1); fma4(a1, w1.y, x1); fma4(a2, w1.z, x1); fma4(a3, w1.w, x1);
        dn.x += w0.x + w1.x; dn.y += w0.y + w1.y;
        dn.z += w0.z + w1.z; dn.w += w0.w + w1.w;
        if (ch == t0) { tw.x += w0.x; tw.y += w0.y; tw.z += w0.z; tw.w += w0.w; }
        if (ch == t1) { tw.x += w1.x; tw.y += w1.y; tw.z += w1.z; tw.w += w1.w; }
    }
    for (; i < nE; i += 4) {
        int2 se0 = se_sorted[b + i];
        int e0 = se0.y & 0xFFFFFF, t0 = se0.y >> 24;
        float4 w0 = W4[e0];
        float4 x0 = X4[(size_t)se0.x * 16 + ch];
        fma4(a0, w0.x, x0); fma4(a1, w0.y, x0); fma4(a2, w0.z, x0); fma4(a3, w0.w, x0);
        dn.x += w0.x; dn.y += w0.y; dn.z += w0.z; dn.w += w0.w;
        if (ch == t0) { tw.x += w0.x; tw.y += w0.y; tw.z += w0.z; tw.w += w0.w; }
    }
    if (sub == 0) {  // self loop
        float e0 = expf(leakyf(asn.x + adn.x + Sael[0]));
        float e1 = expf(leakyf(asn.y + adn.y + Sael[1]));
        float e2 = expf(leakyf(asn.z + adn.z + Sael[2]));
        float e3 = expf(leakyf(asn.w + adn.w + Sael[3]));
        float4 xs = X4[(size_t)n * 16 + ch];
        fma4(a0, e0, xs); fma4(a1, e1, xs); fma4(a2, e2, xs); fma4(a3, e3, xs);
        dn.x += e0; dn.y += e1; dn.z += e2; dn.w += e3;
        int tn = node_type[n];
        if (ch == tn) { tw.x += e0; tw.y += e1; tw.z += e2; tw.w += e3; }
    }
#pragma unroll
    for (int mask = 16; mask < 64; mask <<= 1) {
        a0.x += __shfl_xor(a0.x, mask, 64); a0.y += __shfl_xor(a0.y, mask, 64);
        a0.z += __shfl_xor(a0.z, mask, 64); a0.w += __shfl_xor(a0.w, mask, 64);
        a1.x += __shfl_xor(a1.x, mask, 64); a1.y += __shfl_xor(a1.y, mask, 64);
        a1.z += __shfl_xor(a1.z, mask, 64); a1.w += __shfl_xor(a1.w, mask, 64);
        a2.x += __shfl_xor(a2.x, mask, 64); a2.y += __shfl_xor(a2.y, mask, 64);
        a2.z += __shfl_xor(a2.z, mask, 64); a2.w += __shfl_xor(a2.w, mask, 64);
        a3.x += __shfl_xor(a3.x, mask, 64); a3.y += __shfl_xor(a3.y, mask, 64);
        a3.z += __shfl_xor(a3.z, mask, 64); a3.w += __shfl_xor(a3.w, mask, 64);
        dn.x += __shfl_xor(dn.x, mask, 64); dn.y += __shfl_xor(dn.y, mask, 64);
        dn.z += __shfl_xor(dn.z, mask, 64); dn.w += __shfl_xor(dn.w, mask, 64);
        tw.x += __shfl_xor(tw.x, mask, 64); tw.y += __shfl_xor(tw.y, mask, 64);
        tw.z += __shfl_xor(tw.z, mask, 64); tw.w += __shfl_xor(tw.w, mask, 64);
    }
    if (sub == 0) {
        float i0 = 1.f / dn.x, i1 = 1.f / dn.y, i2 = 1.f / dn.z, i3 = 1.f / dn.w;
        float* A = agg + (size_t)n * 320;
        float4* A4 = (float4*)A;
        A4[ch]      = make_float4(a0.x * i0, a0.y * i0, a0.z * i0, a0.w * i0);
        A4[16 + ch] = make_float4(a1.x * i1, a1.y * i1, a1.z * i1, a1.w * i1);
        A4[32 + ch] = make_float4(a2.x * i2, a2.y * i2, a2.z * i2, a2.w * i2);
        A4[48 + ch] = make_float4(a3.x * i3, a3.y * i3, a3.z * i3, a3.w * i3);
        A[256 + ch]      = tw.x * i0;
        A[256 + 16 + ch] = tw.y * i1;
        A[256 + 32 + ch] = tw.z * i2;
        A[256 + 48 + ch] = tw.w * i3;
    }
}

// ---- layer-2 GAT aggregation: pure gather ----
__global__ __launch_bounds__(256) void agg_gat2_kernel(
    const int* __restrict__ eoff, const int2* __restrict__ se_sorted,
    const float* __restrict__ sc2, const float* __restrict__ X,
    const float* __restrict__ as_, const float* __restrict__ ad_,
    const float* __restrict__ Sael, float* __restrict__ agg) {
    int n = blockIdx.x * 4 + (threadIdx.x >> 6);
    if (n >= NN) return;
    int lane = threadIdx.x & 63;
    int sub = lane >> 4, ch = lane & 15;
    const float4* X4 = (const float4*)X;
    const float4* W4 = (const float4*)sc2;
    float4 asn = ((const float4*)as_)[n];
    float4 adn = ((const float4*)ad_)[n];
    float4 a0 = {0, 0, 0, 0}, a1 = a0, a2 = a0, a3 = a0, dn = a0;
    int b = eoff[n], e = eoff[n + 1];
    int nE = e - b;
    int i = sub;
    for (; i + 4 < nE; i += 8) {
        int2 se0 = se_sorted[b + i], se1 = se_sorted[b + i + 4];
        float4 w0 = W4[se0.y & 0xFFFFFF], w1 = W4[se1.y & 0xFFFFFF];
        float4 x0 = X4[(size_t)se0.x * 16 + ch];
        float4 x1 = X4[(size_t)se1.x * 16 + ch];
        fma4(a0, w0.x, x0); fma4(a1, w0.y, x0); fma4(a2, w0.z, x0); fma4(a3, w0.w, x0);
        fma4(a0, w1.x, x1); fma4(a1, w1.y, x1); fma4(a2, w1.z, x1); fma4(a3, w1.w, x1);
        dn.x += w0.x + w1.x; dn.y += w0.y + w1.y;
        dn.z += w0.z + w1.z; dn.w += w0.w + w1.w;
    }
    for (; i < nE; i += 4) {
        int2 se0 = se_sorted[b + i];
        float4 w0 = W4[se0.y & 0xFFFFFF];
        float4 x0 = X4[(size_t)se0.x * 16 + ch];
        fma4(a0, w0.x, x0); fma4(a1, w0.y, x0); fma4(a2, w0.z, x0); fma4(a3, w0.w, x0);
        dn.x += w0.x; dn.y += w0.y; dn.z += w0.z; dn.w += w0.w;
    }
    if (sub == 0) {  // self loop
        float e0 = expf(leakyf(asn.x + adn.x + Sael[0]));
        float e1 = expf(leakyf(asn.y + adn.y + Sael[1]));
        float e2 = expf(leakyf(asn.z + adn.z + Sael[2]));
        float e3 = expf(leakyf(asn.w + adn.w + Sael[3]));
        float4 xs = X4[(size_t)n * 16 + ch];
        fma4(a0, e0, xs); fma4(a1, e1, xs); fma4(a2, e2, xs); fma4(a3, e3, xs);
        dn.x += e0; dn.y += e1; dn.z += e2; dn.w += e3;
    }
#pragma unroll
    for (int mask = 16; mask < 64; mask <<= 1) {
        a0.x += __shfl_xor(a0.x, mask, 64); a0.y += __shfl_xor(a0.y, mask, 64);
        a0.z += __shfl_xor(a0.z, mask, 64); a0.w += __shfl_xor(a0.w, mask, 64);
        a1.x += __shfl_xor(a1.x, mask, 64); a1.y += __shfl_xor(a1.y, mask, 64);
        a1.z += __shfl_xor(a1.z, mask, 64); a1.w += __shfl_xor(a1.w, mask, 64);
        a2.x += __shfl_xor(a2.x, mask, 64); a2.y += __shfl_xor(a2.y, mask, 64);
        a2.z += __shfl_xor(a2.z, mask, 64); a2.w += __shfl_xor(a2.w, mask, 64);
        a3.x += __shfl_xor(a3.x, mask, 64); a3.y += __shfl_xor(a3.y, mask, 64);
        a3.z += __shfl_xor(a3.z, mask, 64); a3.w += __shfl_xor(a3.w, mask, 64);
        dn.x += __shfl_xor(dn.x, mask, 64); dn.y += __shfl_xor(dn.y, mask, 64);
        dn.z += __shfl_xor(dn.z, mask, 64); dn.w += __shfl_xor(dn.w, mask, 64);
    }
    if (sub == 0) {
        float i0 = 1.f / dn.x, i1 = 1.f / dn.y, i2 = 1.f / dn.z, i3 = 1.f / dn.w;
        float4* agg4 = (float4*)(agg + (size_t)n * 256);
        agg4[ch]      = make_float4(a0.x * i0, a0.y * i0, a0.z * i0, a0.w * i0);
        agg4[16 + ch] = make_float4(a1.x * i1, a1.y * i1, a1.z * i1, a1.w * i1);
        agg4[32 + ch] = make_float4(a2.x * i2, a2.y * i2, a2.z * i2, a2.w * i2);
        agg4[48 + ch] = make_float4(a3.x * i3, a3.y * i3, a3.z * i3, a3.w * i3);
    }
}

// ---- GEMM: out[M,64] = elu(A[M,K]@B[K,64]+bias); 64-row tiles,
//      double-buffered LDS (one barrier per chunk) + register prefetch ----
template <int K, bool DOATT>
__global__ __launch_bounds__(256) void gemm64_kernel(
    const float* __restrict__ A, const float* __restrict__ B,
    const float* __restrict__ bias, float* __restrict__ out,
    const float* __restrict__ ms_g, const float* __restrict__ md_g,
    float* __restrict__ as_, float* __restrict__ ad_) {
    __shared__ float As[2][32 * 68];
    __shared__ float Bs[2][32 * 68];
    __shared__ float msS[256], mdS[256];
    int t = threadIdx.x;
    int tx = t & 15, ty = t >> 4;
    int m_base = blockIdx.x * 64;
    if (DOATT) { msS[t] = ms_g[t]; mdS[t] = md_g[t]; }
    int arow0 = t >> 3, akq0 = (t & 7) * 4;
    int arow1 = (t + 256) >> 3, akq1 = ((t + 256) & 7) * 4;
    int bkr = t >> 4, bnc = (t & 15) * 4;
    int am0 = m_base + arow0, am1 = m_base + arow1;
    float4 fa0, fa1, fb0, fb1;
    fa0 = (am0 < NN) ? *(const float4*)(A + (size_t)am0 * K + akq0) : make_float4(0, 0, 0, 0);
    fa1 = (am1 < NN) ? *(const float4*)(A + (size_t)am1 * K + akq1) : make_float4(0, 0, 0, 0);
    fb0 = *(const float4*)(B + (size_t)bkr * 64 + bnc);
    fb1 = *(const float4*)(B + (size_t)(bkr + 16) * 64 + bnc);
    As[0][(akq0 + 0) * 68 + arow0] = fa0.x;
    As[0][(akq0 + 1) * 68 + arow0] = fa0.y;
    As[0][(akq0 + 2) * 68 + arow0] = fa0.z;
    As[0][(akq0 + 3) * 68 + arow0] = fa0.w;
    As[0][(akq1 + 0) * 68 + arow1] = fa1.x;
    As[0][(akq1 + 1) * 68 + arow1] = fa1.y;
    As[0][(akq1 + 2) * 68 + arow1] = fa1.z;
    As[0][(akq1 + 3) * 68 + arow1] = fa1.w;
    *(float4*)&Bs[0][bkr * 68 + bnc] = fb0;
    *(float4*)&Bs[0][(bkr + 16) * 68 + bnc] = fb1;
    __syncthreads();
    float acc[4][4] = {};
    int cur = 0;
    for (int k0 = 0;; k0 += 32) {
        bool more = (k0 + 32 < K);
        if (more) {
            int kn = k0 + 32;
            fa0 = (am0 < NN) ? *(const float4*)(A + (size_t)am0 * K + kn + akq0)
                             : make_float4(0, 0, 0, 0);
            fa1 = (am1 < NN) ? *(const float4*)(A + (size_t)am1 * K + kn + akq1)
                             : make_float4(0, 0, 0, 0);
            fb0 = *(const float4*)(B + (size_t)(kn + bkr) * 64 + bnc);
            fb1 = *(const float4*)(B + (size_t)(kn + bkr + 16) * 64 + bnc);
        }
#pragma unroll
        for (int k = 0; k < 32; k++) {
            float4 av = *(const float4*)&As[cur][k * 68 + ty * 4];
            float4 bv = *(const float4*)&Bs[cur][k * 68 + tx * 4];
            float a[4] = {av.x, av.y, av.z, av.w};
            float b[4] = {bv.x, bv.y, bv.z, bv.w};
#pragma unroll
            for (int i = 0; i < 4; i++)
#pragma unroll
                for (int j = 0; j < 4; j++) acc[i][j] += a[i] * b[j];
        }
        if (!more) break;
        int nxt = cur ^ 1;
        As[nxt][(akq0 + 0) * 68 + arow0] = fa0.x;
        As[nxt][(akq0 + 1) * 68 + arow0] = fa0.y;
        As[nxt][(akq0 + 2) * 68 + arow0] = fa0.z;
        As[nxt][(akq0 + 3) * 68 + arow0] = fa0.w;
        As[nxt][(akq1 + 0) * 68 + arow1] = fa1.x;
        As[nxt][(akq1 + 1) * 68 + arow1] = fa1.y;
        As[nxt][(akq1 + 2) * 68 + arow1] = fa1.z;
        As[nxt][(akq1 + 3) * 68 + arow1] = fa1.w;
        *(float4*)&Bs[nxt][bkr * 68 + bnc] = fb0;
        *(float4*)&Bs[nxt][(bkr + 16) * 68 + bnc] = fb1;
        __syncthreads();
        cur = nxt;
    }
    float4 bvv = ((const float4*)bias)[tx];
    float o[4][4];
#pragma unroll
    for (int i = 0; i < 4; i++) {
        o[i][0] = eluf(acc[i][0] + bvv.x);
        o[i][1] = eluf(acc[i][1] + bvv.y);
        o[i][2] = eluf(acc[i][2] + bvv.z);
        o[i][3] = eluf(acc[i][3] + bvv.w);
        int m = m_base + ty * 4 + i;
        if (m < NN)
            *(float4*)(out + (size_t)m * 64 + tx * 4) =
                make_float4(o[i][0], o[i][1], o[i][2], o[i][3]);
    }
    if (DOATT) {
        float ps[4][4] = {}, pd[4][4] = {};
#pragma unroll
        for (int i = 0; i < 4; i++)
#pragma unroll
            for (int j = 0; j < 4; j++) {
                float v = o[i][j];
                int kk = (tx * 4 + j) * 4;
#pragma unroll
                for (int h = 0; h < 4; h++) {
                    ps[i][h] += v * msS[kk + h];
                    pd[i][h] += v * mdS[kk + h];
                }
            }
#pragma unroll
        for (int mk = 1; mk < 16; mk <<= 1) {
#pragma unroll
            for (int i = 0; i < 4; i++)
#pragma unroll
                for (int h = 0; h < 4; h++) {
                    ps[i][h] += __shfl_xor(ps[i][h], mk, 64);
                    pd[i][h] += __shfl_xor(pd[i][h], mk, 64);
                }
        }
        if (tx == 0) {
#pragma unroll
            for (int i = 0; i < 4; i++) {
                int m = m_base + ty * 4 + i;
                if (m < NN) {
                    *(float4*)(as_ + (size_t)m * 4) =
                        make_float4(ps[i][0], ps[i][1], ps[i][2], ps[i][3]);
                    *(float4*)(ad_ + (size_t)m * 4) =
                        make_float4(pd[i][0], pd[i][1], pd[i][2], pd[i][3]);
                }
            }
        }
    }
}

// ---- SAGE mean aggregation into AB[:,0:64]; copy h2 into AB[:,64:128] ----
__global__ __launch_bounds__(256) void sage_agg3_kernel(
    const float* __restrict__ h2, const int* __restrict__ eoff,
    const int2* __restrict__ se_sorted, float* __restrict__ AB) {
    int n = blockIdx.x * 16 + (threadIdx.x >> 4);
    if (n >= NN) return;
    int l = threadIdx.x & 15;
    const float4* h24 = (const float4*)h2;
    float4* AB4 = (float4*)AB;
    float ax = 0.f, ay = 0.f, az = 0.f, aw = 0.f;
    int b = eoff[n], e_end = eoff[n + 1];
    int idx = b;
    int stop = b + ((e_end - b) & ~7);
    if (idx < stop) {
        int sreg[8];
#pragma unroll
        for (int u = 0; u < 8; u++) sreg[u] = se_sorted[idx + u].x;
        idx += 8;
        while (true) {
            int sn[8];
            bool more = idx < stop;
            if (more) {
#pragma unroll
                for (int u = 0; u < 8; u++) sn[u] = se_sorted[idx + u].x;
            }
#pragma unroll
            for (int u = 0; u < 8; u++) {
                float4 v = h24[(size_t)sreg[u] * 16 + l];
                ax += v.x; ay += v.y; az += v.z; aw += v.w;
            }
            if (!more) break;
#pragma unroll
            for (int u = 0; u < 8; u++) sreg[u] = sn[u];
            idx += 8;
        }
    }
    for (; idx < e_end; idx++) {
        float4 v0 = h24[(size_t)se_sorted[idx].x * 16 + l];
        ax += v0.x; ay += v0.y; az += v0.z; aw += v0.w;
    }
    float dg = (float)(e_end - b);
    if (dg < 1.f) dg = 1.f;
    float inv = 1.f / dg;
    AB4[(size_t)n * 32 + l] = make_float4(ax * inv, ay * inv, az * inv, aw * inv);
    AB4[(size_t)n * 32 + 16 + l] = h24[(size_t)n * 16 + l];
}

// ---- fused pool + MLP head: one block per graph -> d_out[192] ----
__global__ __launch_bounds__(256) void pool_mlp_kernel(
    const float* __restrict__ h3, const int* __restrict__ goff,
    const float* __restrict__ lin1W, const float* __restrict__ lin1b,
    const float* __restrict__ lin2W, const float* __restrict__ lin2b,
    const float* __restrict__ telW, const float* __restrict__ telb,
    const float* __restrict__ compW, const float* __restrict__ compb,
    const float* __restrict__ pchW, const float* __restrict__ pchb,
    float* __restrict__ out) {
    __shared__ float red[256];
    __shared__ float g[64], G1[64], G2[64];
    int gi = blockIdx.x, t = threadIdx.x;
    int c = t & 63, li = t >> 6;
    int b = goff[gi], e = goff[gi + 1];
    float sum = 0.f;
    for (int r = b + li; r < e; r += 4) sum += h3[(size_t)r * HID + c];
    red[t] = sum;
    __syncthreads();
    if (t < 64) {
        float v = red[t] + red[t + 64] + red[t + 128] + red[t + 192];
        float cntf = (float)(e - b);
        if (cntf < 1.f) cntf = 1.f;
        g[t] = v / cntf;
    }
    __syncthreads();
    {
        float part = 0.f;
#pragma unroll
        for (int k = li * 16; k < li * 16 + 16; k++) part += g[k] * lin1W[k * 64 + c];
        red[t] = part;
        __syncthreads();
        if (t < 64)
            G1[c] = eluf(red[c] + red[c + 64] + red[c + 128] + red[c + 192] + lin1b[c]);
        __syncthreads();
    }
    {
        float part = 0.f;
#pragma unroll
        for (int k = li * 16; k < li * 16 + 16; k++) part += G1[k] * lin2W[k * 64 + c];
        red[t] = part;
        __syncthreads();
        if (t < 64)
            G2[c] = red[c] + red[c + 64] + red[c + 128] + red[c + 192] + lin2b[c];
        __syncthreads();
    }
    if (t < 192) {
        int h = t >> 6, k = t & 63;
        const float* W = (h == 0) ? telW : ((h == 1) ? compW : pchW);
        red[t] = G2[k] * W[k];
    }
    __syncthreads();
    if (t < 3) {
        float acc = 0.f;
        for (int k = 0; k < 64; k++) acc += red[t * 64 + k];
        float bb = (t == 0) ? telb[0] : ((t == 1) ? compb[0] : pchb[0]);
        out[t * 64 + gi] = acc + bb;
    }
}

extern "C" void kernel_launch(void* const* d_in, const int* in_sizes, int n_in,
                              void* d_out, int out_size, void* d_ws, size_t ws_size,
                              hipStream_t stream) {
    const float* x        = (const float*)d_in[0];
    const float* EA       = (const float*)d_in[1];
    const float* node_emb = (const float*)d_in[2];
    const float* edge_W   = (const float*)d_in[3];
    const float* edge_b   = (const float*)d_in[4];
    const float* W1       = (const float*)d_in[5];
    const float* as1      = (const float*)d_in[6];
    const float* ad1      = (const float*)d_in[7];
    const float* ae1      = (const float*)d_in[8];
    const float* leW1     = (const float*)d_in[9];
    const float* b1       = (const float*)d_in[10];
    const float* W2       = (const float*)d_in[11];
    const float* as2      = (const float*)d_in[12];
    const float* ad2      = (const float*)d_in[13];
    const float* ae2      = (const float*)d_in[14];
    const float* leW2     = (const float*)d_in[15];
    const float* b2       = (const float*)d_in[16];
    const float* sage_Wl  = (const float*)d_in[17];
    const float* sage_bl  = (const float*)d_in[18];
    const float* sage_Wr  = (const float*)d_in[19];
    const float* lin1_W   = (const float*)d_in[20];
    const float* lin1_b   = (const float*)d_in[21];
    const float* lin2_W   = (const float*)d_in[22];
    const float* lin2_b   = (const float*)d_in[23];
    const float* tel_W    = (const float*)d_in[24];
    const float* tel_b    = (const float*)d_in[25];
    const float* comp_W   = (const float*)d_in[26];
    const float* comp_b   = (const float*)d_in[27];
    const float* pch_W    = (const float*)d_in[28];
    const float* pch_b    = (const float*)d_in[29];
    const int* edge_index = (const int*)d_in[30];
    const int* batch      = (const int*)d_in[31];
    const int* node_type  = (const int*)d_in[32];
    float* outp = (float*)d_out;

    const int* srcp = edge_index;
    const int* dstp = edge_index + NE;

    float* wf = (float*)d_ws;
    constexpr size_t OFF_H3    = 0;                               // N*64
    constexpr size_t OFF_AGG   = OFF_H3 + (size_t)NN * 64;        // N*512 (agg1[320]/agg2[256]/AB)
    constexpr size_t OFF_H1    = OFF_AGG + (size_t)NN * 512;      // N*64
    constexpr size_t OFF_H2    = OFF_H1 + (size_t)NN * 64;        // N*64
    constexpr size_t OFF_SC    = OFF_H2 + (size_t)NN * 64;        // E*4 (sc1 then sc2)
    constexpr size_t OFF_AE2   = OFF_SC + (size_t)NE * 4;         // E*4
    constexpr size_t OFF_AS    = OFF_AE2 + (size_t)NE * 4;        // N*4
    constexpr size_t OFF_AD    = OFF_AS + (size_t)NN * 4;         // N*4
    constexpr size_t OFF_SMALL = OFF_AD + (size_t)NN * 4;         // 4096
    constexpr size_t OFF_WC1   = OFF_SMALL + 4096;                // 20480
    constexpr size_t OFF_WC2   = OFF_WC1 + 20480;                 // 16384
    constexpr size_t OFF_B128  = OFF_WC2 + 16384;                 // 8192
    constexpr size_t F_TOTAL   = OFF_B128 + 8192;

    int* wi         = (int*)(wf + F_TOTAL);
    int* cnt        = wi;                        // N
    int* rank       = wi + NN;                   // E
    int* eoff       = rank + NE;                 // N+1
    int2* se_sorted = (int2*)(eoff + (NN + 2));  // E int2 (8B aligned)
    int* goff       = (int*)(se_sorted + NE);    // NG+1
    int* bsum       = goff + (NG + 1);           // 64
    int* boff       = bsum + 64;                 // 64

    float* h3    = wf + OFF_H3;
    float* aggb  = wf + OFF_AGG;
    float* h1    = wf + OFF_H1;
    float* h2    = wf + OFF_H2;
    float* sc    = wf + OFF_SC;
    float* ae2s  = wf + OFF_AE2;
    float* as_   = wf + OFF_AS;
    float* ad_   = wf + OFF_AD;
    float* S     = wf + OFF_SMALL;
    float* WC1   = wf + OFF_WC1;
    float* WC2   = wf + OFF_WC2;
    float* B128  = wf + OFF_B128;
    float* AB    = wf + OFF_AGG;                 // alias

    hipMemsetAsync(S + S_MEANEA, 0, 16 * sizeof(float), stream);
    hipMemsetAsync(cnt, 0, NN * sizeof(int), stream);

    // prep weights (blocks 0..175) + count/rank/mean (blocks 176..1113)
    cm_prepw_kernel<<<176 + (NE + 511) / 512, 256, 0, stream>>>(
        dstp, EA, cnt, rank, S, W1, W2, sage_Wl, sage_Wr, node_emb, WC1, WC2, B128);
    {
        int nb = (NN + 1023) / 1024;  // 30
        scan_blocks_kernel<<<nb, 1024, 0, stream>>>(cnt, eoff, bsum);
        tops_goff_prep_kernel<<<3, 256, 0, stream>>>(
            bsum, boff, nb, batch, goff,
            W1, as1, ad1, ae1, leW1, W2, as2, ad2, ae2, leW2, edge_W, edge_b, S);
        scanadd_attn_kernel<<<118 + (NN + 63) / 64, 256, 0, stream>>>(
            boff, eoff, x, node_emb, node_type, S, as_, ad_);
    }
    scatter_score_kernel<<<(NE + 255) / 256, 256, 0, stream>>>(
        srcp, dstp, EA, S, as_, ad_, node_type, eoff, rank, se_sorted, sc, ae2s);

    // ----- GAT layer 1: x-gather + type histogram -> K=320 projection -----
    agg_gat1_kernel<<<(NN + 3) / 4, 256, 0, stream>>>(
        eoff, se_sorted, sc, x, node_type, as_, ad_, S + S_AEL1, aggb);
    gemm64_kernel<320, true><<<(NN + 63) / 64, 256, 0, stream>>>(
        aggb, WC1, b1, h1, S + S_MS2, S + S_MD2, as_, ad_);

    // ----- GAT layer 2: dense score pass then pure gather -----
    score2_kernel<<<(NE + 255) / 256, 256, 0, stream>>>(srcp, dstp, ae2s, as_, ad_, sc);
    agg_gat2_kernel<<<(NN + 3) / 4, 256, 0, stream>>>(
        eoff, se_sorted, sc, h1, as_, ad_, S + S_AEL2, aggb);
    gemm64_kernel<256, false><<<(NN + 63) / 64, 256, 0, stream>>>(
        aggb, WC2, b2, h2, nullptr, nullptr, nullptr, nullptr);

    // ----- SAGE -----
    sage_agg3_kernel<<<(NN + 15) / 16, 256, 0, stream>>>(h2, eoff, se_sorted, AB);
    gemm64_kernel<128, false><<<(NN + 63) / 64, 256, 0, stream>>>(
        AB, B128, sage_bl, h3, nullptr, nullptr, nullptr, nullptr);

    // ----- fused pool + MLP head -----
    pool_mlp_kernel<<<NG, 256, 0, stream>>>(h3, goff, lin1_W, lin1_b, lin2_W, lin2_b,
                                            tel_W, tel_b, comp_W, comp_b, pch_W, pch_b, outp);
}

// Round 14
// 401.438 us; speedup vs baseline: 1.1552x; 1.0250x over previous
//
#include <hip/hip_runtime.h>
#include <math.h>

#define NN 30000          // nodes
#define NE 480000         // edges
#define FEA 16            // edge feature dim
#define HID 64
#define NG 64             // graphs
#define LEAKK 0.2f

// ---- small-constant region layout (float offsets) ----
#define S_MEANEA 0    // 16
#define S_KF1    16   // 64  (K1 [16,4])
#define S_C1     80   // 4
#define S_AEL1   84   // 4
#define S_KF2    88   // 64
#define S_C2     152  // 4
#define S_AEL2   156  // 4
#define S_MS1    160  // 512 (Ms1 [128,4])
#define S_MD1    672  // 512
#define S_MS2    1184 // 256 (Ms2 [64,4])
#define S_MD2    1440 // 256

__device__ __forceinline__ float eluf(float v) { return v > 0.f ? v : expm1f(v); }
__device__ __forceinline__ float leakyf(float v) { return v >= 0.f ? v : LEAKK * v; }
__device__ __forceinline__ void fma4(float4& a, float w, const float4& x) {
    a.x += w * x.x; a.y += w * x.y; a.z += w * x.z; a.w += w * x.w;
}
// pack two floats into bf16x2 (RNE)
__device__ __forceinline__ unsigned bf16pack(float a, float b) {
    unsigned ua = __float_as_uint(a), ub = __float_as_uint(b);
    ua = (ua + 0x7FFFu + ((ua >> 16) & 1u)) >> 16;
    ub = (ub + 0x7FFFu + ((ub >> 16) & 1u)) >> 16;
    return ua | (ub << 16);
}
// unpack 4 bf16 (uint2) -> float4
__device__ __forceinline__ float4 bf16x4(uint2 p) {
    float4 r;
    r.x = __uint_as_float(p.x << 16);
    r.y = __uint_as_float(p.x & 0xFFFF0000u);
    r.z = __uint_as_float(p.y << 16);
    r.w = __uint_as_float(p.y & 0xFFFF0000u);
    return r;
}

// ---- merged: blocks 0..175 weight-layout build; blocks 176.. count+rank+mean ----
__global__ __launch_bounds__(256) void cm_prepw_kernel(
    const int* __restrict__ dst, const float* __restrict__ EA,
    int* __restrict__ cnt, int* __restrict__ rank, float* __restrict__ S,
    const float* __restrict__ W1, const float* __restrict__ W2,
    const float* __restrict__ Wl, const float* __restrict__ Wr,
    const float* __restrict__ emb,
    float* __restrict__ WC1, float* __restrict__ WC2, float* __restrict__ B128) {
    __shared__ float red[1024];
    int t = threadIdx.x;
    if (blockIdx.x < 176) {
        int i = blockIdx.x * 256 + t;
        if (i < 16384) {            // WC1 x part
            int hk = i >> 6, c = i & 63;
            int h = hk >> 6, k = hk & 63;
            WC1[i] = 0.25f * W1[k * 256 + h * 64 + c];
        } else if (i < 20480) {     // WC1 emb part
            int j2 = i - 16384;
            int r2 = j2 >> 6, c = j2 & 63;
            int h = r2 >> 4, tau = r2 & 15;
            float v = 0.f;
            for (int j = 0; j < 64; j++)
                v += emb[tau * 64 + j] * W1[(64 + j) * 256 + h * 64 + c];
            WC1[i] = 0.25f * v;
        } else if (i < 36864) {
            int j = i - 20480;
            int hk = j >> 6, c = j & 63;
            int h = hk >> 6, k = hk & 63;
            WC2[j] = 0.25f * W2[k * 256 + h * 64 + c];
        } else if (i < 45056) {
            int j = i - 36864;
            int k = j >> 6, c = j & 63;
            B128[j] = (k < 64) ? Wl[k * 64 + c] : Wr[(k - 64) * 64 + c];
        }
        return;
    }
    int base = (blockIdx.x - 176) * 512;
#pragma unroll
    for (int i = 0; i < 2; i++) {
        int e = base + i * 256 + t;
        if (e < NE) rank[e] = atomicAdd(&cnt[dst[e]], 1);
    }
    int c4 = t & 3;
    int rbase = base + (t >> 2);
    float4 acc = {0, 0, 0, 0};
#pragma unroll
    for (int i = 0; i < 8; i++) {
        int r = rbase + i * 64;
        if (r < NE) {
            float4 v = *(const float4*)(EA + (size_t)r * FEA + c4 * 4);
            acc.x += v.x; acc.y += v.y; acc.z += v.z; acc.w += v.w;
        }
    }
    *(float4*)&red[t * 4] = acc;
    __syncthreads();
    if (t < 16) {
        int grp = t >> 2;
        int comp = t & 3;
        float sum = 0.f;
        for (int j = 0; j < 64; j++) sum += red[(grp + 4 * j) * 4 + comp];
        atomicAdd(&S[S_MEANEA + grp * 4 + comp], sum);
    }
}

// ---- 30-block scan over degree counts ----
__global__ void scan_blocks_kernel(const int* __restrict__ cnt, int* __restrict__ eoff,
                                   int* __restrict__ bsum) {
    __shared__ int wsum[16];
    int t = threadIdx.x;
    int i = blockIdx.x * 1024 + t;
    int v = (i < NN) ? cnt[i] : 0;
    int lane = t & 63;
    int incl = v;
#pragma unroll
    for (int ofs = 1; ofs < 64; ofs <<= 1) {
        int u = __shfl_up(incl, ofs, 64);
        if (lane >= ofs) incl += u;
    }
    int wid = t >> 6;
    if (lane == 63) wsum[wid] = incl;
    __syncthreads();
    if (t < 16) {
        int s = wsum[t];
#pragma unroll
        for (int ofs = 1; ofs < 16; ofs <<= 1) {
            int u = __shfl_up(s, ofs, 64);
            if (t >= ofs) s += u;
        }
        wsum[t] = s;
    }
    __syncthreads();
    int excl = incl - v + (wid > 0 ? wsum[wid - 1] : 0);
    if (i < NN) eoff[i] = excl;
    if (t == 1023) bsum[blockIdx.x] = excl + v;
}

// ---- merged: block 0 scan-tops; block 1 goff; block 2 prep_small folds ----
__global__ void tops_goff_prep_kernel(
    const int* __restrict__ bsum, int* __restrict__ boff, int nb,
    const int* __restrict__ batch, int* __restrict__ goff,
    const float* __restrict__ W1, const float* __restrict__ as1, const float* __restrict__ ad1,
    const float* __restrict__ ae1, const float* __restrict__ leW1,
    const float* __restrict__ W2, const float* __restrict__ as2, const float* __restrict__ ad2,
    const float* __restrict__ ae2, const float* __restrict__ leW2,
    const float* __restrict__ edge_W, const float* __restrict__ edge_b,
    float* __restrict__ S) {
    __shared__ float M1[256], M2[256], meh[64];
    int t = threadIdx.x;
    if (blockIdx.x == 0) {
        if (t >= 64) return;
        int v = (t < nb) ? bsum[t] : 0;
        int incl = v;
#pragma unroll
        for (int ofs = 1; ofs < 64; ofs <<= 1) {
            int u = __shfl_up(incl, ofs, 64);
            if (t >= ofs) incl += u;
        }
        boff[t] = incl - v;
        return;
    }
    if (blockIdx.x == 1) {
        if (t > NG) return;
        int lo = 0, hi = NN;
        while (lo < hi) {
            int mid = (lo + hi) >> 1;
            if (batch[mid] < t) lo = mid + 1; else hi = mid;
        }
        goff[t] = lo;
        return;
    }
    if (t < 16) S[S_MEANEA + t] *= (1.0f / (float)NE);
    __syncthreads();
    {
        int k = t >> 2, h = t & 3;
        float m1 = 0.f, m2 = 0.f;
        for (int c = 0; c < 64; c++) {
            m1 += leW1[k * 256 + h * 64 + c] * ae1[h * 64 + c];
            m2 += leW2[k * 256 + h * 64 + c] * ae2[h * 64 + c];
        }
        M1[t] = m1; M2[t] = m2;
    }
    if (t < 64) {
        float v = edge_b[t];
        for (int f = 0; f < FEA; f++) v += S[S_MEANEA + f] * edge_W[f * 64 + t];
        meh[t] = v;
    }
    __syncthreads();
    if (t < 64) {
        int f = t >> 2, h = t & 3;
        float k1 = 0.f, k2 = 0.f;
        for (int k = 0; k < 64; k++) {
            k1 += edge_W[f * 64 + k] * M1[k * 4 + h];
            k2 += edge_W[f * 64 + k] * M2[k * 4 + h];
        }
        S[S_KF1 + t] = k1; S[S_KF2 + t] = k2;
    } else if (t < 68) {
        int h = t - 64;
        float c1 = 0.f, c2 = 0.f, a1 = 0.f, a2 = 0.f;
        for (int k = 0; k < 64; k++) {
            c1 += edge_b[k] * M1[k * 4 + h];
            c2 += edge_b[k] * M2[k * 4 + h];
            a1 += meh[k] * M1[k * 4 + h];
            a2 += meh[k] * M2[k * 4 + h];
        }
        S[S_C1 + h] = c1; S[S_C2 + h] = c2;
        S[S_AEL1 + h] = a1; S[S_AEL2 + h] = a2;
    }
    for (int i = t; i < 512; i += 256) {
        int k = i >> 2, h = i & 3;
        float s = 0.f, d = 0.f;
        for (int c = 0; c < 64; c++) {
            float w = W1[k * 256 + h * 64 + c];
            s += w * as1[h * 64 + c];
            d += w * ad1[h * 64 + c];
        }
        S[S_MS1 + i] = s; S[S_MD1 + i] = d;
    }
    for (int i = t; i < 256; i += 256) {
        int k = i >> 2, h = i & 3;
        float s = 0.f, d = 0.f;
        for (int c = 0; c < 64; c++) {
            float w = W2[k * 256 + h * 64 + c];
            s += w * as2[h * 64 + c];
            d += w * ad2[h * 64 + c];
        }
        S[S_MS2 + i] = s; S[S_MD2 + i] = d;
    }
}

// ---- merged: blocks 0..117 scan-add; blocks 118.. layer-1 a_s/a_d + xb cast ----
__global__ __launch_bounds__(256) void scanadd_attn_kernel(
    const int* __restrict__ boff, int* __restrict__ eoff,
    const float* __restrict__ x, const float* __restrict__ node_emb,
    const int* __restrict__ node_type, const float* __restrict__ S,
    float* __restrict__ as_, float* __restrict__ ad_, unsigned* __restrict__ xb) {
    __shared__ float xt[64 * 132];
    __shared__ float ms[512], md[512];
    __shared__ int ntS[64];
    int t = threadIdx.x;
    if (blockIdx.x < 118) {
        int i = blockIdx.x * 256 + t;
        if (i < NN) eoff[i] += boff[i >> 10];
        if (i == 0) eoff[NN] = NE;
        return;
    }
    int n0 = (blockIdx.x - 118) * 64;
    if (t < 64) {
        int n = n0 + t;
        ntS[t] = (n < NN) ? node_type[n] : 0;
    }
    for (int i = t; i < 512; i += 256) { ms[i] = S[S_MS1 + i]; md[i] = S[S_MD1 + i]; }
    __syncthreads();
    for (int i = t; i < 1024; i += 256) {
        int r = i >> 4, c4 = (i & 15) * 4;
        int n = n0 + r;
        float4 f = {0, 0, 0, 0};
        if (n < NN) f = *(const float4*)(x + (size_t)n * 64 + c4);
        *(float4*)&xt[r * 132 + c4] = f;
    }
    for (int i = t; i < 1024; i += 256) {
        int r = i >> 4, c4 = (i & 15) * 4;
        int n = n0 + r;
        float4 f = {0, 0, 0, 0};
        if (n < NN) f = *(const float4*)(node_emb + (size_t)ntS[r] * 64 + c4);
        *(float4*)&xt[r * 132 + 64 + c4] = f;
    }
    __syncthreads();
    // write xb (bf16 x rows): 64 nodes x 32 uints
    for (int i = t; i < 2048; i += 256) {
        int r = i >> 5, u = i & 31;
        int n = n0 + r;
        if (n < NN)
            xb[(size_t)n * 32 + u] = bf16pack(xt[r * 132 + 2 * u], xt[r * 132 + 2 * u + 1]);
    }
    int r = t >> 2, h = t & 3;
    float s = 0.f, d = 0.f;
#pragma unroll 8
    for (int k = 0; k < 128; k++) {
        float xv = xt[r * 132 + k];
        s += xv * ms[k * 4 + h];
        d += xv * md[k * 4 + h];
    }
    int n = n0 + r;
    if (n < NN) { as_[n * 4 + h] = s; ad_[n * 4 + h] = d; }
}

// ---- fused scatter + layer-1 scoring (atomic-free via rank) ----
__global__ void scatter_score_kernel(const int* __restrict__ src, const int* __restrict__ dst,
                                     const float* __restrict__ EA, const float* __restrict__ S,
                                     const float* __restrict__ as_, const float* __restrict__ ad_,
                                     const int* __restrict__ node_type,
                                     const int* __restrict__ eoff, const int* __restrict__ rank,
                                     int2* __restrict__ se_sorted,
                                     float* __restrict__ sc1, float* __restrict__ ae2s) {
    int e = blockIdx.x * 256 + threadIdx.x;
    if (e >= NE) return;
    int s = src[e], d = dst[e];
    float a1[4], a2[4];
#pragma unroll
    for (int h = 0; h < 4; h++) { a1[h] = S[S_C1 + h]; a2[h] = S[S_C2 + h]; }
    const float4* EA4 = (const float4*)(EA + (size_t)e * FEA);
#pragma unroll
    for (int q = 0; q < 4; q++) {
        float4 v = EA4[q];
        float vv[4] = {v.x, v.y, v.z, v.w};
#pragma unroll
        for (int j = 0; j < 4; j++) {
            int f = q * 4 + j;
#pragma unroll
            for (int h = 0; h < 4; h++) {
                a1[h] += vv[j] * S[S_KF1 + f * 4 + h];
                a2[h] += vv[j] * S[S_KF2 + f * 4 + h];
            }
        }
    }
    ((float4*)ae2s)[e] = make_float4(a2[0], a2[1], a2[2], a2[3]);
    float4 asv = ((const float4*)as_)[s];
    float4 adv = ((const float4*)ad_)[d];
    float4 r;
    r.x = expf(leakyf(asv.x + adv.x + a1[0]));
    r.y = expf(leakyf(asv.y + adv.y + a1[1]));
    r.z = expf(leakyf(asv.z + adv.z + a1[2]));
    r.w = expf(leakyf(asv.w + adv.w + a1[3]));
    ((float4*)sc1)[e] = r;
    int ty = node_type[s];
    se_sorted[eoff[d] + rank[e]] = make_int2(s, e | (ty << 24));
}

// ---- dense layer-2 scoring ----
__global__ void score2_kernel(const int* __restrict__ src, const int* __restrict__ dst,
                              const float* __restrict__ ae2s,
                              const float* __restrict__ as_, const float* __restrict__ ad_,
                              float* __restrict__ sc2) {
    int e = blockIdx.x * 256 + threadIdx.x;
    if (e >= NE) return;
    int s = src[e], d = dst[e];
    float4 ae = ((const float4*)ae2s)[e];
    float4 asv = ((const float4*)as_)[s];
    float4 adv = ((const float4*)ad_)[d];
    float4 r;
    r.x = expf(leakyf(asv.x + adv.x + ae.x));
    r.y = expf(leakyf(asv.y + adv.y + ae.y));
    r.z = expf(leakyf(asv.z + adv.z + ae.z));
    r.w = expf(leakyf(asv.w + adv.w + ae.w));
    ((float4*)sc2)[e] = r;
}

// ---- layer-1 GAT aggregation: gather bf16 x rows + per-type weight histogram ----
__global__ __launch_bounds__(256) void agg_gat1_kernel(
    const int* __restrict__ eoff, const int2* __restrict__ se_sorted,
    const float* __restrict__ sc1, const unsigned* __restrict__ xb,
    const int* __restrict__ node_type,
    const float* __restrict__ as_, const float* __restrict__ ad_,
    const float* __restrict__ Sael, float* __restrict__ agg) {
    int n = blockIdx.x * 4 + (threadIdx.x >> 6);
    if (n >= NN) return;
    int lane = threadIdx.x & 63;
    int sub = lane >> 4, ch = lane & 15;
    const uint2* Xb = (const uint2*)xb;
    const float4* W4 = (const float4*)sc1;
    float4 asn = ((const float4*)as_)[n];
    float4 adn = ((const float4*)ad_)[n];
    float4 a0 = {0, 0, 0, 0}, a1 = a0, a2 = a0, a3 = a0, dn = a0, tw = a0;
    int b = eoff[n], e_end = eoff[n + 1];
    int nE = e_end - b;
    int i = sub;
    for (; i + 4 < nE; i += 8) {
        int2 se0 = se_sorted[b + i], se1 = se_sorted[b + i + 4];
        int e0 = se0.y & 0xFFFFFF, t0 = se0.y >> 24;
        int e1 = se1.y & 0xFFFFFF, t1 = se1.y >> 24;
        float4 w0 = W4[e0], w1 = W4[e1];
        float4 x0 = bf16x4(Xb[(size_t)se0.x * 16 + ch]);
        float4 x1 = bf16x4(Xb[(size_t)se1.x * 16 + ch]);
        fma4(a0, w0.x, x0); fma4(a1, w0.y, x0); fma4(a2, w0.z, x0); fma4(a3, w0.w, x0);
        fma4(a0, w1.x, x1); fma4(a1, w1.y, x1); fma4(a2, w1.z, x1); fma4(a3, w1.w, x1);
        dn.x += w0.x + w1.x; dn.y += w0.y + w1.y;
        dn.z += w0.z + w1.z; dn.w += w0.w + w1.w;
        if (ch == t0) { tw.x += w0.x; tw.y += w0.y; tw.z += w0.z; tw.w += w0.w; }
        if (ch == t1) { tw.x += w1.x; tw.y += w1.y; tw.z += w1.z; tw.w += w1.w; }
    }
    for (; i < nE; i += 4) {
        int2 se0 = se_sorted[b + i];
        int e0 = se0.y & 0xFFFFFF, t0 = se0.y >> 24;
        float4 w0 = W4[e0];
        float4 x0 = bf16x4(Xb[(size_t)se0.x * 16 + ch]);
        fma4(a0, w0.x, x0); fma4(a1, w0.y, x0); fma4(a2, w0.z, x0); fma4(a3, w0.w, x0);
        dn.x += w0.x; dn.y += w0.y; dn.z += w0.z; dn.w += w0.w;
        if (ch == t0) { tw.x += w0.x; tw.y += w0.y; tw.z += w0.z; tw.w += w0.w; }
    }
    if (sub == 0) {  // self loop
        float e0 = expf(leakyf(asn.x + adn.x + Sael[0]));
        float e1 = expf(leakyf(asn.y + adn.y + Sael[1]));
        float e2 = expf(leakyf(asn.z + adn.z + Sael[2]));
        float e3 = expf(leakyf(asn.w + adn.w + Sael[3]));
        float4 xs = bf16x4(Xb[(size_t)n * 16 + ch]);
        fma4(a0, e0, xs); fma4(a1, e1, xs); fma4(a2, e2, xs); fma4(a3, e3, xs);
        dn.x += e0; dn.y += e1; dn.z += e2; dn.w += e3;
        int tn = node_type[n];
        if (ch == tn) { tw.x += e0; tw.y += e1; tw.z += e2; tw.w += e3; }
    }
#pragma unroll
    for (int mask = 16; mask < 64; mask <<= 1) {
        a0.x += __shfl_xor(a0.x, mask, 64); a0.y += __shfl_xor(a0.y, mask, 64);
        a0.z += __shfl_xor(a0.z, mask, 64); a0.w += __shfl_xor(a0.w, mask, 64);
        a1.x += __shfl_xor(a1.x, mask, 64); a1.y += __shfl_xor(a1.y, mask, 64);
        a1.z += __shfl_xor(a1.z, mask, 64); a1.w += __shfl_xor(a1.w, mask, 64);
        a2.x += __shfl_xor(a2.x, mask, 64); a2.y += __shfl_xor(a2.y, mask, 64);
        a2.z += __shfl_xor(a2.z, mask, 64); a2.w += __shfl_xor(a2.w, mask, 64);
        a3.x += __shfl_xor(a3.x, mask, 64); a3.y += __shfl_xor(a3.y, mask, 64);
        a3.z += __shfl_xor(a3.z, mask, 64); a3.w += __shfl_xor(a3.w, mask, 64);
        dn.x += __shfl_xor(dn.x, mask, 64); dn.y += __shfl_xor(dn.y, mask, 64);
        dn.z += __shfl_xor(dn.z, mask, 64); dn.w += __shfl_xor(dn.w, mask, 64);
        tw.x += __shfl_xor(tw.x, mask, 64); tw.y += __shfl_xor(tw.y, mask, 64);
        tw.z += __shfl_xor(tw.z, mask, 64); tw.w += __shfl_xor(tw.w, mask, 64);
    }
    if (sub == 0) {
        float i0 = 1.f / dn.x, i1 = 1.f / dn.y, i2 = 1.f / dn.z, i3 = 1.f / dn.w;
        float* A = agg + (size_t)n * 320;
        float4* A4 = (float4*)A;
        A4[ch]      = make_float4(a0.x * i0, a0.y * i0, a0.z * i0, a0.w * i0);
        A4[16 + ch] = make_float4(a1.x * i1, a1.y * i1, a1.z * i1, a1.w * i1);
        A4[32 + ch] = make_float4(a2.x * i2, a2.y * i2, a2.z * i2, a2.w * i2);
        A4[48 + ch] = make_float4(a3.x * i3, a3.y * i3, a3.z * i3, a3.w * i3);
        A[256 + ch]      = tw.x * i0;
        A[256 + 16 + ch] = tw.y * i1;
        A[256 + 32 + ch] = tw.z * i2;
        A[256 + 48 + ch] = tw.w * i3;
    }
}

// ---- layer-2 GAT aggregation: pure gather of bf16 h1 rows ----
__global__ __launch_bounds__(256) void agg_gat2_kernel(
    const int* __restrict__ eoff, const int2* __restrict__ se_sorted,
    const float* __restrict__ sc2, const unsigned* __restrict__ h1b,
    const float* __restrict__ as_, const float* __restrict__ ad_,
    const float* __restrict__ Sael, float* __restrict__ agg) {
    int n = blockIdx.x * 4 + (threadIdx.x >> 6);
    if (n >= NN) return;
    int lane = threadIdx.x & 63;
    int sub = lane >> 4, ch = lane & 15;
    const uint2* Xb = (const uint2*)h1b;
    const float4* W4 = (const float4*)sc2;
    float4 asn = ((const float4*)as_)[n];
    float4 adn = ((const float4*)ad_)[n];
    float4 a0 = {0, 0, 0, 0}, a1 = a0, a2 = a0, a3 = a0, dn = a0;
    int b = eoff[n], e = eoff[n + 1];
    int nE = e - b;
    int i = sub;
    for (; i + 4 < nE; i += 8) {
        int2 se0 = se_sorted[b + i], se1 = se_sorted[b + i + 4];
        float4 w0 = W4[se0.y & 0xFFFFFF], w1 = W4[se1.y & 0xFFFFFF];
        float4 x0 = bf16x4(Xb[(size_t)se0.x * 16 + ch]);
        float4 x1 = bf16x4(Xb[(size_t)se1.x * 16 + ch]);
        fma4(a0, w0.x, x0); fma4(a1, w0.y, x0); fma4(a2, w0.z, x0); fma4(a3, w0.w, x0);
        fma4(a0, w1.x, x1); fma4(a1, w1.y, x1); fma4(a2, w1.z, x1); fma4(a3, w1.w, x1);
        dn.x += w0.x + w1.x; dn.y += w0.y + w1.y;
        dn.z += w0.z + w1.z; dn.w += w0.w + w1.w;
    }
    for (; i < nE; i += 4) {
        int2 se0 = se_sorted[b + i];
        float4 w0 = W4[se0.y & 0xFFFFFF];
        float4 x0 = bf16x4(Xb[(size_t)se0.x * 16 + ch]);
        fma4(a0, w0.x, x0); fma4(a1, w0.y, x0); fma4(a2, w0.z, x0); fma4(a3, w0.w, x0);
        dn.x += w0.x; dn.y += w0.y; dn.z += w0.z; dn.w += w0.w;
    }
    if (sub == 0) {  // self loop
        float e0 = expf(leakyf(asn.x + adn.x + Sael[0]));
        float e1 = expf(leakyf(asn.y + adn.y + Sael[1]));
        float e2 = expf(leakyf(asn.z + adn.z + Sael[2]));
        float e3 = expf(leakyf(asn.w + adn.w + Sael[3]));
        float4 xs = bf16x4(Xb[(size_t)n * 16 + ch]);
        fma4(a0, e0, xs); fma4(a1, e1, xs); fma4(a2, e2, xs); fma4(a3, e3, xs);
        dn.x += e0; dn.y += e1; dn.z += e2; dn.w += e3;
    }
#pragma unroll
    for (int mask = 16; mask < 64; mask <<= 1) {
        a0.x += __shfl_xor(a0.x, mask, 64); a0.y += __shfl_xor(a0.y, mask, 64);
        a0.z += __shfl_xor(a0.z, mask, 64); a0.w += __shfl_xor(a0.w, mask, 64);
        a1.x += __shfl_xor(a1.x, mask, 64); a1.y += __shfl_xor(a1.y, mask, 64);
        a1.z += __shfl_xor(a1.z, mask, 64); a1.w += __shfl_xor(a1.w, mask, 64);
        a2.x += __shfl_xor(a2.x, mask, 64); a2.y += __shfl_xor(a2.y, mask, 64);
        a2.z += __shfl_xor(a2.z, mask, 64); a2.w += __shfl_xor(a2.w, mask, 64);
        a3.x += __shfl_xor(a3.x, mask, 64); a3.y += __shfl_xor(a3.y, mask, 64);
        a3.z += __shfl_xor(a3.z, mask, 64); a3.w += __shfl_xor(a3.w, mask, 64);
        dn.x += __shfl_xor(dn.x, mask, 64); dn.y += __shfl_xor(dn.y, mask, 64);
        dn.z += __shfl_xor(dn.z, mask, 64); dn.w += __shfl_xor(dn.w, mask, 64);
    }
    if (sub == 0) {
        float i0 = 1.f / dn.x, i1 = 1.f / dn.y, i2 = 1.f / dn.z, i3 = 1.f / dn.w;
        float4* agg4 = (float4*)(agg + (size_t)n * 256);
        agg4[ch]      = make_float4(a0.x * i0, a0.y * i0, a0.z * i0, a0.w * i0);
        agg4[16 + ch] = make_float4(a1.x * i1, a1.y * i1, a1.z * i1, a1.w * i1);
        agg4[32 + ch] = make_float4(a2.x * i2, a2.y * i2, a2.z * i2, a2.w * i2);
        agg4[48 + ch] = make_float4(a3.x * i3, a3.y * i3, a3.z * i3, a3.w * i3);
    }
}

// ---- GEMM: out[M,64] = elu(A@B+bias); dbuf LDS; optional bf16 copy + DOATT ----
template <int K, bool DOATT>
__global__ __launch_bounds__(256) void gemm64_kernel(
    const float* __restrict__ A, const float* __restrict__ B,
    const float* __restrict__ bias, float* __restrict__ out,
    unsigned* __restrict__ out16,
    const float* __restrict__ ms_g, const float* __restrict__ md_g,
    float* __restrict__ as_, float* __restrict__ ad_) {
    __shared__ float As[2][32 * 68];
    __shared__ float Bs[2][32 * 68];
    __shared__ float msS[256], mdS[256];
    int t = threadIdx.x;
    int tx = t & 15, ty = t >> 4;
    int m_base = blockIdx.x * 64;
    if (DOATT) { msS[t] = ms_g[t]; mdS[t] = md_g[t]; }
    int arow0 = t >> 3, akq0 = (t & 7) * 4;
    int arow1 = (t + 256) >> 3, akq1 = ((t + 256) & 7) * 4;
    int bkr = t >> 4, bnc = (t & 15) * 4;
    int am0 = m_base + arow0, am1 = m_base + arow1;
    float4 fa0, fa1, fb0, fb1;
    fa0 = (am0 < NN) ? *(const float4*)(A + (size_t)am0 * K + akq0) : make_float4(0, 0, 0, 0);
    fa1 = (am1 < NN) ? *(const float4*)(A + (size_t)am1 * K + akq1) : make_float4(0, 0, 0, 0);
    fb0 = *(const float4*)(B + (size_t)bkr * 64 + bnc);
    fb1 = *(const float4*)(B + (size_t)(bkr + 16) * 64 + bnc);
    As[0][(akq0 + 0) * 68 + arow0] = fa0.x;
    As[0][(akq0 + 1) * 68 + arow0] = fa0.y;
    As[0][(akq0 + 2) * 68 + arow0] = fa0.z;
    As[0][(akq0 + 3) * 68 + arow0] = fa0.w;
    As[0][(akq1 + 0) * 68 + arow1] = fa1.x;
    As[0][(akq1 + 1) * 68 + arow1] = fa1.y;
    As[0][(akq1 + 2) * 68 + arow1] = fa1.z;
    As[0][(akq1 + 3) * 68 + arow1] = fa1.w;
    *(float4*)&Bs[0][bkr * 68 + bnc] = fb0;
    *(float4*)&Bs[0][(bkr + 16) * 68 + bnc] = fb1;
    __syncthreads();
    float acc[4][4] = {};
    int cur = 0;
    for (int k0 = 0;; k0 += 32) {
        bool more = (k0 + 32 < K);
        if (more) {
            int kn = k0 + 32;
            fa0 = (am0 < NN) ? *(const float4*)(A + (size_t)am0 * K + kn + akq0)
                             : make_float4(0, 0, 0, 0);
            fa1 = (am1 < NN) ? *(const float4*)(A + (size_t)am1 * K + kn + akq1)
                             : make_float4(0, 0, 0, 0);
            fb0 = *(const float4*)(B + (size_t)(kn + bkr) * 64 + bnc);
            fb1 = *(const float4*)(B + (size_t)(kn + bkr + 16) * 64 + bnc);
        }
#pragma unroll
        for (int k = 0; k < 32; k++) {
            float4 av = *(const float4*)&As[cur][k * 68 + ty * 4];
            float4 bv = *(const float4*)&Bs[cur][k * 68 + tx * 4];
            float a[4] = {av.x, av.y, av.z, av.w};
            float b[4] = {bv.x, bv.y, bv.z, bv.w};
#pragma unroll
            for (int i = 0; i < 4; i++)
#pragma unroll
                for (int j = 0; j < 4; j++) acc[i][j] += a[i] * b[j];
        }
        if (!more) break;
        int nxt = cur ^ 1;
        As[nxt][(akq0 + 0) * 68 + arow0] = fa0.x;
        As[nxt][(akq0 + 1) * 68 + arow0] = fa0.y;
        As[nxt][(akq0 + 2) * 68 + arow0] = fa0.z;
        As[nxt][(akq0 + 3) * 68 + arow0] = fa0.w;
        As[nxt][(akq1 + 0) * 68 + arow1] = fa1.x;
        As[nxt][(akq1 + 1) * 68 + arow1] = fa1.y;
        As[nxt][(akq1 + 2) * 68 + arow1] = fa1.z;
        As[nxt][(akq1 + 3) * 68 + arow1] = fa1.w;
        *(float4*)&Bs[nxt][bkr * 68 + bnc] = fb0;
        *(float4*)&Bs[nxt][(bkr + 16) * 68 + bnc] = fb1;
        __syncthreads();
        cur = nxt;
    }
    float4 bvv = ((const float4*)bias)[tx];
    float o[4][4];
#pragma unroll
    for (int i = 0; i < 4; i++) {
        o[i][0] = eluf(acc[i][0] + bvv.x);
        o[i][1] = eluf(acc[i][1] + bvv.y);
        o[i][2] = eluf(acc[i][2] + bvv.z);
        o[i][3] = eluf(acc[i][3] + bvv.w);
        int m = m_base + ty * 4 + i;
        if (m < NN) {
            *(float4*)(out + (size_t)m * 64 + tx * 4) =
                make_float4(o[i][0], o[i][1], o[i][2], o[i][3]);
            if (out16) {
                out16[(size_t)m * 32 + tx * 2]     = bf16pack(o[i][0], o[i][1]);
                out16[(size_t)m * 32 + tx * 2 + 1] = bf16pack(o[i][2], o[i][3]);
            }
        }
    }
    if (DOATT) {
        float ps[4][4] = {}, pd[4][4] = {};
#pragma unroll
        for (int i = 0; i < 4; i++)
#pragma unroll
            for (int j = 0; j < 4; j++) {
                float v = o[i][j];
                int kk = (tx * 4 + j) * 4;
#pragma unroll
                for (int h = 0; h < 4; h++) {
                    ps[i][h] += v * msS[kk + h];
                    pd[i][h] += v * mdS[kk + h];
                }
            }
#pragma unroll
        for (int mk = 1; mk < 16; mk <<= 1) {
#pragma unroll
            for (int i = 0; i < 4; i++)
#pragma unroll
                for (int h = 0; h < 4; h++) {
                    ps[i][h] += __shfl_xor(ps[i][h], mk, 64);
                    pd[i][h] += __shfl_xor(pd[i][h], mk, 64);
                }
        }
        if (tx == 0) {
#pragma unroll
            for (int i = 0; i < 4; i++) {
                int m = m_base + ty * 4 + i;
                if (m < NN) {
                    *(float4*)(as_ + (size_t)m * 4) =
                        make_float4(ps[i][0], ps[i][1], ps[i][2], ps[i][3]);
                    *(float4*)(ad_ + (size_t)m * 4) =
                        make_float4(pd[i][0], pd[i][1], pd[i][2], pd[i][3]);
                }
            }
        }
    }
}

// ---- SAGE mean aggregation (bf16 neighbor gather) + fp32 self copy ----
__global__ __launch_bounds__(256) void sage_agg3_kernel(
    const float* __restrict__ h2, const unsigned* __restrict__ h2b,
    const int* __restrict__ eoff, const int2* __restrict__ se_sorted,
    float* __restrict__ AB) {
    int n = blockIdx.x * 16 + (threadIdx.x >> 4);
    if (n >= NN) return;
    int l = threadIdx.x & 15;
    const uint2* Hb = (const uint2*)h2b;
    const float4* h24 = (const float4*)h2;
    float4* AB4 = (float4*)AB;
    float ax = 0.f, ay = 0.f, az = 0.f, aw = 0.f;
    int b = eoff[n], e_end = eoff[n + 1];
    int idx = b;
    int stop = b + ((e_end - b) & ~7);
    if (idx < stop) {
        int sreg[8];
#pragma unroll
        for (int u = 0; u < 8; u++) sreg[u] = se_sorted[idx + u].x;
        idx += 8;
        while (true) {
            int sn[8];
            bool more = idx < stop;
            if (more) {
#pragma unroll
                for (int u = 0; u < 8; u++) sn[u] = se_sorted[idx + u].x;
            }
#pragma unroll
            for (int u = 0; u < 8; u++) {
                float4 v = bf16x4(Hb[(size_t)sreg[u] * 16 + l]);
                ax += v.x; ay += v.y; az += v.z; aw += v.w;
            }
            if (!more) break;
#pragma unroll
            for (int u = 0; u < 8; u++) sreg[u] = sn[u];
            idx += 8;
        }
    }
    for (; idx < e_end; idx++) {
        float4 v0 = bf16x4(Hb[(size_t)se_sorted[idx].x * 16 + l]);
        ax += v0.x; ay += v0.y; az += v0.z; aw += v0.w;
    }
    float dg = (float)(e_end - b);
    if (dg < 1.f) dg = 1.f;
    float inv = 1.f / dg;
    AB4[(size_t)n * 32 + l] = make_float4(ax * inv, ay * inv, az * inv, aw * inv);
    AB4[(size_t)n * 32 + 16 + l] = h24[(size_t)n * 16 + l];
}

// ---- fused pool + MLP head: one block per graph -> d_out[192] ----
__global__ __launch_bounds__(256) void pool_mlp_kernel(
    const float* __restrict__ h3, const int* __restrict__ goff,
    const float* __restrict__ lin1W, const float* __restrict__ lin1b,
    const float* __restrict__ lin2W, const float* __restrict__ lin2b,
    const float* __restrict__ telW, const float* __restrict__ telb,
    const float* __restrict__ compW, const float* __restrict__ compb,
    const float* __restrict__ pchW, const float* __restrict__ pchb,
    float* __restrict__ out) {
    __shared__ float red[256];
    __shared__ float g[64], G1[64], G2[64];
    int gi = blockIdx.x, t = threadIdx.x;
    int c = t & 63, li = t >> 6;
    int b = goff[gi], e = goff[gi + 1];
    float sum = 0.f;
    for (int r = b + li; r < e; r += 4) sum += h3[(size_t)r * HID + c];
    red[t] = sum;
    __syncthreads();
    if (t < 64) {
        float v = red[t] + red[t + 64] + red[t + 128] + red[t + 192];
        float cntf = (float)(e - b);
        if (cntf < 1.f) cntf = 1.f;
        g[t] = v / cntf;
    }
    __syncthreads();
    {
        float part = 0.f;
#pragma unroll
        for (int k = li * 16; k < li * 16 + 16; k++) part += g[k] * lin1W[k * 64 + c];
        red[t] = part;
        __syncthreads();
        if (t < 64)
            G1[c] = eluf(red[c] + red[c + 64] + red[c + 128] + red[c + 192] + lin1b[c]);
        __syncthreads();
    }
    {
        float part = 0.f;
#pragma unroll
        for (int k = li * 16; k < li * 16 + 16; k++) part += G1[k] * lin2W[k * 64 + c];
        red[t] = part;
        __syncthreads();
        if (t < 64)
            G2[c] = red[c] + red[c + 64] + red[c + 128] + red[c + 192] + lin2b[c];
        __syncthreads();
    }
    if (t < 192) {
        int h = t >> 6, k = t & 63;
        const float* W = (h == 0) ? telW : ((h == 1) ? compW : pchW);
        red[t] = G2[k] * W[k];
    }
    __syncthreads();
    if (t < 3) {
        float acc = 0.f;
        for (int k = 0; k < 64; k++) acc += red[t * 64 + k];
        float bb = (t == 0) ? telb[0] : ((t == 1) ? compb[0] : pchb[0]);
        out[t * 64 + gi] = acc + bb;
    }
}

extern "C" void kernel_launch(void* const* d_in, const int* in_sizes, int n_in,
                              void* d_out, int out_size, void* d_ws, size_t ws_size,
                              hipStream_t stream) {
    const float* x        = (const float*)d_in[0];
    const float* EA       = (const float*)d_in[1];
    const float* node_emb = (const float*)d_in[2];
    const float* edge_W   = (const float*)d_in[3];
    const float* edge_b   = (const float*)d_in[4];
    const float* W1       = (const float*)d_in[5];
    const float* as1      = (const float*)d_in[6];
    const float* ad1      = (const float*)d_in[7];
    const float* ae1      = (const float*)d_in[8];
    const float* leW1     = (const float*)d_in[9];
    const float* b1       = (const float*)d_in[10];
    const float* W2       = (const float*)d_in[11];
    const float* as2      = (const float*)d_in[12];
    const float* ad2      = (const float*)d_in[13];
    const float* ae2      = (const float*)d_in[14];
    const float* leW2     = (const float*)d_in[15];
    const float* b2       = (const float*)d_in[16];
    const float* sage_Wl  = (const float*)d_in[17];
    const float* sage_bl  = (const float*)d_in[18];
    const float* sage_Wr  = (const float*)d_in[19];
    const float* lin1_W   = (const float*)d_in[20];
    const float* lin1_b   = (const float*)d_in[21];
    const float* lin2_W   = (const float*)d_in[22];
    const float* lin2_b   = (const float*)d_in[23];
    const float* tel_W    = (const float*)d_in[24];
    const float* tel_b    = (const float*)d_in[25];
    const float* comp_W   = (const float*)d_in[26];
    const float* comp_b   = (const float*)d_in[27];
    const float* pch_W    = (const float*)d_in[28];
    const float* pch_b    = (const float*)d_in[29];
    const int* edge_index = (const int*)d_in[30];
    const int* batch      = (const int*)d_in[31];
    const int* node_type  = (const int*)d_in[32];
    float* outp = (float*)d_out;

    const int* srcp = edge_index;
    const int* dstp = edge_index + NE;

    float* wf = (float*)d_ws;
    constexpr size_t OFF_H3    = 0;                               // N*64
    constexpr size_t OFF_AGG   = OFF_H3 + (size_t)NN * 64;        // N*512 (agg1[320]/agg2[256]/AB)
    constexpr size_t OFF_H1    = OFF_AGG + (size_t)NN * 512;      // N*64
    constexpr size_t OFF_H2    = OFF_H1 + (size_t)NN * 64;        // N*64
    constexpr size_t OFF_SC    = OFF_H2 + (size_t)NN * 64;        // E*4 (sc1 then sc2)
    constexpr size_t OFF_AE2   = OFF_SC + (size_t)NE * 4;         // E*4
    constexpr size_t OFF_AS    = OFF_AE2 + (size_t)NE * 4;        // N*4
    constexpr size_t OFF_AD    = OFF_AS + (size_t)NN * 4;         // N*4
    constexpr size_t OFF_SMALL = OFF_AD + (size_t)NN * 4;         // 4096
    constexpr size_t OFF_WC1   = OFF_SMALL + 4096;                // 20480
    constexpr size_t OFF_WC2   = OFF_WC1 + 20480;                 // 16384
    constexpr size_t OFF_B128  = OFF_WC2 + 16384;                 // 8192
    constexpr size_t OFF_XB    = OFF_B128 + 8192;                 // N*32 (uint = bf16x2)
    constexpr size_t OFF_H1B   = OFF_XB + (size_t)NN * 32;        // N*32
    constexpr size_t OFF_H2B   = OFF_H1B + (size_t)NN * 32;       // N*32
    constexpr size_t F_TOTAL   = OFF_H2B + (size_t)NN * 32;

    int* wi         = (int*)(wf + F_TOTAL);
    int* cnt        = wi;                        // N
    int* rank       = wi + NN;                   // E
    int* eoff       = rank + NE;                 // N+1
    int2* se_sorted = (int2*)(eoff + (NN + 2));  // E int2 (8B aligned)
    int* goff       = (int*)(se_sorted + NE);    // NG+1
    int* bsum       = goff + (NG + 1);           // 64
    int* boff       = bsum + 64;                 // 64

    float* h3    = wf + OFF_H3;
    float* aggb  = wf + OFF_AGG;
    float* h1    = wf + OFF_H1;
    float* h2    = wf + OFF_H2;
    float* sc    = wf + OFF_SC;
    float* ae2s  = wf + OFF_AE2;
    float* as_   = wf + OFF_AS;
    float* ad_   = wf + OFF_AD;
    float* S     = wf + OFF_SMALL;
    float* WC1   = wf + OFF_WC1;
    float* WC2   = wf + OFF_WC2;
    float* B128  = wf + OFF_B128;
    unsigned* xb  = (unsigned*)(wf + OFF_XB);
    unsigned* h1b = (unsigned*)(wf + OFF_H1B);
    unsigned* h2b = (unsigned*)(wf + OFF_H2B);
    float* AB    = wf + OFF_AGG;                 // alias

    hipMemsetAsync(S + S_MEANEA, 0, 16 * sizeof(float), stream);
    hipMemsetAsync(cnt, 0, NN * sizeof(int), stream);

    cm_prepw_kernel<<<176 + (NE + 511) / 512, 256, 0, stream>>>(
        dstp, EA, cnt, rank, S, W1, W2, sage_Wl, sage_Wr, node_emb, WC1, WC2, B128);
    {
        int nb = (NN + 1023) / 1024;  // 30
        scan_blocks_kernel<<<nb, 1024, 0, stream>>>(cnt, eoff, bsum);
        tops_goff_prep_kernel<<<3, 256, 0, stream>>>(
            bsum, boff, nb, batch, goff,
            W1, as1, ad1, ae1, leW1, W2, as2, ad2, ae2, leW2, edge_W, edge_b, S);
        scanadd_attn_kernel<<<118 + (NN + 63) / 64, 256, 0, stream>>>(
            boff, eoff, x, node_emb, node_type, S, as_, ad_, xb);
    }
    scatter_score_kernel<<<(NE + 255) / 256, 256, 0, stream>>>(
        srcp, dstp, EA, S, as_, ad_, node_type, eoff, rank, se_sorted, sc, ae2s);

    // ----- GAT layer 1: bf16 x-gather + type histogram -> K=320 projection -----
    agg_gat1_kernel<<<(NN + 3) / 4, 256, 0, stream>>>(
        eoff, se_sorted, sc, xb, node_type, as_, ad_, S + S_AEL1, aggb);
    gemm64_kernel<320, true><<<(NN + 63) / 64, 256, 0, stream>>>(
        aggb, WC1, b1, h1, h1b, S + S_MS2, S + S_MD2, as_, ad_);

    // ----- GAT layer 2: dense score pass then bf16 gather -----
    score2_kernel<<<(NE + 255) / 256, 256, 0, stream>>>(srcp, dstp, ae2s, as_, ad_, sc);
    agg_gat2_kernel<<<(NN + 3) / 4, 256, 0, stream>>>(
        eoff, se_sorted, sc, h1b, as_, ad_, S + S_AEL2, aggb);
    gemm64_kernel<256, false><<<(NN + 63) / 64, 256, 0, stream>>>(
        aggb, WC2, b2, h2, h2b, nullptr, nullptr, nullptr, nullptr);

    // ----- SAGE -----
    sage_agg3_kernel<<<(NN + 15) / 16, 256, 0, stream>>>(h2, h2b, eoff, se_sorted, AB);
    gemm64_kernel<128, false><<<(NN + 63) / 64, 256, 0, stream>>>(
        AB, B128, sage_bl, h3, nullptr, nullptr, nullptr, nullptr, nullptr);

    // ----- fused pool + MLP head -----
    pool_mlp_kernel<<<NG, 256, 0, stream>>>(h3, goff, lin1_W, lin1_b, lin2_W, lin2_b,
                                            tel_W, tel_b, comp_W, comp_b, pch_W, pch_b, outp);
}